// Round 2
// baseline (2646.615 us; speedup 1.0000x reference)
//
#include <hip/hip_runtime.h>
#include <math.h>

#define Bn 32
#define Mn 2048
#define Nn 65536      // Bn * Mn
#define SDn 16
#define CWn 512
#define EPSf 1e-5f
#define KGF 8

typedef unsigned short bf16_t;

__device__ __forceinline__ float b2f(bf16_t h) {
    unsigned int u = ((unsigned int)h) << 16;
    union { unsigned int u; float f; } c; c.u = u; return c.f;
}
__device__ __forceinline__ bf16_t f2b(float f) {
    union { float f; unsigned int u; } c; c.f = f;
    unsigned int u = c.u + 0x7FFFu + ((c.u >> 16) & 1u);   // round-to-nearest-even
    return (bf16_t)(u >> 16);
}

template<typename T> __device__ __forceinline__ float4 load4(const T* p);
template<> __device__ __forceinline__ float4 load4<float>(const float* p) {
    return *(const float4*)p;
}
template<> __device__ __forceinline__ float4 load4<bf16_t>(const bf16_t* p) {
    ushort4 h = *(const ushort4*)p;
    return make_float4(b2f(h.x), b2f(h.y), b2f(h.z), b2f(h.w));
}
template<typename T> __device__ __forceinline__ void store4(T* p, float4 v);
template<> __device__ __forceinline__ void store4<float>(float* p, float4 v) {
    *(float4*)p = v;
}
template<> __device__ __forceinline__ void store4<bf16_t>(bf16_t* p, float4 v) {
    ushort4 h = {f2b(v.x), f2b(v.y), f2b(v.z), f2b(v.w)};
    *(ushort4*)p = h;
}

// ---------------------------------------------------------------------------
// per-point L2 normalize of s[B,16,M], transpose to xs[16, B*M] (fp32)
// ---------------------------------------------------------------------------
__global__ __launch_bounds__(256) void normalize_kernel(const float* __restrict__ s,
                                                        float* __restrict__ xs) {
    const int m = blockIdx.x * 256 + threadIdx.x;
    const int b = blockIdx.y;
    const float* sp = s + (size_t)b * SDn * Mn + m;
    float v[SDn];
    float sq = 0.f;
#pragma unroll
    for (int c = 0; c < SDn; ++c) { v[c] = sp[(size_t)c * Mn]; sq += v[c] * v[c]; }
    const float r = 1.0f / sqrtf(sq);
    float* xp = xs + (size_t)b * Mn + m;
#pragma unroll
    for (int c = 0; c < SDn; ++c) xp[(size_t)c * Nn] = v[c] * r;
}

// ---------------------------------------------------------------------------
// Fused GEMM: Y[Cout, N] = W[Cout, Cin] * X[Cin, N] (+epilogues)
// IN_MODE:  0 = plain X, 1 = BN(scale,shift)+ReLU applied to X on load
// EPI_MODE: 0 = +bias, ReLU
//           1 = +bias, Hardtanh, * z[b, r]
//           2 = +bias (raw), accumulate per-channel sum/sumsq into stats
// ---------------------------------------------------------------------------
template<typename XT, typename YT, int IN_MODE, int EPI_MODE>
__global__ __launch_bounds__(256) void gemm_kernel(
    const float* __restrict__ W, const XT* __restrict__ X, YT* __restrict__ Y,
    const float* __restrict__ bias, const float* __restrict__ bnp,
    const float* __restrict__ zmod, float* __restrict__ stats, int Cout, int Cin)
{
    __shared__ __align__(16) float sW[16][64];   // [k][row]
    __shared__ __align__(16) float sX[16][64];   // [k][col]
    const int tid = threadIdx.x;
    const int tx = tid & 15, ty = tid >> 4;
    const int n0 = blockIdx.x * 64;
    const int co0 = blockIdx.y * 64;
    const int wr = tid >> 2, wc = (tid & 3) << 2;   // W loader: row, k-col
    const int xr = tid >> 4, xc = (tid & 15) << 2;  // X loader: k-row, col
    float acc[4][4] = {};
    for (int k0 = 0; k0 < Cin; k0 += 16) {
        float4 wv = *(const float4*)(W + (size_t)(co0 + wr) * Cin + k0 + wc);
        float4 xv = load4<XT>(X + (size_t)(k0 + xr) * Nn + n0 + xc);
        if (IN_MODE == 1) {
            const float sc = bnp[(k0 + xr) * 2], sh = bnp[(k0 + xr) * 2 + 1];
            xv.x = fmaxf(fmaf(xv.x, sc, sh), 0.f);
            xv.y = fmaxf(fmaf(xv.y, sc, sh), 0.f);
            xv.z = fmaxf(fmaf(xv.z, sc, sh), 0.f);
            xv.w = fmaxf(fmaf(xv.w, sc, sh), 0.f);
        }
        __syncthreads();
        sW[wc + 0][wr] = wv.x; sW[wc + 1][wr] = wv.y;
        sW[wc + 2][wr] = wv.z; sW[wc + 3][wr] = wv.w;
        *(float4*)&sX[xr][xc] = xv;
        __syncthreads();
#pragma unroll
        for (int k = 0; k < 16; ++k) {
            const float4 a4 = *(const float4*)&sW[k][ty << 2];
            const float4 b4 = *(const float4*)&sX[k][tx << 2];
            const float av[4] = {a4.x, a4.y, a4.z, a4.w};
            const float bv[4] = {b4.x, b4.y, b4.z, b4.w};
#pragma unroll
            for (int i = 0; i < 4; ++i)
#pragma unroll
                for (int j = 0; j < 4; ++j)
                    acc[i][j] = fmaf(av[i], bv[j], acc[i][j]);
        }
    }
#pragma unroll
    for (int i = 0; i < 4; ++i) {
        const int r = co0 + (ty << 2) + i;
        const float bs = bias[r];
        float v[4];
#pragma unroll
        for (int j = 0; j < 4; ++j) v[j] = acc[i][j] + bs;
        if (EPI_MODE == 0) {
#pragma unroll
            for (int j = 0; j < 4; ++j) v[j] = fmaxf(v[j], 0.f);
        } else if (EPI_MODE == 1) {
            const int bb = n0 >> 11;                 // column block -> batch index
            const float zf = zmod[bb * CWn + r];
#pragma unroll
            for (int j = 0; j < 4; ++j) v[j] = fminf(fmaxf(v[j], -1.f), 1.f) * zf;
        }
        float4 st = {v[0], v[1], v[2], v[3]};
        store4<YT>(Y + (size_t)r * Nn + n0 + (tx << 2), st);
        if (EPI_MODE == 2) {
            float ps = v[0] + v[1] + v[2] + v[3];
            float pq = v[0] * v[0] + v[1] * v[1] + v[2] * v[2] + v[3] * v[3];
#pragma unroll
            for (int off = 1; off < 16; off <<= 1) {
                ps += __shfl_xor(ps, off);
                pq += __shfl_xor(pq, off);
            }
            if (tx == 0) {
                atomicAdd(&stats[r * 2], ps);
                atomicAdd(&stats[r * 2 + 1], pq);
            }
        }
    }
}

// ---------------------------------------------------------------------------
// BN finalize: stats(sum,sumsq) -> (scale, shift) per channel
// ---------------------------------------------------------------------------
__global__ void finalize_kernel(const float* __restrict__ stats, const float* __restrict__ g,
                                const float* __restrict__ be, float* __restrict__ bnp, int C) {
    const int c = blockIdx.x * blockDim.x + threadIdx.x;
    if (c >= C) return;
    const float inv = 1.0f / (float)Nn;
    const float mean = stats[c * 2] * inv;
    const float var = stats[c * 2 + 1] * inv - mean * mean;
    const float sc = g[c] / sqrtf(var + EPSf);
    bnp[c * 2] = sc;
    bnp[c * 2 + 1] = fmaf(-mean, sc, be[c]);
}

// ---------------------------------------------------------------------------
// Final 64->3 conv (BN+ReLU on input), writes pts[N][4] = x,y,z,|p|^2
// ---------------------------------------------------------------------------
__global__ __launch_bounds__(256) void finalconv_kernel(
    const float* __restrict__ y3, const float* __restrict__ bnp,
    const float* __restrict__ wout, const float* __restrict__ bout,
    float* __restrict__ pts)
{
    __shared__ float swo[3][64];
    __shared__ float ssc[64], ssh[64];
    const int tid = threadIdx.x;
    if (tid < 192) swo[tid / 64][tid % 64] = wout[tid];
    if (tid < 64) { ssc[tid] = bnp[tid * 2]; ssh[tid] = bnp[tid * 2 + 1]; }
    __syncthreads();
    const int n = blockIdx.x * 256 + tid;
    float d0 = bout[0], d1 = bout[1], d2 = bout[2];
    for (int c = 0; c < 64; ++c) {
        const float v = y3[(size_t)c * Nn + n];
        const float a = fmaxf(fmaf(v, ssc[c], ssh[c]), 0.f);
        d0 = fmaf(a, swo[0][c], d0);
        d1 = fmaf(a, swo[1][c], d1);
        d2 = fmaf(a, swo[2][c], d2);
    }
    float4 p = {d0, d1, d2, d0 * d0 + d1 * d1 + d2 * d2};
    *(float4*)(pts + (size_t)n * 4) = p;
}

// ---------------------------------------------------------------------------
// Graph filtering: per batch, kNN (K=8, excl self) + out = 2*p - mean(neigh)
// ---------------------------------------------------------------------------
__global__ __launch_bounds__(256) void knn_kernel(const float* __restrict__ pts,
                                                  float* __restrict__ out) {
    __shared__ __align__(16) float4 sp[Mn];   // 32 KB: all points of this batch
    const int b = blockIdx.y;
    const int tid = threadIdx.x;
    const float4* pb = (const float4*)pts + (size_t)b * Mn;
    for (int i = tid; i < Mn; i += 256) sp[i] = pb[i];
    __syncthreads();
    const int m = blockIdx.x * 256 + tid;
    const float4 p = sp[m];
    float bd[KGF]; int bi[KGF];
#pragma unroll
    for (int k = 0; k < KGF; ++k) { bd[k] = 1e30f; bi[k] = -1; }
    float worst = 1e30f; int wslot = 0;
    for (int n = 0; n < Mn; ++n) {
        const float4 q = sp[n];
        const float d = p.w + q.w - 2.f * (p.x * q.x + p.y * q.y + p.z * q.z);
        if (d < worst && n != m) {            // tie (d==worst): earlier index kept
            bd[wslot] = d; bi[wslot] = n;
            worst = bd[0]; wslot = 0; int wi = bi[0];
#pragma unroll
            for (int k = 1; k < KGF; ++k) {
                // among equal max distances evict the highest index (matches top_k order)
                if (bd[k] > worst || (bd[k] == worst && bi[k] > wi)) {
                    worst = bd[k]; wslot = k; wi = bi[k];
                }
            }
        }
    }
    float nx = 0.f, ny = 0.f, nz = 0.f;
#pragma unroll
    for (int k = 0; k < KGF; ++k) { const float4 q = sp[bi[k]]; nx += q.x; ny += q.y; nz += q.z; }
    const float s8 = 0.125f;
    float* ob = out + (size_t)b * 3 * Mn;
    ob[m]          = 2.f * p.x - nx * s8;
    ob[Mn + m]     = 2.f * p.y - ny * s8;
    ob[2 * Mn + m] = 2.f * p.z - nz * s8;
}

// ---------------------------------------------------------------------------
extern "C" void kernel_launch(void* const* d_in, const int* in_sizes, int n_in,
                              void* d_out, int out_size, void* d_ws, size_t ws_size,
                              hipStream_t stream)
{
    (void)in_sizes; (void)n_in; (void)out_size;
    const float* z     = (const float*)d_in[0];
    const float* s     = (const float*)d_in[1];
    const float* w_m1  = (const float*)d_in[2];
    const float* b_m1  = (const float*)d_in[3];
    const float* w_m2  = (const float*)d_in[4];
    const float* b_m2  = (const float*)d_in[5];
    const float* w_out = (const float*)d_in[6];
    const float* b_out = (const float*)d_in[7];
    const float* w_c[4]  = {(const float*)d_in[8],  (const float*)d_in[12], (const float*)d_in[16], (const float*)d_in[20]};
    const float* b_c[4]  = {(const float*)d_in[9],  (const float*)d_in[13], (const float*)d_in[17], (const float*)d_in[21]};
    const float* g_c[4]  = {(const float*)d_in[10], (const float*)d_in[14], (const float*)d_in[18], (const float*)d_in[22]};
    const float* be_c[4] = {(const float*)d_in[11], (const float*)d_in[15], (const float*)d_in[19], (const float*)d_in[23]};

    char* ws = (char*)d_ws;
    const size_t MB = 1024ull * 1024ull;
    // stats/bnp scratch lives in d_out (768 KB); knn overwrites all of d_out last.
    float* stats = (float*)d_out;          // 4096 floats (sum,sumsq per layer, offsets 0/1024/2048/3072)
    float* bnp   = (float*)d_out + 4096;   // 4096 floats (scale,shift per layer)
    float* outp  = (float*)d_out;

    hipMemsetAsync(stats, 0, 4096 * sizeof(float), stream);

    const dim3 g256(Nn / 64, 4), g512(Nn / 64, 8), g128(Nn / 64, 2), g64(Nn / 64, 1);

    if (ws_size >= 256 * MB) {
        // ---- tier 1: all fp32 (two 128 MiB ping-pong buffers) ----
        float* bufA = (float*)ws;
        float* bufB = (float*)(ws + 128 * MB);
        normalize_kernel<<<dim3(Mn / 256, Bn), 256, 0, stream>>>(s, bufA);
        gemm_kernel<float, float, 0, 0><<<g256, 256, 0, stream>>>(w_m1, bufA, bufB, b_m1, nullptr, nullptr, nullptr, 256, 16);
        gemm_kernel<float, float, 0, 1><<<g512, 256, 0, stream>>>(w_m2, bufB, bufA, b_m2, nullptr, z, nullptr, 512, 256);
        gemm_kernel<float, float, 0, 2><<<g512, 256, 0, stream>>>(w_c[0], bufA, bufB, b_c[0], nullptr, nullptr, stats + 0, 512, 512);
        finalize_kernel<<<2, 256, 0, stream>>>(stats + 0, g_c[0], be_c[0], bnp + 0, 512);
        gemm_kernel<float, float, 1, 2><<<g256, 256, 0, stream>>>(w_c[1], bufB, bufA, b_c[1], bnp + 0, nullptr, stats + 1024, 256, 512);
        finalize_kernel<<<1, 256, 0, stream>>>(stats + 1024, g_c[1], be_c[1], bnp + 1024, 256);
        gemm_kernel<float, float, 1, 2><<<g128, 256, 0, stream>>>(w_c[2], bufA, bufB, b_c[2], bnp + 1024, nullptr, stats + 2048, 128, 256);
        finalize_kernel<<<1, 128, 0, stream>>>(stats + 2048, g_c[2], be_c[2], bnp + 2048, 128);
        gemm_kernel<float, float, 1, 2><<<g64, 256, 0, stream>>>(w_c[3], bufB, bufA, b_c[3], bnp + 2048, nullptr, stats + 3072, 64, 128);
        finalize_kernel<<<1, 64, 0, stream>>>(stats + 3072, g_c[3], be_c[3], bnp + 3072, 64);
        finalconv_kernel<<<Nn / 256, 256, 0, stream>>>(bufA, bnp + 3072, w_out, b_out, bufB);
        knn_kernel<<<dim3(Mn / 256, Bn), 256, 0, stream>>>(bufB, outp);
    } else if (ws_size >= 192 * MB) {
        // ---- tier 2: x2/y0 (512-ch tensors) in bf16, rest fp32; 3x 64 MiB regions ----
        float*  x1  = (float*)ws;                 // 64 MiB @ B
        float*  y1  = (float*)ws;                 //       @ B (x1 dead)
        float*  pts = (float*)ws;                 //       @ B (y1 dead)
        float*  xs  = (float*)(ws + 64 * MB);     //  4 MiB @ C
        bf16_t* x2  = (bf16_t*)(ws + 64 * MB);    // 64 MiB @ C (xs dead)
        float*  y2  = (float*)(ws + 64 * MB);     // 32 MiB @ C (x2 dead)
        bf16_t* y0  = (bf16_t*)(ws + 128 * MB);   // 64 MiB @ D
        float*  y3  = (float*)(ws + 128 * MB);    // 16 MiB @ D (y0 dead)
        normalize_kernel<<<dim3(Mn / 256, Bn), 256, 0, stream>>>(s, xs);
        gemm_kernel<float, float, 0, 0><<<g256, 256, 0, stream>>>(w_m1, xs, x1, b_m1, nullptr, nullptr, nullptr, 256, 16);
        gemm_kernel<float, bf16_t, 0, 1><<<g512, 256, 0, stream>>>(w_m2, x1, x2, b_m2, nullptr, z, nullptr, 512, 256);
        gemm_kernel<bf16_t, bf16_t, 0, 2><<<g512, 256, 0, stream>>>(w_c[0], x2, y0, b_c[0], nullptr, nullptr, stats + 0, 512, 512);
        finalize_kernel<<<2, 256, 0, stream>>>(stats + 0, g_c[0], be_c[0], bnp + 0, 512);
        gemm_kernel<bf16_t, float, 1, 2><<<g256, 256, 0, stream>>>(w_c[1], y0, y1, b_c[1], bnp + 0, nullptr, stats + 1024, 256, 512);
        finalize_kernel<<<1, 256, 0, stream>>>(stats + 1024, g_c[1], be_c[1], bnp + 1024, 256);
        gemm_kernel<float, float, 1, 2><<<g128, 256, 0, stream>>>(w_c[2], y1, y2, b_c[2], bnp + 1024, nullptr, stats + 2048, 128, 256);
        finalize_kernel<<<1, 128, 0, stream>>>(stats + 2048, g_c[2], be_c[2], bnp + 2048, 128);
        gemm_kernel<float, float, 1, 2><<<g64, 256, 0, stream>>>(w_c[3], y2, y3, b_c[3], bnp + 2048, nullptr, stats + 3072, 64, 128);
        finalize_kernel<<<1, 64, 0, stream>>>(stats + 3072, g_c[3], be_c[3], bnp + 3072, 64);
        finalconv_kernel<<<Nn / 256, 256, 0, stream>>>(y3, bnp + 3072, w_out, b_out, pts);
        knn_kernel<<<dim3(Mn / 256, Bn), 256, 0, stream>>>(pts, outp);
    } else if (ws_size >= 96 * MB) {
        // ---- tier 3: all intermediates bf16 (except xs/y3/pts); 3x 32 MiB regions ----
        bf16_t* x1  = (bf16_t*)ws;                // 32 MiB @ B
        bf16_t* y1  = (bf16_t*)ws;                // 16 MiB @ B (x1 dead)
        float*  pts = (float*)ws;                 //  1 MiB @ B (y1 dead)
        float*  xs  = (float*)(ws + 32 * MB);     //  4 MiB @ C
        bf16_t* x2  = (bf16_t*)(ws + 32 * MB);    // 32 MiB @ C (xs dead)
        bf16_t* y2  = (bf16_t*)(ws + 32 * MB);    //  8 MiB @ C (x2 dead)
        bf16_t* y0  = (bf16_t*)(ws + 64 * MB);    // 32 MiB @ D
        float*  y3  = (float*)(ws + 64 * MB);     // 16 MiB @ D (y0 dead)
        normalize_kernel<<<dim3(Mn / 256, Bn), 256, 0, stream>>>(s, xs);
        gemm_kernel<float, bf16_t, 0, 0><<<g256, 256, 0, stream>>>(w_m1, xs, x1, b_m1, nullptr, nullptr, nullptr, 256, 16);
        gemm_kernel<bf16_t, bf16_t, 0, 1><<<g512, 256, 0, stream>>>(w_m2, x1, x2, b_m2, nullptr, z, nullptr, 512, 256);
        gemm_kernel<bf16_t, bf16_t, 0, 2><<<g512, 256, 0, stream>>>(w_c[0], x2, y0, b_c[0], nullptr, nullptr, stats + 0, 512, 512);
        finalize_kernel<<<2, 256, 0, stream>>>(stats + 0, g_c[0], be_c[0], bnp + 0, 512);
        gemm_kernel<bf16_t, bf16_t, 1, 2><<<g256, 256, 0, stream>>>(w_c[1], y0, y1, b_c[1], bnp + 0, nullptr, stats + 1024, 256, 512);
        finalize_kernel<<<1, 256, 0, stream>>>(stats + 1024, g_c[1], be_c[1], bnp + 1024, 256);
        gemm_kernel<bf16_t, bf16_t, 1, 2><<<g128, 256, 0, stream>>>(w_c[2], y1, y2, b_c[2], bnp + 1024, nullptr, stats + 2048, 128, 256);
        finalize_kernel<<<1, 128, 0, stream>>>(stats + 2048, g_c[2], be_c[2], bnp + 2048, 128);
        gemm_kernel<bf16_t, float, 1, 2><<<g64, 256, 0, stream>>>(w_c[3], y2, y3, b_c[3], bnp + 2048, nullptr, stats + 3072, 64, 128);
        finalize_kernel<<<1, 64, 0, stream>>>(stats + 3072, g_c[3], be_c[3], bnp + 3072, 64);
        finalconv_kernel<<<Nn / 256, 256, 0, stream>>>(y3, bnp + 3072, w_out, b_out, pts);
        knn_kernel<<<dim3(Mn / 256, Bn), 256, 0, stream>>>(pts, outp);
    }
    // else: ws too small for any plan — next round will shrink further (chunked BN).
}

// Round 7
// 1856.557 us; speedup vs baseline: 1.4256x; 1.4256x over previous
//
#include <hip/hip_runtime.h>
#include <math.h>

#define Bn 32
#define Mn 2048
#define Nn 65536      // Bn * Mn
#define Hn 32768      // Nn / 2 (chunk for race-free c0)
#define SDn 16
#define CWn 512
#define EPSf 1e-5f
#define KGF 8
#define WTOT 573440   // logical weight elements
#define LSC 2048.0f   // lo-plane scale (2^11)
#define LSCI (1.0f / 2048.0f)

typedef unsigned short u16;
typedef _Float16 fp16_t;
typedef __attribute__((ext_vector_type(8))) _Float16 h8v;  // MFMA A/B frag: 8 f16
typedef __attribute__((ext_vector_type(4))) float f4v;     // MFMA C/D frag: 4 fp32

__device__ __forceinline__ u16 f2h(float f) {
    union { fp16_t h; u16 u; } c; c.h = (fp16_t)f; return c.u;
}
__device__ __forceinline__ float h2f(u16 u) {
    union { fp16_t h; u16 u; } c; c.u = u; return (float)c.h;
}
// split f into fp16 hi + scaled fp16 lo (lo = fp16((f-hi)*2048))
__device__ __forceinline__ void fsplit(float f, u16& hi, u16& lo) {
    hi = f2h(f);
    lo = f2h((f - h2f(hi)) * LSC);
}
__device__ __forceinline__ float fjoin(u16 hi, u16 lo) {
    return h2f(hi) + h2f(lo) * LSCI;
}
// bf16 helpers (fallback path)
__device__ __forceinline__ float b2f(u16 h) {
    union { unsigned int u; float f; } c; c.u = ((unsigned int)h) << 16; return c.f;
}
__device__ __forceinline__ u16 f2b(float f) {
    union { float f; unsigned int u; } c; c.f = f;
    unsigned int u = c.u + 0x7FFFu + ((c.u >> 16) & 1u);
    return (u16)(u >> 16);
}

// ============================================================================
// Split-precision fp16 MFMA path: tensors stored [rows][2C] (hi | lo*2048)
// ============================================================================

// ---- weights fp32 -> per-row [hi[Cin] | lo[Cin]] layout --------------------
__global__ __launch_bounds__(256) void wcvt_kernel(
    const float* __restrict__ wm1, const float* __restrict__ wm2,
    const float* __restrict__ wc0, const float* __restrict__ wc1,
    const float* __restrict__ wc2, const float* __restrict__ wc3,
    u16* __restrict__ dst)
{
    int i = blockIdx.x * 256 + threadIdx.x;     // 0 .. WTOT-1 logical
    float w; int r, k, Cin; size_t base;
    if (i < 8192) {                              // m1 padded [256][32]
        r = i >> 5; k = i & 31; Cin = 32; base = 0;
        w = (k < SDn) ? wm1[r * SDn + k] : 0.f;
    } else {
        int j = i - 8192;
        if (j < 131072)                    { r = j >> 8; k = j & 255; Cin = 256; base = 16384;   w = wm2[j]; }
        else if ((j -= 131072) < 262144)   { r = j >> 9; k = j & 511; Cin = 512; base = 278528;  w = wc0[j]; }
        else if ((j -= 262144) < 131072)   { r = j >> 9; k = j & 511; Cin = 512; base = 802816;  w = wc1[j]; }
        else if ((j -= 131072) < 32768)    { r = j >> 8; k = j & 255; Cin = 256; base = 1064960; w = wc2[j]; }
        else { j -= 32768;                   r = j >> 7; k = j & 127; Cin = 128; base = 1130496; w = wc3[j]; }
    }
    const size_t addr = base + (size_t)r * (2 * Cin) + k;
    u16 hi, lo; fsplit(w, hi, lo);
    dst[addr] = hi;
    dst[addr + Cin] = lo;
}

// ---- normalize s[B,16,M] -> xs[N][64] (hi[32]|lo[32], upper 16 zero) -------
__global__ __launch_bounds__(256) void normalize_pm(const float* __restrict__ s,
                                                    u16* __restrict__ xs) {
    const int m = blockIdx.x * 256 + threadIdx.x;
    const int b = blockIdx.y;
    const float* sp = s + (size_t)b * SDn * Mn + m;
    float v[SDn]; float sq = 0.f;
#pragma unroll
    for (int c = 0; c < SDn; ++c) { v[c] = sp[(size_t)c * Mn]; sq += v[c] * v[c]; }
    const float r = 1.0f / sqrtf(sq);
    unsigned int uh[8], ul[8];
#pragma unroll
    for (int c = 0; c < 8; ++c) {
        u16 h0, l0, h1, l1;
        fsplit(v[2 * c] * r, h0, l0);
        fsplit(v[2 * c + 1] * r, h1, l1);
        uh[c] = (unsigned int)h0 | ((unsigned int)h1 << 16);
        ul[c] = (unsigned int)l0 | ((unsigned int)l1 << 16);
    }
    uint4* xp = (uint4*)(xs + (size_t)(b * Mn + m) * 64);
    xp[0] = make_uint4(uh[0], uh[1], uh[2], uh[3]);
    xp[1] = make_uint4(uh[4], uh[5], uh[6], uh[7]);
    xp[2] = make_uint4(0, 0, 0, 0);
    xp[3] = make_uint4(0, 0, 0, 0);
    xp[4] = make_uint4(ul[0], ul[1], ul[2], ul[3]);
    xp[5] = make_uint4(ul[4], ul[5], ul[6], ul[7]);
    xp[6] = make_uint4(0, 0, 0, 0);
    xp[7] = make_uint4(0, 0, 0, 0);
}

// ---- split fp16 MFMA GEMM: Y = W * X, all tensors [rows][2C] hi|lo ---------
// acc0 = Wh*Xh ; accL = Wh*Xl' + Wl'*Xh ; result = acc0 + accL/2048
// EPI 0: +bias, ReLU. EPI 1: +bias, hardtanh, *z. EPI 2: +bias raw + stats.
template<int RW, int CWv, int EPI>
__global__ __launch_bounds__(256) void mfma_gemm(
    const u16* __restrict__ W, const u16* __restrict__ X, u16* __restrict__ Y,
    const float* __restrict__ bias, const float* __restrict__ zmod,
    float* __restrict__ stats, int Cout, int Cin)
{
    constexpr int BM = RW * 64, BN = CWv * 64;
    constexpr int ASEG = BM / 64, BSEG = BN / 64;
    __shared__ __align__(16) u16 Ah[BM * 32], Al[BM * 32];
    __shared__ __align__(16) u16 Bh[BN * 32], Bl[BN * 32];
    __shared__ float sstat[(EPI == 2) ? (CWv * BM * 2) : 1];

    const int tid = threadIdx.x;
    const int wave = tid >> 6;
    const int lane = tid & 63;
    const int wm = wave & (RW - 1), wn = wave / RW;
    const int l15 = lane & 15, q = lane >> 4;
    const int m0 = blockIdx.y * BM, n0 = blockIdx.x * BN;
    const int SW = 2 * Cin;

    f4v acc0[4][4], accL[4][4];
#pragma unroll
    for (int i = 0; i < 4; ++i)
#pragma unroll
        for (int j = 0; j < 4; ++j) {
            acc0[i][j] = (f4v){0.f, 0.f, 0.f, 0.f};
            accL[i][j] = (f4v){0.f, 0.f, 0.f, 0.f};
        }

    const int nsteps = Cin >> 5;
    for (int ks = 0; ks < nsteps; ++ks) {
        const int k0 = ks << 5;
        uint4 avh[ASEG], avl[ASEG], bvh[BSEG], bvl[BSEG];
#pragma unroll
        for (int s = 0; s < ASEG; ++s) {
            const int flat = s * 256 + tid;
            const size_t off = (size_t)(m0 + (flat >> 2)) * SW + k0 + ((flat & 3) << 3);
            avh[s] = *(const uint4*)(W + off);
            avl[s] = *(const uint4*)(W + off + Cin);
        }
#pragma unroll
        for (int s = 0; s < BSEG; ++s) {
            const int flat = s * 256 + tid;
            const size_t off = (size_t)(n0 + (flat >> 2)) * SW + k0 + ((flat & 3) << 3);
            bvh[s] = *(const uint4*)(X + off);
            bvl[s] = *(const uint4*)(X + off + Cin);
        }
        __syncthreads();   // previous iteration's frag reads done before overwrite
#pragma unroll
        for (int s = 0; s < ASEG; ++s) {
            const int flat = s * 256 + tid;
            *(uint4*)(Ah + flat * 8) = avh[s];
            *(uint4*)(Al + flat * 8) = avl[s];
        }
#pragma unroll
        for (int s = 0; s < BSEG; ++s) {
            const int flat = s * 256 + tid;
            *(uint4*)(Bh + flat * 8) = bvh[s];
            *(uint4*)(Bl + flat * 8) = bvl[s];
        }
        __syncthreads();
        h8v afh[4], afl[4], bfh[4], bfl[4];
#pragma unroll
        for (int i = 0; i < 4; ++i) {
            const int ao = (wm * 64 + i * 16 + l15) * 32 + q * 8;
            afh[i] = *(const h8v*)(Ah + ao);
            afl[i] = *(const h8v*)(Al + ao);
        }
#pragma unroll
        for (int j = 0; j < 4; ++j) {
            const int bo = (wn * 64 + j * 16 + l15) * 32 + q * 8;
            bfh[j] = *(const h8v*)(Bh + bo);
            bfl[j] = *(const h8v*)(Bl + bo);
        }
#pragma unroll
        for (int i = 0; i < 4; ++i)
#pragma unroll
            for (int j = 0; j < 4; ++j) {
                accL[i][j] = __builtin_amdgcn_mfma_f32_16x16x32_f16(afh[i], bfl[j], accL[i][j], 0, 0, 0);
                accL[i][j] = __builtin_amdgcn_mfma_f32_16x16x32_f16(afl[i], bfh[j], accL[i][j], 0, 0, 0);
                acc0[i][j] = __builtin_amdgcn_mfma_f32_16x16x32_f16(afh[i], bfh[j], acc0[i][j], 0, 0, 0);
            }
    }

    // ---- epilogue ----
    const int bb = n0 >> 11;    // batch index (EPI==1 launches are full-N, BN | 2048)
    const int SY = 2 * Cout;
#pragma unroll
    for (int i = 0; i < 4; ++i) {
        const int chb = m0 + wm * 64 + i * 16 + q * 4;          // global channel base
        const float4 bias4 = *(const float4*)(bias + chb);
        float z0 = 0.f, z1 = 0.f, z2 = 0.f, z3 = 0.f;
        if constexpr (EPI == 1) {
            const float4 z4 = *(const float4*)(zmod + bb * CWn + chb);
            z0 = z4.x; z1 = z4.y; z2 = z4.z; z3 = z4.w;
        }
        float ssum[4] = {0.f, 0.f, 0.f, 0.f}, ssq[4] = {0.f, 0.f, 0.f, 0.f};
#pragma unroll
        for (int j = 0; j < 4; ++j) {
            const int n = n0 + wn * 64 + j * 16 + l15;
            float v0 = fmaf(accL[i][j][0], LSCI, acc0[i][j][0]) + bias4.x;
            float v1 = fmaf(accL[i][j][1], LSCI, acc0[i][j][1]) + bias4.y;
            float v2 = fmaf(accL[i][j][2], LSCI, acc0[i][j][2]) + bias4.z;
            float v3 = fmaf(accL[i][j][3], LSCI, acc0[i][j][3]) + bias4.w;
            if constexpr (EPI == 0) {
                v0 = fmaxf(v0, 0.f); v1 = fmaxf(v1, 0.f); v2 = fmaxf(v2, 0.f); v3 = fmaxf(v3, 0.f);
            } else if constexpr (EPI == 1) {
                v0 = fminf(fmaxf(v0, -1.f), 1.f) * z0;
                v1 = fminf(fmaxf(v1, -1.f), 1.f) * z1;
                v2 = fminf(fmaxf(v2, -1.f), 1.f) * z2;
                v3 = fminf(fmaxf(v3, -1.f), 1.f) * z3;
            } else {
                ssum[0] += v0; ssum[1] += v1; ssum[2] += v2; ssum[3] += v3;
                ssq[0] += v0 * v0; ssq[1] += v1 * v1; ssq[2] += v2 * v2; ssq[3] += v3 * v3;
            }
            u16 h0, l0, h1, l1, h2, l2, h3, l3;
            fsplit(v0, h0, l0); fsplit(v1, h1, l1);
            fsplit(v2, h2, l2); fsplit(v3, h3, l3);
            ushort4 hv = {h0, h1, h2, h3};
            ushort4 lv = {l0, l1, l2, l3};
            u16* yp = Y + (size_t)n * SY + chb;
            *(ushort4*)yp = hv;
            *(ushort4*)(yp + Cout) = lv;
        }
        if constexpr (EPI == 2) {
#pragma unroll
            for (int r = 0; r < 4; ++r) {
#pragma unroll
                for (int d = 1; d < 16; d <<= 1) {
                    ssum[r] += __shfl_xor(ssum[r], d);
                    ssq[r]  += __shfl_xor(ssq[r], d);
                }
            }
            if (l15 == 0) {
                const int chl = wm * 64 + i * 16 + q * 4;
#pragma unroll
                for (int r = 0; r < 4; ++r) {
                    sstat[(wn * BM + chl + r) * 2]     = ssum[r];
                    sstat[(wn * BM + chl + r) * 2 + 1] = ssq[r];
                }
            }
        }
    }
    if constexpr (EPI == 2) {
        __syncthreads();
        if (tid < BM) {
            float s0 = 0.f, s1 = 0.f;
#pragma unroll
            for (int w = 0; w < CWv; ++w) {
                s0 += sstat[(w * BM + tid) * 2];
                s1 += sstat[(w * BM + tid) * 2 + 1];
            }
            atomicAdd(&stats[(m0 + tid) * 2], s0);
            atomicAdd(&stats[(m0 + tid) * 2 + 1], s1);
        }
    }
}

// ---- BN finalize -----------------------------------------------------------
__global__ void finalize_kernel(const float* __restrict__ stats, const float* __restrict__ g,
                                const float* __restrict__ be, float* __restrict__ bnp, int C) {
    const int c = blockIdx.x * blockDim.x + threadIdx.x;
    if (c >= C) return;
    const float inv = 1.0f / (float)Nn;
    const float mean = stats[c * 2] * inv;
    const float var = stats[c * 2 + 1] * inv - mean * mean;
    const float sc = g[c] / sqrtf(var + EPSf);
    bnp[c * 2] = sc;
    bnp[c * 2 + 1] = fmaf(-mean, sc, be[c]);
}

// ---- in-place BN+ReLU over [rows][2C] split tensor -------------------------
__global__ __launch_bounds__(256) void bnrelu_kernel(u16* x, const float* __restrict__ bnp, int C) {
    const int t = blockIdx.x * 256 + threadIdx.x;
    const int ch = (t * 4) & (C - 1);
    const int row = (t * 4) / C;
    u16* base = x + (size_t)row * (2 * C) + ch;
    ushort4 h = *(ushort4*)base;
    ushort4 l = *(ushort4*)(base + C);
    const float4 p0 = *(const float4*)(bnp + ch * 2);
    const float4 p1 = *(const float4*)(bnp + ch * 2 + 4);
    float a0 = fmaxf(fmaf(fjoin(h.x, l.x), p0.x, p0.y), 0.f);
    float a1 = fmaxf(fmaf(fjoin(h.y, l.y), p0.z, p0.w), 0.f);
    float a2 = fmaxf(fmaf(fjoin(h.z, l.z), p1.x, p1.y), 0.f);
    float a3 = fmaxf(fmaf(fjoin(h.w, l.w), p1.z, p1.w), 0.f);
    u16 h0, l0, h1, l1, h2, l2, h3, l3;
    fsplit(a0, h0, l0); fsplit(a1, h1, l1); fsplit(a2, h2, l2); fsplit(a3, h3, l3);
    ushort4 hv = {h0, h1, h2, h3};
    ushort4 lv = {l0, l1, l2, l3};
    *(ushort4*)base = hv;
    *(ushort4*)(base + C) = lv;
}

// ---- final 64->3 conv (BN+ReLU on split input), pts[N][4] = x,y,z,|p|^2 ----
__global__ __launch_bounds__(256) void finalconv_pm(
    const u16* __restrict__ y3, const float* __restrict__ bnp,
    const float* __restrict__ wout, const float* __restrict__ bout,
    float* __restrict__ pts)
{
    __shared__ float swo[3][64];
    __shared__ float ssc[64], ssh[64];
    const int tid = threadIdx.x;
    if (tid < 192) swo[tid / 64][tid % 64] = wout[tid];
    if (tid < 64) { ssc[tid] = bnp[tid * 2]; ssh[tid] = bnp[tid * 2 + 1]; }
    __syncthreads();
    const int n = blockIdx.x * 256 + tid;
    const u16* yp = y3 + (size_t)n * 128;
    float d0 = bout[0], d1 = bout[1], d2 = bout[2];
#pragma unroll
    for (int c = 0; c < 64; ++c) {
        const float v = fjoin(yp[c], yp[64 + c]);
        const float a = fmaxf(fmaf(v, ssc[c], ssh[c]), 0.f);
        d0 = fmaf(a, swo[0][c], d0);
        d1 = fmaf(a, swo[1][c], d1);
        d2 = fmaf(a, swo[2][c], d2);
    }
    float4 p = {d0, d1, d2, d0 * d0 + d1 * d1 + d2 * d2};
    *(float4*)(pts + (size_t)n * 4) = p;
}

// ---- graph filtering (kNN K=8 excl self + sharpening) ----------------------
__global__ __launch_bounds__(256) void knn_kernel(const float* __restrict__ pts,
                                                  float* __restrict__ out) {
    __shared__ __align__(16) float4 sp[Mn];
    const int b = blockIdx.y;
    const int tid = threadIdx.x;
    const float4* pb = (const float4*)pts + (size_t)b * Mn;
    for (int i = tid; i < Mn; i += 256) sp[i] = pb[i];
    __syncthreads();
    const int m = blockIdx.x * 256 + tid;
    const float4 p = sp[m];
    float bd[KGF]; int bi[KGF];
#pragma unroll
    for (int k = 0; k < KGF; ++k) { bd[k] = 1e30f; bi[k] = -1; }
    float worst = 1e30f; int wslot = 0;
    for (int n = 0; n < Mn; ++n) {
        const float4 qq = sp[n];
        const float d = p.w + qq.w - 2.f * (p.x * qq.x + p.y * qq.y + p.z * qq.z);
        if (d < worst && n != m) {
            bd[wslot] = d; bi[wslot] = n;
            worst = bd[0]; wslot = 0; int wi = bi[0];
#pragma unroll
            for (int k = 1; k < KGF; ++k) {
                if (bd[k] > worst || (bd[k] == worst && bi[k] > wi)) {
                    worst = bd[k]; wslot = k; wi = bi[k];
                }
            }
        }
    }
    float nx = 0.f, ny = 0.f, nz = 0.f;
#pragma unroll
    for (int k = 0; k < KGF; ++k) { const float4 qq = sp[bi[k]]; nx += qq.x; ny += qq.y; nz += qq.z; }
    const float s8 = 0.125f;
    float* ob = out + (size_t)b * 3 * Mn;
    ob[m]          = 2.f * p.x - nx * s8;
    ob[Mn + m]     = 2.f * p.y - ny * s8;
    ob[2 * Mn + m] = 2.f * p.z - nz * s8;
}

// ============================================================================
// FALLBACK (verified round-2 tier-3): channel-major vector GEMM, 96 MiB
// ============================================================================
template<typename T> __device__ __forceinline__ float4 load4(const T* p);
template<> __device__ __forceinline__ float4 load4<float>(const float* p) { return *(const float4*)p; }
template<> __device__ __forceinline__ float4 load4<u16>(const u16* p) {
    ushort4 h = *(const ushort4*)p;
    return make_float4(b2f(h.x), b2f(h.y), b2f(h.z), b2f(h.w));
}
template<typename T> __device__ __forceinline__ void store4(T* p, float4 v);
template<> __device__ __forceinline__ void store4<float>(float* p, float4 v) { *(float4*)p = v; }
template<> __device__ __forceinline__ void store4<u16>(u16* p, float4 v) {
    ushort4 h = {f2b(v.x), f2b(v.y), f2b(v.z), f2b(v.w)};
    *(ushort4*)p = h;
}

__global__ __launch_bounds__(256) void normalize_cm(const float* __restrict__ s,
                                                    float* __restrict__ xs) {
    const int m = blockIdx.x * 256 + threadIdx.x;
    const int b = blockIdx.y;
    const float* sp = s + (size_t)b * SDn * Mn + m;
    float v[SDn]; float sq = 0.f;
#pragma unroll
    for (int c = 0; c < SDn; ++c) { v[c] = sp[(size_t)c * Mn]; sq += v[c] * v[c]; }
    const float r = 1.0f / sqrtf(sq);
    float* xp = xs + (size_t)b * Mn + m;
#pragma unroll
    for (int c = 0; c < SDn; ++c) xp[(size_t)c * Nn] = v[c] * r;
}

template<typename XT, typename YT, int IN_MODE, int EPI_MODE>
__global__ __launch_bounds__(256) void gemm_cm(
    const float* __restrict__ W, const XT* X, YT* Y,
    const float* __restrict__ bias, const float* __restrict__ bnp,
    const float* __restrict__ zmod, float* __restrict__ stats, int Cout, int Cin)
{
    __shared__ __align__(16) float sW[16][64];
    __shared__ __align__(16) float sX[16][64];
    const int tid = threadIdx.x;
    const int tx = tid & 15, ty = tid >> 4;
    const int n0 = blockIdx.x * 64;
    const int co0 = blockIdx.y * 64;
    const int wr = tid >> 2, wc = (tid & 3) << 2;
    const int xr = tid >> 4, xc = (tid & 15) << 2;
    float acc[4][4] = {};
    for (int k0 = 0; k0 < Cin; k0 += 16) {
        float4 wv = *(const float4*)(W + (size_t)(co0 + wr) * Cin + k0 + wc);
        float4 xv = load4<XT>(X + (size_t)(k0 + xr) * Nn + n0 + xc);
        if (IN_MODE == 1) {
            const float sc = bnp[(k0 + xr) * 2], sh = bnp[(k0 + xr) * 2 + 1];
            xv.x = fmaxf(fmaf(xv.x, sc, sh), 0.f);
            xv.y = fmaxf(fmaf(xv.y, sc, sh), 0.f);
            xv.z = fmaxf(fmaf(xv.z, sc, sh), 0.f);
            xv.w = fmaxf(fmaf(xv.w, sc, sh), 0.f);
        }
        __syncthreads();
        sW[wc + 0][wr] = wv.x; sW[wc + 1][wr] = wv.y;
        sW[wc + 2][wr] = wv.z; sW[wc + 3][wr] = wv.w;
        *(float4*)&sX[xr][xc] = xv;
        __syncthreads();
#pragma unroll
        for (int k = 0; k < 16; ++k) {
            const float4 a4 = *(const float4*)&sW[k][ty << 2];
            const float4 b4 = *(const float4*)&sX[k][tx << 2];
            const float av[4] = {a4.x, a4.y, a4.z, a4.w};
            const float bv[4] = {b4.x, b4.y, b4.z, b4.w};
#pragma unroll
            for (int i = 0; i < 4; ++i)
#pragma unroll
                for (int j = 0; j < 4; ++j)
                    acc[i][j] = fmaf(av[i], bv[j], acc[i][j]);
        }
    }
#pragma unroll
    for (int i = 0; i < 4; ++i) {
        const int r = co0 + (ty << 2) + i;
        const float bs = bias[r];
        float v[4];
#pragma unroll
        for (int j = 0; j < 4; ++j) v[j] = acc[i][j] + bs;
        if (EPI_MODE == 0) {
#pragma unroll
            for (int j = 0; j < 4; ++j) v[j] = fmaxf(v[j], 0.f);
        } else if (EPI_MODE == 1) {
            const int bb = n0 >> 11;
            const float zf = zmod[bb * CWn + r];
#pragma unroll
            for (int j = 0; j < 4; ++j) v[j] = fminf(fmaxf(v[j], -1.f), 1.f) * zf;
        }
        float4 st = {v[0], v[1], v[2], v[3]};
        store4<YT>(Y + (size_t)r * Nn + n0 + (tx << 2), st);
        if (EPI_MODE == 2) {
            float ps = v[0] + v[1] + v[2] + v[3];
            float pq = v[0] * v[0] + v[1] * v[1] + v[2] * v[2] + v[3] * v[3];
#pragma unroll
            for (int off = 1; off < 16; off <<= 1) {
                ps += __shfl_xor(ps, off);
                pq += __shfl_xor(pq, off);
            }
            if (tx == 0) {
                atomicAdd(&stats[r * 2], ps);
                atomicAdd(&stats[r * 2 + 1], pq);
            }
        }
    }
}

__global__ __launch_bounds__(256) void finalconv_cm(
    const float* __restrict__ y3, const float* __restrict__ bnp,
    const float* __restrict__ wout, const float* __restrict__ bout,
    float* __restrict__ pts)
{
    __shared__ float swo[3][64];
    __shared__ float ssc[64], ssh[64];
    const int tid = threadIdx.x;
    if (tid < 192) swo[tid / 64][tid % 64] = wout[tid];
    if (tid < 64) { ssc[tid] = bnp[tid * 2]; ssh[tid] = bnp[tid * 2 + 1]; }
    __syncthreads();
    const int n = blockIdx.x * 256 + tid;
    float d0 = bout[0], d1 = bout[1], d2 = bout[2];
    for (int c = 0; c < 64; ++c) {
        const float v = y3[(size_t)c * Nn + n];
        const float a = fmaxf(fmaf(v, ssc[c], ssh[c]), 0.f);
        d0 = fmaf(a, swo[0][c], d0);
        d1 = fmaf(a, swo[1][c], d1);
        d2 = fmaf(a, swo[2][c], d2);
    }
    float4 p = {d0, d1, d2, d0 * d0 + d1 * d1 + d2 * d2};
    *(float4*)(pts + (size_t)n * 4) = p;
}

// ============================================================================
extern "C" void kernel_launch(void* const* d_in, const int* in_sizes, int n_in,
                              void* d_out, int out_size, void* d_ws, size_t ws_size,
                              hipStream_t stream)
{
    (void)in_sizes; (void)n_in; (void)out_size;
    const float* z     = (const float*)d_in[0];
    const float* s     = (const float*)d_in[1];
    const float* w_m1  = (const float*)d_in[2];
    const float* b_m1  = (const float*)d_in[3];
    const float* w_m2  = (const float*)d_in[4];
    const float* b_m2  = (const float*)d_in[5];
    const float* w_out = (const float*)d_in[6];
    const float* b_out = (const float*)d_in[7];
    const float* w_c[4]  = {(const float*)d_in[8],  (const float*)d_in[12], (const float*)d_in[16], (const float*)d_in[20]};
    const float* b_c[4]  = {(const float*)d_in[9],  (const float*)d_in[13], (const float*)d_in[17], (const float*)d_in[21]};
    const float* g_c[4]  = {(const float*)d_in[10], (const float*)d_in[14], (const float*)d_in[18], (const float*)d_in[22]};
    const float* be_c[4] = {(const float*)d_in[11], (const float*)d_in[15], (const float*)d_in[19], (const float*)d_in[23]};

    char* ws = (char*)d_ws;
    const size_t MB = 1024ull * 1024ull;
    float* outp = (float*)d_out;

    if (ws_size >= 208 * MB) {
        // -------- split-fp16 MFMA path (peak 204 MiB) --------
        // 0..2.25 : wbuf [Cout][2Cin] per layer
        // 3..3.04 : stats + bnp
        // 4..12   : xs [N][64]        (later: pts @4..5)
        // 12..76  : x1 [N][512]       (later: y0a rows 0..32K, then y2 @12..44)
        // 76..204 : x2 [N][1024]      (later: y0b @76..140 -> y0 contiguous @12..140;
        //                              y1 @140..204; y3 @76..92)
        u16*   wbuf  = (u16*)ws;
        float* stats = (float*)(ws + 3 * MB);
        float* bnp   = stats + 4096;
        u16*   xs  = (u16*)(ws + 4 * MB);
        u16*   x1  = (u16*)(ws + 12 * MB);
        u16*   x2  = (u16*)(ws + 76 * MB);
        u16*   y0  = (u16*)(ws + 12 * MB);   // contiguous after both chunks
        u16*   y0a = (u16*)(ws + 12 * MB);   // rows [0, 32K)
        u16*   y0b = (u16*)(ws + 76 * MB);   // rows [32K, 64K)
        u16*   y1  = (u16*)(ws + 140 * MB);
        u16*   y2  = (u16*)(ws + 12 * MB);
        u16*   y3  = (u16*)(ws + 76 * MB);
        float* pts = (float*)(ws + 4 * MB);

        hipMemsetAsync(stats, 0, 4096 * sizeof(float), stream);
        wcvt_kernel<<<WTOT / 256, 256, 0, stream>>>(w_m1, w_m2, w_c[0], w_c[1], w_c[2], w_c[3], wbuf);
        normalize_pm<<<dim3(Mn / 256, Bn), 256, 0, stream>>>(s, xs);
        // m1: [N][32] -> [N][256], ReLU            (reads 4..12, writes 12..76)
        mfma_gemm<2, 2, 0><<<dim3(Nn / 128, 2), 256, 0, stream>>>(wbuf, xs, x1, b_m1, nullptr, nullptr, 256, 32);
        // m2: [N][256] -> [N][512], hardtanh*z     (reads 12..76, writes 76..204)
        mfma_gemm<2, 2, 1><<<dim3(Nn / 128, 4), 256, 0, stream>>>(wbuf + 16384, x1, x2, b_m2, z, nullptr, 512, 256);
        // c0 chunk a: rows [0,32K)                 (reads 76..140, writes 12..76)
        mfma_gemm<2, 2, 2><<<dim3(Hn / 128, 4), 256, 0, stream>>>(wbuf + 278528, x2, y0a, b_c[0], nullptr, stats + 0, 512, 512);
        // c0 chunk b: rows [32K,64K)               (reads 140..204, writes 76..140)
        mfma_gemm<2, 2, 2><<<dim3(Hn / 128, 4), 256, 0, stream>>>(wbuf + 278528, x2 + (size_t)Hn * 1024, y0b, b_c[0], nullptr, stats + 0, 512, 512);
        finalize_kernel<<<2, 256, 0, stream>>>(stats + 0, g_c[0], be_c[0], bnp + 0, 512);
        bnrelu_kernel<<<(Nn / 256) * 512 / 4, 256, 0, stream>>>(y0, bnp + 0, 512);
        // c1: [N][512] -> [N][256]                 (reads 12..140, writes 140..204)
        mfma_gemm<2, 2, 2><<<dim3(Nn / 128, 2), 256, 0, stream>>>(wbuf + 802816, y0, y1, b_c[1], nullptr, stats + 1024, 256, 512);
        finalize_kernel<<<1, 256, 0, stream>>>(stats + 1024, g_c[1], be_c[1], bnp + 1024, 256);
        bnrelu_kernel<<<(Nn / 256) * 256 / 4, 256, 0, stream>>>(y1, bnp + 1024, 256);
        // c2: [N][256] -> [N][128]                 (reads 140..204, writes 12..44)
        mfma_gemm<2, 2, 2><<<dim3(Nn / 128, 1), 256, 0, stream>>>(wbuf + 1064960, y1, y2, b_c[2], nullptr, stats + 2048, 128, 256);
        finalize_kernel<<<1, 128, 0, stream>>>(stats + 2048, g_c[2], be_c[2], bnp + 2048, 128);
        bnrelu_kernel<<<(Nn / 256) * 128 / 4, 256, 0, stream>>>(y2, bnp + 2048, 128);
        // c3: [N][128] -> [N][64]                  (reads 12..44, writes 76..92)
        mfma_gemm<1, 4, 2><<<dim3(Nn / 256, 1), 256, 0, stream>>>(wbuf + 1130496, y2, y3, b_c[3], nullptr, stats + 3072, 64, 128);
        finalize_kernel<<<1, 64, 0, stream>>>(stats + 3072, g_c[3], be_c[3], bnp + 3072, 64);
        // finalconv: reads 76..92 -> pts @4..5
        finalconv_pm<<<Nn / 256, 256, 0, stream>>>(y3, bnp + 3072, w_out, b_out, pts);
        knn_kernel<<<dim3(Mn / 256, Bn), 256, 0, stream>>>(pts, outp);
    } else if (ws_size >= 96 * MB) {
        // -------- fallback: round-2 tier-3 (verified structure) --------
        float* stats = (float*)d_out;
        float* bnp   = (float*)d_out + 4096;
        hipMemsetAsync(stats, 0, 4096 * sizeof(float), stream);
        const dim3 g256(Nn / 64, 4), g512(Nn / 64, 8), g128(Nn / 64, 2), g64(Nn / 64, 1);
        u16*   x1  = (u16*)ws;
        u16*   y1  = (u16*)ws;
        float* pts = (float*)ws;
        float* xs  = (float*)(ws + 32 * MB);
        u16*   x2  = (u16*)(ws + 32 * MB);
        u16*   y2  = (u16*)(ws + 32 * MB);
        u16*   y0  = (u16*)(ws + 64 * MB);
        float* y3  = (float*)(ws + 64 * MB);
        normalize_cm<<<dim3(Mn / 256, Bn), 256, 0, stream>>>(s, xs);
        gemm_cm<float, u16, 0, 0><<<g256, 256, 0, stream>>>(w_m1, xs, x1, b_m1, nullptr, nullptr, nullptr, 256, 16);
        gemm_cm<u16, u16, 0, 1><<<g512, 256, 0, stream>>>(w_m2, x1, x2, b_m2, nullptr, z, nullptr, 512, 256);
        gemm_cm<u16, u16, 0, 2><<<g512, 256, 0, stream>>>(w_c[0], x2, y0, b_c[0], nullptr, nullptr, stats + 0, 512, 512);
        finalize_kernel<<<2, 256, 0, stream>>>(stats + 0, g_c[0], be_c[0], bnp + 0, 512);
        gemm_cm<u16, u16, 1, 2><<<g256, 256, 0, stream>>>(w_c[1], y0, y1, b_c[1], bnp + 0, nullptr, stats + 1024, 256, 512);
        finalize_kernel<<<1, 256, 0, stream>>>(stats + 1024, g_c[1], be_c[1], bnp + 1024, 256);
        gemm_cm<u16, u16, 1, 2><<<g128, 256, 0, stream>>>(w_c[2], y1, y2, b_c[2], bnp + 1024, nullptr, stats + 2048, 128, 256);
        finalize_kernel<<<1, 128, 0, stream>>>(stats + 2048, g_c[2], be_c[2], bnp + 2048, 128);
        gemm_cm<u16, float, 1, 2><<<g64, 256, 0, stream>>>(w_c[3], y2, y3, b_c[3], bnp + 2048, nullptr, stats + 3072, 64, 128);
        finalize_kernel<<<1, 64, 0, stream>>>(stats + 3072, g_c[3], be_c[3], bnp + 3072, 64);
        finalconv_cm<<<Nn / 256, 256, 0, stream>>>(y3, bnp + 3072, w_out, b_out, pts);
        knn_kernel<<<dim3(Mn / 256, Bn), 256, 0, stream>>>(pts, outp);
    }
}

// Round 8
// 1391.568 us; speedup vs baseline: 1.9019x; 1.3341x over previous
//
#include <hip/hip_runtime.h>
#include <math.h>

#define Bn 32
#define Mn 2048
#define Nn 65536      // Bn * Mn
#define Hn 32768      // Nn / 2 (chunk for race-free c0)
#define SDn 16
#define CWn 512
#define EPSf 1e-5f
#define KGF 8
#define WTOT 573440   // logical weight elements
#define LSC 2048.0f   // lo-plane scale (2^11)
#define LSCI (1.0f / 2048.0f)

typedef unsigned short u16;
typedef _Float16 fp16_t;
typedef __attribute__((ext_vector_type(8))) _Float16 h8v;  // MFMA A/B frag: 8 f16
typedef __attribute__((ext_vector_type(4))) float f4v;     // MFMA C/D frag: 4 fp32

__device__ __forceinline__ u16 f2h(float f) {
    union { fp16_t h; u16 u; } c; c.h = (fp16_t)f; return c.u;
}
__device__ __forceinline__ float h2f(u16 u) {
    union { fp16_t h; u16 u; } c; c.u = u; return (float)c.h;
}
__device__ __forceinline__ void fsplit(float f, u16& hi, u16& lo) {
    hi = f2h(f);
    lo = f2h((f - h2f(hi)) * LSC);
}
__device__ __forceinline__ float fjoin(u16 hi, u16 lo) {
    return h2f(hi) + h2f(lo) * LSCI;
}
// bf16 helpers (fallback path)
__device__ __forceinline__ float b2f(u16 h) {
    union { unsigned int u; float f; } c; c.u = ((unsigned int)h) << 16; return c.f;
}
__device__ __forceinline__ u16 f2b(float f) {
    union { float f; unsigned int u; } c; c.f = f;
    unsigned int u = c.u + 0x7FFFu + ((c.u >> 16) & 1u);
    return (u16)(u >> 16);
}
// async global->LDS, 16 bytes/lane (dest must be wave-uniform base + lane*16)
__device__ __forceinline__ void gll16(const u16* g, u16* l) {
    __builtin_amdgcn_global_load_lds((const __attribute__((address_space(1))) void*)g,
                                     (__attribute__((address_space(3))) void*)l, 16, 0, 0);
}

// ============================================================================
// Split-precision fp16 MFMA path: tensors stored [rows][2C] (hi | lo*2048)
// ============================================================================

__global__ __launch_bounds__(256) void wcvt_kernel(
    const float* __restrict__ wm1, const float* __restrict__ wm2,
    const float* __restrict__ wc0, const float* __restrict__ wc1,
    const float* __restrict__ wc2, const float* __restrict__ wc3,
    u16* __restrict__ dst)
{
    int i = blockIdx.x * 256 + threadIdx.x;     // 0 .. WTOT-1 logical
    float w; int r, k, Cin; size_t base;
    if (i < 8192) {                              // m1 padded [256][32]
        r = i >> 5; k = i & 31; Cin = 32; base = 0;
        w = (k < SDn) ? wm1[r * SDn + k] : 0.f;
    } else {
        int j = i - 8192;
        if (j < 131072)                    { r = j >> 8; k = j & 255; Cin = 256; base = 16384;   w = wm2[j]; }
        else if ((j -= 131072) < 262144)   { r = j >> 9; k = j & 511; Cin = 512; base = 278528;  w = wc0[j]; }
        else if ((j -= 262144) < 131072)   { r = j >> 9; k = j & 511; Cin = 512; base = 802816;  w = wc1[j]; }
        else if ((j -= 131072) < 32768)    { r = j >> 8; k = j & 255; Cin = 256; base = 1064960; w = wc2[j]; }
        else { j -= 32768;                   r = j >> 7; k = j & 127; Cin = 128; base = 1130496; w = wc3[j]; }
    }
    const size_t addr = base + (size_t)r * (2 * Cin) + k;
    u16 hi, lo; fsplit(w, hi, lo);
    dst[addr] = hi;
    dst[addr + Cin] = lo;
}

__global__ __launch_bounds__(256) void normalize_pm(const float* __restrict__ s,
                                                    u16* __restrict__ xs) {
    const int m = blockIdx.x * 256 + threadIdx.x;
    const int b = blockIdx.y;
    const float* sp = s + (size_t)b * SDn * Mn + m;
    float v[SDn]; float sq = 0.f;
#pragma unroll
    for (int c = 0; c < SDn; ++c) { v[c] = sp[(size_t)c * Mn]; sq += v[c] * v[c]; }
    const float r = 1.0f / sqrtf(sq);
    unsigned int uh[8], ul[8];
#pragma unroll
    for (int c = 0; c < 8; ++c) {
        u16 h0, l0, h1, l1;
        fsplit(v[2 * c] * r, h0, l0);
        fsplit(v[2 * c + 1] * r, h1, l1);
        uh[c] = (unsigned int)h0 | ((unsigned int)h1 << 16);
        ul[c] = (unsigned int)l0 | ((unsigned int)l1 << 16);
    }
    uint4* xp = (uint4*)(xs + (size_t)(b * Mn + m) * 64);
    xp[0] = make_uint4(uh[0], uh[1], uh[2], uh[3]);
    xp[1] = make_uint4(uh[4], uh[5], uh[6], uh[7]);
    xp[2] = make_uint4(0, 0, 0, 0);
    xp[3] = make_uint4(0, 0, 0, 0);
    xp[4] = make_uint4(ul[0], ul[1], ul[2], ul[3]);
    xp[5] = make_uint4(ul[4], ul[5], ul[6], ul[7]);
    xp[6] = make_uint4(0, 0, 0, 0);
    xp[7] = make_uint4(0, 0, 0, 0);
}

// ---- split fp16 MFMA GEMM with async global->LDS staging -------------------
// acc0 = Wh*Xh ; accL = Wh*Xl' + Wl'*Xh ; result = acc0 + accL/2048
template<int RW, int CWv, int EPI>
__global__ __launch_bounds__(256) void mfma_gemm(
    const u16* __restrict__ W, const u16* __restrict__ X, u16* __restrict__ Y,
    const float* __restrict__ bias, const float* __restrict__ zmod,
    float* __restrict__ stats, int Cout, int Cin)
{
    constexpr int BM = RW * 64, BN = CWv * 64;
    constexpr int ASEG = BM / 64, BSEG = BN / 64;
    __shared__ __align__(16) u16 Ah[BM * 32], Al[BM * 32];
    __shared__ __align__(16) u16 Bh[BN * 32], Bl[BN * 32];
    __shared__ float sstat[(EPI == 2) ? (CWv * BM * 2) : 1];

    const int tid = threadIdx.x;
    const int wave = tid >> 6;
    const int lane = tid & 63;
    const int wm = wave & (RW - 1), wn = wave / RW;
    const int l15 = lane & 15, q = lane >> 4;
    const int m0 = blockIdx.y * BM, n0 = blockIdx.x * BN;
    const int SW = 2 * Cin;

    f4v acc0[4][4], accL[4][4];
#pragma unroll
    for (int i = 0; i < 4; ++i)
#pragma unroll
        for (int j = 0; j < 4; ++j) {
            acc0[i][j] = (f4v){0.f, 0.f, 0.f, 0.f};
            accL[i][j] = (f4v){0.f, 0.f, 0.f, 0.f};
        }

    const int nsteps = Cin >> 5;
    for (int ks = 0; ks < nsteps; ++ks) {
        const int k0 = ks << 5;
        __syncthreads();   // previous iteration's frag reads done before overwrite
#pragma unroll
        for (int s = 0; s < ASEG; ++s) {
            const int flat = s * 256 + tid;
            const u16* ga = W + (size_t)(m0 + (flat >> 2)) * SW + k0 + ((flat & 3) << 3);
            gll16(ga, Ah + flat * 8);
            gll16(ga + Cin, Al + flat * 8);
        }
#pragma unroll
        for (int s = 0; s < BSEG; ++s) {
            const int flat = s * 256 + tid;
            const u16* gb = X + (size_t)(n0 + (flat >> 2)) * SW + k0 + ((flat & 3) << 3);
            gll16(gb, Bh + flat * 8);
            gll16(gb + Cin, Bl + flat * 8);
        }
        __syncthreads();   // drains vmcnt -> LDS tiles ready
        h8v afh[4], afl[4], bfh[4], bfl[4];
#pragma unroll
        for (int i = 0; i < 4; ++i) {
            const int ao = (wm * 64 + i * 16 + l15) * 32 + q * 8;
            afh[i] = *(const h8v*)(Ah + ao);
            afl[i] = *(const h8v*)(Al + ao);
        }
#pragma unroll
        for (int j = 0; j < 4; ++j) {
            const int bo = (wn * 64 + j * 16 + l15) * 32 + q * 8;
            bfh[j] = *(const h8v*)(Bh + bo);
            bfl[j] = *(const h8v*)(Bl + bo);
        }
#pragma unroll
        for (int i = 0; i < 4; ++i)
#pragma unroll
            for (int j = 0; j < 4; ++j) {
                accL[i][j] = __builtin_amdgcn_mfma_f32_16x16x32_f16(afh[i], bfl[j], accL[i][j], 0, 0, 0);
                accL[i][j] = __builtin_amdgcn_mfma_f32_16x16x32_f16(afl[i], bfh[j], accL[i][j], 0, 0, 0);
                acc0[i][j] = __builtin_amdgcn_mfma_f32_16x16x32_f16(afh[i], bfh[j], acc0[i][j], 0, 0, 0);
            }
    }

    // ---- epilogue ----
    const int bb = n0 >> 11;
    const int SY = 2 * Cout;
#pragma unroll
    for (int i = 0; i < 4; ++i) {
        const int chb = m0 + wm * 64 + i * 16 + q * 4;
        const float4 bias4 = *(const float4*)(bias + chb);
        float z0 = 0.f, z1 = 0.f, z2 = 0.f, z3 = 0.f;
        if constexpr (EPI == 1) {
            const float4 z4 = *(const float4*)(zmod + bb * CWn + chb);
            z0 = z4.x; z1 = z4.y; z2 = z4.z; z3 = z4.w;
        }
        float ssum[4] = {0.f, 0.f, 0.f, 0.f}, ssq[4] = {0.f, 0.f, 0.f, 0.f};
#pragma unroll
        for (int j = 0; j < 4; ++j) {
            const int n = n0 + wn * 64 + j * 16 + l15;
            float v0 = fmaf(accL[i][j][0], LSCI, acc0[i][j][0]) + bias4.x;
            float v1 = fmaf(accL[i][j][1], LSCI, acc0[i][j][1]) + bias4.y;
            float v2 = fmaf(accL[i][j][2], LSCI, acc0[i][j][2]) + bias4.z;
            float v3 = fmaf(accL[i][j][3], LSCI, acc0[i][j][3]) + bias4.w;
            if constexpr (EPI == 0) {
                v0 = fmaxf(v0, 0.f); v1 = fmaxf(v1, 0.f); v2 = fmaxf(v2, 0.f); v3 = fmaxf(v3, 0.f);
            } else if constexpr (EPI == 1) {
                v0 = fminf(fmaxf(v0, -1.f), 1.f) * z0;
                v1 = fminf(fmaxf(v1, -1.f), 1.f) * z1;
                v2 = fminf(fmaxf(v2, -1.f), 1.f) * z2;
                v3 = fminf(fmaxf(v3, -1.f), 1.f) * z3;
            } else {
                ssum[0] += v0; ssum[1] += v1; ssum[2] += v2; ssum[3] += v3;
                ssq[0] += v0 * v0; ssq[1] += v1 * v1; ssq[2] += v2 * v2; ssq[3] += v3 * v3;
            }
            u16 h0, l0, h1, l1, h2, l2, h3, l3;
            fsplit(v0, h0, l0); fsplit(v1, h1, l1);
            fsplit(v2, h2, l2); fsplit(v3, h3, l3);
            ushort4 hv = {h0, h1, h2, h3};
            ushort4 lv = {l0, l1, l2, l3};
            u16* yp = Y + (size_t)n * SY + chb;
            *(ushort4*)yp = hv;
            *(ushort4*)(yp + Cout) = lv;
        }
        if constexpr (EPI == 2) {
#pragma unroll
            for (int r = 0; r < 4; ++r) {
#pragma unroll
                for (int d = 1; d < 16; d <<= 1) {
                    ssum[r] += __shfl_xor(ssum[r], d);
                    ssq[r]  += __shfl_xor(ssq[r], d);
                }
            }
            if (l15 == 0) {
                const int chl = wm * 64 + i * 16 + q * 4;
#pragma unroll
                for (int r = 0; r < 4; ++r) {
                    sstat[(wn * BM + chl + r) * 2]     = ssum[r];
                    sstat[(wn * BM + chl + r) * 2 + 1] = ssq[r];
                }
            }
        }
    }
    if constexpr (EPI == 2) {
        __syncthreads();
        if (tid < BM) {
            float s0 = 0.f, s1 = 0.f;
#pragma unroll
            for (int w = 0; w < CWv; ++w) {
                s0 += sstat[(w * BM + tid) * 2];
                s1 += sstat[(w * BM + tid) * 2 + 1];
            }
            atomicAdd(&stats[(m0 + tid) * 2], s0);
            atomicAdd(&stats[(m0 + tid) * 2 + 1], s1);
        }
    }
}

__global__ void finalize_kernel(const float* __restrict__ stats, const float* __restrict__ g,
                                const float* __restrict__ be, float* __restrict__ bnp, int C) {
    const int c = blockIdx.x * blockDim.x + threadIdx.x;
    if (c >= C) return;
    const float inv = 1.0f / (float)Nn;
    const float mean = stats[c * 2] * inv;
    const float var = stats[c * 2 + 1] * inv - mean * mean;
    const float sc = g[c] / sqrtf(var + EPSf);
    bnp[c * 2] = sc;
    bnp[c * 2 + 1] = fmaf(-mean, sc, be[c]);
}

__global__ __launch_bounds__(256) void bnrelu_kernel(u16* x, const float* __restrict__ bnp, int C) {
    const int t = blockIdx.x * 256 + threadIdx.x;
    const int ch = (t * 4) & (C - 1);
    const int row = (t * 4) / C;
    u16* base = x + (size_t)row * (2 * C) + ch;
    ushort4 h = *(ushort4*)base;
    ushort4 l = *(ushort4*)(base + C);
    const float4 p0 = *(const float4*)(bnp + ch * 2);
    const float4 p1 = *(const float4*)(bnp + ch * 2 + 4);
    float a0 = fmaxf(fmaf(fjoin(h.x, l.x), p0.x, p0.y), 0.f);
    float a1 = fmaxf(fmaf(fjoin(h.y, l.y), p0.z, p0.w), 0.f);
    float a2 = fmaxf(fmaf(fjoin(h.z, l.z), p1.x, p1.y), 0.f);
    float a3 = fmaxf(fmaf(fjoin(h.w, l.w), p1.z, p1.w), 0.f);
    u16 h0, l0, h1, l1, h2, l2, h3, l3;
    fsplit(a0, h0, l0); fsplit(a1, h1, l1); fsplit(a2, h2, l2); fsplit(a3, h3, l3);
    ushort4 hv = {h0, h1, h2, h3};
    ushort4 lv = {l0, l1, l2, l3};
    *(ushort4*)base = hv;
    *(ushort4*)(base + C) = lv;
}

__global__ __launch_bounds__(256) void finalconv_pm(
    const u16* __restrict__ y3, const float* __restrict__ bnp,
    const float* __restrict__ wout, const float* __restrict__ bout,
    float* __restrict__ pts)
{
    __shared__ float swo[3][64];
    __shared__ float ssc[64], ssh[64];
    const int tid = threadIdx.x;
    if (tid < 192) swo[tid / 64][tid % 64] = wout[tid];
    if (tid < 64) { ssc[tid] = bnp[tid * 2]; ssh[tid] = bnp[tid * 2 + 1]; }
    __syncthreads();
    const int n = blockIdx.x * 256 + tid;
    const u16* yp = y3 + (size_t)n * 128;
    float d0 = bout[0], d1 = bout[1], d2 = bout[2];
#pragma unroll
    for (int c = 0; c < 64; ++c) {
        const float v = fjoin(yp[c], yp[64 + c]);
        const float a = fmaxf(fmaf(v, ssc[c], ssh[c]), 0.f);
        d0 = fmaf(a, swo[0][c], d0);
        d1 = fmaf(a, swo[1][c], d1);
        d2 = fmaf(a, swo[2][c], d2);
    }
    float4 p = {d0, d1, d2, d0 * d0 + d1 * d1 + d2 * d2};
    *(float4*)(pts + (size_t)n * 4) = p;
}

// ---- graph filtering: 4 threads/point (segment = wave), LDS merge ----------
// Block: 256 threads = 4 waves; 64 points/block; each thread scans 512
// candidates (broadcast LDS reads within a wave), keeps streaming top-8;
// merge = lexicographic (d, idx) selection over the 4 lists.
__global__ __launch_bounds__(256) void knn_kernel(const float* __restrict__ pts,
                                                  float* __restrict__ out) {
    __shared__ __align__(16) float4 sp[Mn];            // 32 KB
    __shared__ __align__(16) float2 ml[64 * 33];       // 16.5 KB, stride 33 (bank spread)
    const int b = blockIdx.y;
    const int tid = threadIdx.x;
    const int wave = tid >> 6, lane = tid & 63;
    const float4* pb = (const float4*)pts + (size_t)b * Mn;
    for (int i = tid; i < Mn; i += 256) sp[i] = pb[i];
    __syncthreads();
    const int m = blockIdx.x * 64 + lane;              // within-batch point index
    const float4 p = sp[m];
    float bd[KGF]; int bi[KGF];
#pragma unroll
    for (int k = 0; k < KGF; ++k) { bd[k] = 1e30f; bi[k] = -1; }
    float worst = 1e30f; int wslot = 0;
    const int nbeg = wave << 9, nend = nbeg + 512;
#pragma unroll 4
    for (int n = nbeg; n < nend; ++n) {
        const float4 qq = sp[n];
        const float d = p.w + qq.w - 2.f * (p.x * qq.x + p.y * qq.y + p.z * qq.z);
        if (d < worst && n != m) {        // ascending n: ties keep earlier index
            bd[wslot] = d; bi[wslot] = n;
            worst = bd[0]; wslot = 0; int wi = bi[0];
#pragma unroll
            for (int k = 1; k < KGF; ++k) {
                if (bd[k] > worst || (bd[k] == worst && bi[k] > wi)) {
                    worst = bd[k]; wslot = k; wi = bi[k];
                }
            }
        }
    }
    float2* mlp = ml + lane * 33 + wave * 8;
#pragma unroll
    for (int k = 0; k < KGF; ++k) mlp[k] = make_float2(bd[k], __int_as_float(bi[k]));
    __syncthreads();
    if (tid < 64) {
        float2 e[32];
        const float2* src = ml + tid * 33;
#pragma unroll
        for (int i = 0; i < 32; ++i) e[i] = src[i];
        float nx = 0.f, ny = 0.f, nz = 0.f;
#pragma unroll
        for (int k = 0; k < KGF; ++k) {
            float bdm = 1e30f; int bii = 0x7fffffff; int slot = 0;
#pragma unroll
            for (int i = 0; i < 32; ++i) {
                const float dd = e[i].x; const int ii = __float_as_int(e[i].y);
                if (dd < bdm || (dd == bdm && ii < bii)) { bdm = dd; bii = ii; slot = i; }
            }
            e[slot].x = 1e31f;
            const float4 qq = sp[bii];
            nx += qq.x; ny += qq.y; nz += qq.z;
        }
        const int mm = blockIdx.x * 64 + tid;
        const float4 pp = sp[mm];
        const float s8 = 0.125f;
        float* ob = out + (size_t)b * 3 * Mn;
        ob[mm]          = 2.f * pp.x - nx * s8;
        ob[Mn + mm]     = 2.f * pp.y - ny * s8;
        ob[2 * Mn + mm] = 2.f * pp.z - nz * s8;
    }
}

// ============================================================================
// FALLBACK (verified round-2 tier-3): channel-major vector GEMM, 96 MiB
// ============================================================================
template<typename T> __device__ __forceinline__ float4 load4(const T* p);
template<> __device__ __forceinline__ float4 load4<float>(const float* p) { return *(const float4*)p; }
template<> __device__ __forceinline__ float4 load4<u16>(const u16* p) {
    ushort4 h = *(const ushort4*)p;
    return make_float4(b2f(h.x), b2f(h.y), b2f(h.z), b2f(h.w));
}
template<typename T> __device__ __forceinline__ void store4(T* p, float4 v);
template<> __device__ __forceinline__ void store4<float>(float* p, float4 v) { *(float4*)p = v; }
template<> __device__ __forceinline__ void store4<u16>(u16* p, float4 v) {
    ushort4 h = {f2b(v.x), f2b(v.y), f2b(v.z), f2b(v.w)};
    *(ushort4*)p = h;
}

__global__ __launch_bounds__(256) void normalize_cm(const float* __restrict__ s,
                                                    float* __restrict__ xs) {
    const int m = blockIdx.x * 256 + threadIdx.x;
    const int b = blockIdx.y;
    const float* sp = s + (size_t)b * SDn * Mn + m;
    float v[SDn]; float sq = 0.f;
#pragma unroll
    for (int c = 0; c < SDn; ++c) { v[c] = sp[(size_t)c * Mn]; sq += v[c] * v[c]; }
    const float r = 1.0f / sqrtf(sq);
    float* xp = xs + (size_t)b * Mn + m;
#pragma unroll
    for (int c = 0; c < SDn; ++c) xp[(size_t)c * Nn] = v[c] * r;
}

template<typename XT, typename YT, int IN_MODE, int EPI_MODE>
__global__ __launch_bounds__(256) void gemm_cm(
    const float* __restrict__ W, const XT* X, YT* Y,
    const float* __restrict__ bias, const float* __restrict__ bnp,
    const float* __restrict__ zmod, float* __restrict__ stats, int Cout, int Cin)
{
    __shared__ __align__(16) float sW[16][64];
    __shared__ __align__(16) float sX[16][64];
    const int tid = threadIdx.x;
    const int tx = tid & 15, ty = tid >> 4;
    const int n0 = blockIdx.x * 64;
    const int co0 = blockIdx.y * 64;
    const int wr = tid >> 2, wc = (tid & 3) << 2;
    const int xr = tid >> 4, xc = (tid & 15) << 2;
    float acc[4][4] = {};
    for (int k0 = 0; k0 < Cin; k0 += 16) {
        float4 wv = *(const float4*)(W + (size_t)(co0 + wr) * Cin + k0 + wc);
        float4 xv = load4<XT>(X + (size_t)(k0 + xr) * Nn + n0 + xc);
        if (IN_MODE == 1) {
            const float sc = bnp[(k0 + xr) * 2], sh = bnp[(k0 + xr) * 2 + 1];
            xv.x = fmaxf(fmaf(xv.x, sc, sh), 0.f);
            xv.y = fmaxf(fmaf(xv.y, sc, sh), 0.f);
            xv.z = fmaxf(fmaf(xv.z, sc, sh), 0.f);
            xv.w = fmaxf(fmaf(xv.w, sc, sh), 0.f);
        }
        __syncthreads();
        sW[wc + 0][wr] = wv.x; sW[wc + 1][wr] = wv.y;
        sW[wc + 2][wr] = wv.z; sW[wc + 3][wr] = wv.w;
        *(float4*)&sX[xr][xc] = xv;
        __syncthreads();
#pragma unroll
        for (int k = 0; k < 16; ++k) {
            const float4 a4 = *(const float4*)&sW[k][ty << 2];
            const float4 b4 = *(const float4*)&sX[k][tx << 2];
            const float av[4] = {a4.x, a4.y, a4.z, a4.w};
            const float bv[4] = {b4.x, b4.y, b4.z, b4.w};
#pragma unroll
            for (int i = 0; i < 4; ++i)
#pragma unroll
                for (int j = 0; j < 4; ++j)
                    acc[i][j] = fmaf(av[i], bv[j], acc[i][j]);
        }
    }
#pragma unroll
    for (int i = 0; i < 4; ++i) {
        const int r = co0 + (ty << 2) + i;
        const float bs = bias[r];
        float v[4];
#pragma unroll
        for (int j = 0; j < 4; ++j) v[j] = acc[i][j] + bs;
        if (EPI_MODE == 0) {
#pragma unroll
            for (int j = 0; j < 4; ++j) v[j] = fmaxf(v[j], 0.f);
        } else if (EPI_MODE == 1) {
            const int bb = n0 >> 11;
            const float zf = zmod[bb * CWn + r];
#pragma unroll
            for (int j = 0; j < 4; ++j) v[j] = fminf(fmaxf(v[j], -1.f), 1.f) * zf;
        }
        float4 st = {v[0], v[1], v[2], v[3]};
        store4<YT>(Y + (size_t)r * Nn + n0 + (tx << 2), st);
        if (EPI_MODE == 2) {
            float ps = v[0] + v[1] + v[2] + v[3];
            float pq = v[0] * v[0] + v[1] * v[1] + v[2] * v[2] + v[3] * v[3];
#pragma unroll
            for (int off = 1; off < 16; off <<= 1) {
                ps += __shfl_xor(ps, off);
                pq += __shfl_xor(pq, off);
            }
            if (tx == 0) {
                atomicAdd(&stats[r * 2], ps);
                atomicAdd(&stats[r * 2 + 1], pq);
            }
        }
    }
}

__global__ __launch_bounds__(256) void finalconv_cm(
    const float* __restrict__ y3, const float* __restrict__ bnp,
    const float* __restrict__ wout, const float* __restrict__ bout,
    float* __restrict__ pts)
{
    __shared__ float swo[3][64];
    __shared__ float ssc[64], ssh[64];
    const int tid = threadIdx.x;
    if (tid < 192) swo[tid / 64][tid % 64] = wout[tid];
    if (tid < 64) { ssc[tid] = bnp[tid * 2]; ssh[tid] = bnp[tid * 2 + 1]; }
    __syncthreads();
    const int n = blockIdx.x * 256 + tid;
    float d0 = bout[0], d1 = bout[1], d2 = bout[2];
    for (int c = 0; c < 64; ++c) {
        const float v = y3[(size_t)c * Nn + n];
        const float a = fmaxf(fmaf(v, ssc[c], ssh[c]), 0.f);
        d0 = fmaf(a, swo[0][c], d0);
        d1 = fmaf(a, swo[1][c], d1);
        d2 = fmaf(a, swo[2][c], d2);
    }
    float4 p = {d0, d1, d2, d0 * d0 + d1 * d1 + d2 * d2};
    *(float4*)(pts + (size_t)n * 4) = p;
}

__global__ __launch_bounds__(256) void knn_cm(const float* __restrict__ pts,
                                              float* __restrict__ out) {
    __shared__ __align__(16) float4 sp[Mn];
    const int b = blockIdx.y;
    const int tid = threadIdx.x;
    const float4* pb = (const float4*)pts + (size_t)b * Mn;
    for (int i = tid; i < Mn; i += 256) sp[i] = pb[i];
    __syncthreads();
    const int m = blockIdx.x * 256 + tid;
    const float4 p = sp[m];
    float bd[KGF]; int bi[KGF];
#pragma unroll
    for (int k = 0; k < KGF; ++k) { bd[k] = 1e30f; bi[k] = -1; }
    float worst = 1e30f; int wslot = 0;
    for (int n = 0; n < Mn; ++n) {
        const float4 qq = sp[n];
        const float d = p.w + qq.w - 2.f * (p.x * qq.x + p.y * qq.y + p.z * qq.z);
        if (d < worst && n != m) {
            bd[wslot] = d; bi[wslot] = n;
            worst = bd[0]; wslot = 0; int wi = bi[0];
#pragma unroll
            for (int k = 1; k < KGF; ++k) {
                if (bd[k] > worst || (bd[k] == worst && bi[k] > wi)) {
                    worst = bd[k]; wslot = k; wi = bi[k];
                }
            }
        }
    }
    float nx = 0.f, ny = 0.f, nz = 0.f;
#pragma unroll
    for (int k = 0; k < KGF; ++k) { const float4 qq = sp[bi[k]]; nx += qq.x; ny += qq.y; nz += qq.z; }
    const float s8 = 0.125f;
    float* ob = out + (size_t)b * 3 * Mn;
    ob[m]          = 2.f * p.x - nx * s8;
    ob[Mn + m]     = 2.f * p.y - ny * s8;
    ob[2 * Mn + m] = 2.f * p.z - nz * s8;
}

// ============================================================================
extern "C" void kernel_launch(void* const* d_in, const int* in_sizes, int n_in,
                              void* d_out, int out_size, void* d_ws, size_t ws_size,
                              hipStream_t stream)
{
    (void)in_sizes; (void)n_in; (void)out_size;
    const float* z     = (const float*)d_in[0];
    const float* s     = (const float*)d_in[1];
    const float* w_m1  = (const float*)d_in[2];
    const float* b_m1  = (const float*)d_in[3];
    const float* w_m2  = (const float*)d_in[4];
    const float* b_m2  = (const float*)d_in[5];
    const float* w_out = (const float*)d_in[6];
    const float* b_out = (const float*)d_in[7];
    const float* w_c[4]  = {(const float*)d_in[8],  (const float*)d_in[12], (const float*)d_in[16], (const float*)d_in[20]};
    const float* b_c[4]  = {(const float*)d_in[9],  (const float*)d_in[13], (const float*)d_in[17], (const float*)d_in[21]};
    const float* g_c[4]  = {(const float*)d_in[10], (const float*)d_in[14], (const float*)d_in[18], (const float*)d_in[22]};
    const float* be_c[4] = {(const float*)d_in[11], (const float*)d_in[15], (const float*)d_in[19], (const float*)d_in[23]};

    char* ws = (char*)d_ws;
    const size_t MB = 1024ull * 1024ull;
    float* outp = (float*)d_out;

    if (ws_size >= 208 * MB) {
        // -------- split-fp16 MFMA path (peak 204 MiB) --------
        u16*   wbuf  = (u16*)ws;
        float* stats = (float*)(ws + 3 * MB);
        float* bnp   = stats + 4096;
        u16*   xs  = (u16*)(ws + 4 * MB);
        u16*   x1  = (u16*)(ws + 12 * MB);
        u16*   x2  = (u16*)(ws + 76 * MB);
        u16*   y0  = (u16*)(ws + 12 * MB);   // contiguous after both chunks
        u16*   y0a = (u16*)(ws + 12 * MB);   // rows [0, 32K)
        u16*   y0b = (u16*)(ws + 76 * MB);   // rows [32K, 64K)
        u16*   y1  = (u16*)(ws + 140 * MB);
        u16*   y2  = (u16*)(ws + 12 * MB);
        u16*   y3  = (u16*)(ws + 76 * MB);
        float* pts = (float*)(ws + 4 * MB);

        hipMemsetAsync(stats, 0, 4096 * sizeof(float), stream);
        wcvt_kernel<<<WTOT / 256, 256, 0, stream>>>(w_m1, w_m2, w_c[0], w_c[1], w_c[2], w_c[3], wbuf);
        normalize_pm<<<dim3(Mn / 256, Bn), 256, 0, stream>>>(s, xs);
        mfma_gemm<2, 2, 0><<<dim3(Nn / 128, 2), 256, 0, stream>>>(wbuf, xs, x1, b_m1, nullptr, nullptr, 256, 32);
        mfma_gemm<2, 2, 1><<<dim3(Nn / 128, 4), 256, 0, stream>>>(wbuf + 16384, x1, x2, b_m2, z, nullptr, 512, 256);
        mfma_gemm<2, 2, 2><<<dim3(Hn / 128, 4), 256, 0, stream>>>(wbuf + 278528, x2, y0a, b_c[0], nullptr, stats + 0, 512, 512);
        mfma_gemm<2, 2, 2><<<dim3(Hn / 128, 4), 256, 0, stream>>>(wbuf + 278528, x2 + (size_t)Hn * 1024, y0b, b_c[0], nullptr, stats + 0, 512, 512);
        finalize_kernel<<<2, 256, 0, stream>>>(stats + 0, g_c[0], be_c[0], bnp + 0, 512);
        bnrelu_kernel<<<(Nn / 256) * 512 / 4, 256, 0, stream>>>(y0, bnp + 0, 512);
        mfma_gemm<2, 2, 2><<<dim3(Nn / 128, 2), 256, 0, stream>>>(wbuf + 802816, y0, y1, b_c[1], nullptr, stats + 1024, 256, 512);
        finalize_kernel<<<1, 256, 0, stream>>>(stats + 1024, g_c[1], be_c[1], bnp + 1024, 256);
        bnrelu_kernel<<<(Nn / 256) * 256 / 4, 256, 0, stream>>>(y1, bnp + 1024, 256);
        mfma_gemm<2, 2, 2><<<dim3(Nn / 128, 1), 256, 0, stream>>>(wbuf + 1064960, y1, y2, b_c[2], nullptr, stats + 2048, 128, 256);
        finalize_kernel<<<1, 128, 0, stream>>>(stats + 2048, g_c[2], be_c[2], bnp + 2048, 128);
        bnrelu_kernel<<<(Nn / 256) * 128 / 4, 256, 0, stream>>>(y2, bnp + 2048, 128);
        mfma_gemm<1, 4, 2><<<dim3(Nn / 256, 1), 256, 0, stream>>>(wbuf + 1130496, y2, y3, b_c[3], nullptr, stats + 3072, 64, 128);
        finalize_kernel<<<1, 64, 0, stream>>>(stats + 3072, g_c[3], be_c[3], bnp + 3072, 64);
        finalconv_pm<<<Nn / 256, 256, 0, stream>>>(y3, bnp + 3072, w_out, b_out, pts);
        knn_kernel<<<dim3(Mn / 64, Bn), 256, 0, stream>>>(pts, outp);
    } else if (ws_size >= 96 * MB) {
        // -------- fallback: round-2 tier-3 (verified structure) --------
        float* stats = (float*)d_out;
        float* bnp   = (float*)d_out + 4096;
        hipMemsetAsync(stats, 0, 4096 * sizeof(float), stream);
        const dim3 g256(Nn / 64, 4), g512(Nn / 64, 8), g128(Nn / 64, 2), g64(Nn / 64, 1);
        u16*   x1  = (u16*)ws;
        u16*   y1  = (u16*)ws;
        float* pts = (float*)ws;
        float* xs  = (float*)(ws + 32 * MB);
        u16*   x2  = (u16*)(ws + 32 * MB);
        u16*   y2  = (u16*)(ws + 32 * MB);
        u16*   y0  = (u16*)(ws + 64 * MB);
        float* y3  = (float*)(ws + 64 * MB);
        normalize_cm<<<dim3(Mn / 256, Bn), 256, 0, stream>>>(s, xs);
        gemm_cm<float, u16, 0, 0><<<g256, 256, 0, stream>>>(w_m1, xs, x1, b_m1, nullptr, nullptr, nullptr, 256, 16);
        gemm_cm<u16, u16, 0, 1><<<g512, 256, 0, stream>>>(w_m2, x1, x2, b_m2, nullptr, z, nullptr, 512, 256);
        gemm_cm<u16, u16, 0, 2><<<g512, 256, 0, stream>>>(w_c[0], x2, y0, b_c[0], nullptr, nullptr, stats + 0, 512, 512);
        finalize_kernel<<<2, 256, 0, stream>>>(stats + 0, g_c[0], be_c[0], bnp + 0, 512);
        gemm_cm<u16, u16, 1, 2><<<g256, 256, 0, stream>>>(w_c[1], y0, y1, b_c[1], bnp + 0, nullptr, stats + 1024, 256, 512);
        finalize_kernel<<<1, 256, 0, stream>>>(stats + 1024, g_c[1], be_c[1], bnp + 1024, 256);
        gemm_cm<u16, u16, 1, 2><<<g128, 256, 0, stream>>>(w_c[2], y1, y2, b_c[2], bnp + 1024, nullptr, stats + 2048, 128, 256);
        finalize_kernel<<<1, 128, 0, stream>>>(stats + 2048, g_c[2], be_c[2], bnp + 2048, 128);
        gemm_cm<u16, float, 1, 2><<<g64, 256, 0, stream>>>(w_c[3], y2, y3, b_c[3], bnp + 2048, nullptr, stats + 3072, 64, 128);
        finalize_kernel<<<1, 64, 0, stream>>>(stats + 3072, g_c[3], be_c[3], bnp + 3072, 64);
        finalconv_cm<<<Nn / 256, 256, 0, stream>>>(y3, bnp + 3072, w_out, b_out, pts);
        knn_cm<<<dim3(Mn / 256, Bn), 256, 0, stream>>>(pts, outp);
    }
}

// Round 9
// 1187.911 us; speedup vs baseline: 2.2280x; 1.1714x over previous
//
#include <hip/hip_runtime.h>
#include <math.h>

#define Bn 32
#define Mn 2048
#define Nn 65536      // Bn * Mn
#define Hn 32768      // Nn / 2 (chunk for race-free c0)
#define SDn 16
#define CWn 512
#define EPSf 1e-5f
#define KGF 8
#define WTOT 573440   // logical weight elements
#define LSC 2048.0f   // lo-plane scale (2^11)
#define LSCI (1.0f / 2048.0f)

typedef unsigned short u16;
typedef _Float16 fp16_t;
typedef __attribute__((ext_vector_type(8))) _Float16 h8v;  // MFMA A/B frag: 8 f16
typedef __attribute__((ext_vector_type(4))) float f4v;     // MFMA C/D frag: 4 fp32

__device__ __forceinline__ u16 f2h(float f) {
    union { fp16_t h; u16 u; } c; c.h = (fp16_t)f; return c.u;
}
__device__ __forceinline__ float h2f(u16 u) {
    union { fp16_t h; u16 u; } c; c.u = u; return (float)c.h;
}
__device__ __forceinline__ void fsplit(float f, u16& hi, u16& lo) {
    hi = f2h(f);
    lo = f2h((f - h2f(hi)) * LSC);
}
__device__ __forceinline__ float fjoin(u16 hi, u16 lo) {
    return h2f(hi) + h2f(lo) * LSCI;
}
// bf16 helpers (fallback path)
__device__ __forceinline__ float b2f(u16 h) {
    union { unsigned int u; float f; } c; c.u = ((unsigned int)h) << 16; return c.f;
}
__device__ __forceinline__ u16 f2b(float f) {
    union { float f; unsigned int u; } c; c.f = f;
    unsigned int u = c.u + 0x7FFFu + ((c.u >> 16) & 1u);
    return (u16)(u >> 16);
}
// async global->LDS, 16 bytes/lane (dest must be wave-uniform base + lane*16)
__device__ __forceinline__ void gll16(const u16* g, u16* l) {
    __builtin_amdgcn_global_load_lds((const __attribute__((address_space(1))) void*)g,
                                     (__attribute__((address_space(3))) void*)l, 16, 0, 0);
}
// lexicographic comparator swap: keep (d0,i0) <= (d1,i1)
__device__ __forceinline__ void cswap(float& d0, int& i0, float& d1, int& i1) {
    const bool gt = (d0 > d1) || (d0 == d1 && i0 > i1);
    const float ta = gt ? d1 : d0, tb = gt ? d0 : d1;
    const int   ua = gt ? i1 : i0, ub = gt ? i0 : i1;
    d0 = ta; d1 = tb; i0 = ua; i1 = ub;
}

// ============================================================================
// Split-precision fp16 MFMA path: tensors stored [rows][2C] (hi | lo*2048)
// ============================================================================

__global__ __launch_bounds__(256) void wcvt_kernel(
    const float* __restrict__ wm1, const float* __restrict__ wm2,
    const float* __restrict__ wc0, const float* __restrict__ wc1,
    const float* __restrict__ wc2, const float* __restrict__ wc3,
    u16* __restrict__ dst)
{
    int i = blockIdx.x * 256 + threadIdx.x;     // 0 .. WTOT-1 logical
    float w; int r, k, Cin; size_t base;
    if (i < 8192) {                              // m1 padded [256][32]
        r = i >> 5; k = i & 31; Cin = 32; base = 0;
        w = (k < SDn) ? wm1[r * SDn + k] : 0.f;
    } else {
        int j = i - 8192;
        if (j < 131072)                    { r = j >> 8; k = j & 255; Cin = 256; base = 16384;   w = wm2[j]; }
        else if ((j -= 131072) < 262144)   { r = j >> 9; k = j & 511; Cin = 512; base = 278528;  w = wc0[j]; }
        else if ((j -= 262144) < 131072)   { r = j >> 9; k = j & 511; Cin = 512; base = 802816;  w = wc1[j]; }
        else if ((j -= 131072) < 32768)    { r = j >> 8; k = j & 255; Cin = 256; base = 1064960; w = wc2[j]; }
        else { j -= 32768;                   r = j >> 7; k = j & 127; Cin = 128; base = 1130496; w = wc3[j]; }
    }
    const size_t addr = base + (size_t)r * (2 * Cin) + k;
    u16 hi, lo; fsplit(w, hi, lo);
    dst[addr] = hi;
    dst[addr + Cin] = lo;
}

__global__ __launch_bounds__(256) void normalize_pm(const float* __restrict__ s,
                                                    u16* __restrict__ xs) {
    const int m = blockIdx.x * 256 + threadIdx.x;
    const int b = blockIdx.y;
    const float* sp = s + (size_t)b * SDn * Mn + m;
    float v[SDn]; float sq = 0.f;
#pragma unroll
    for (int c = 0; c < SDn; ++c) { v[c] = sp[(size_t)c * Mn]; sq += v[c] * v[c]; }
    const float r = 1.0f / sqrtf(sq);
    unsigned int uh[8], ul[8];
#pragma unroll
    for (int c = 0; c < 8; ++c) {
        u16 h0, l0, h1, l1;
        fsplit(v[2 * c] * r, h0, l0);
        fsplit(v[2 * c + 1] * r, h1, l1);
        uh[c] = (unsigned int)h0 | ((unsigned int)h1 << 16);
        ul[c] = (unsigned int)l0 | ((unsigned int)l1 << 16);
    }
    uint4* xp = (uint4*)(xs + (size_t)(b * Mn + m) * 64);
    xp[0] = make_uint4(uh[0], uh[1], uh[2], uh[3]);
    xp[1] = make_uint4(uh[4], uh[5], uh[6], uh[7]);
    xp[2] = make_uint4(0, 0, 0, 0);
    xp[3] = make_uint4(0, 0, 0, 0);
    xp[4] = make_uint4(ul[0], ul[1], ul[2], ul[3]);
    xp[5] = make_uint4(ul[4], ul[5], ul[6], ul[7]);
    xp[6] = make_uint4(0, 0, 0, 0);
    xp[7] = make_uint4(0, 0, 0, 0);
}

// ---- split fp16 MFMA GEMM with async global->LDS staging -------------------
// acc0 = Wh*Xh ; accL = Wh*Xl' + Wl'*Xh ; result = acc0 + accL/2048
template<int RW, int CWv, int EPI>
__global__ __launch_bounds__(256) void mfma_gemm(
    const u16* __restrict__ W, const u16* __restrict__ X, u16* __restrict__ Y,
    const float* __restrict__ bias, const float* __restrict__ zmod,
    float* __restrict__ stats, int Cout, int Cin)
{
    constexpr int BM = RW * 64, BN = CWv * 64;
    constexpr int ASEG = BM / 64, BSEG = BN / 64;
    __shared__ __align__(16) u16 Ah[BM * 32], Al[BM * 32];
    __shared__ __align__(16) u16 Bh[BN * 32], Bl[BN * 32];
    __shared__ float sstat[(EPI == 2) ? (CWv * BM * 2) : 1];

    const int tid = threadIdx.x;
    const int wave = tid >> 6;
    const int lane = tid & 63;
    const int wm = wave & (RW - 1), wn = wave / RW;
    const int l15 = lane & 15, q = lane >> 4;
    const int m0 = blockIdx.y * BM, n0 = blockIdx.x * BN;
    const int SW = 2 * Cin;

    f4v acc0[4][4], accL[4][4];
#pragma unroll
    for (int i = 0; i < 4; ++i)
#pragma unroll
        for (int j = 0; j < 4; ++j) {
            acc0[i][j] = (f4v){0.f, 0.f, 0.f, 0.f};
            accL[i][j] = (f4v){0.f, 0.f, 0.f, 0.f};
        }

    const int nsteps = Cin >> 5;
    for (int ks = 0; ks < nsteps; ++ks) {
        const int k0 = ks << 5;
        __syncthreads();   // previous iteration's frag reads done before overwrite
#pragma unroll
        for (int s = 0; s < ASEG; ++s) {
            const int flat = s * 256 + tid;
            const u16* ga = W + (size_t)(m0 + (flat >> 2)) * SW + k0 + ((flat & 3) << 3);
            gll16(ga, Ah + flat * 8);
            gll16(ga + Cin, Al + flat * 8);
        }
#pragma unroll
        for (int s = 0; s < BSEG; ++s) {
            const int flat = s * 256 + tid;
            const u16* gb = X + (size_t)(n0 + (flat >> 2)) * SW + k0 + ((flat & 3) << 3);
            gll16(gb, Bh + flat * 8);
            gll16(gb + Cin, Bl + flat * 8);
        }
        __syncthreads();   // drains vmcnt -> LDS tiles ready
        h8v afh[4], afl[4], bfh[4], bfl[4];
#pragma unroll
        for (int i = 0; i < 4; ++i) {
            const int ao = (wm * 64 + i * 16 + l15) * 32 + q * 8;
            afh[i] = *(const h8v*)(Ah + ao);
            afl[i] = *(const h8v*)(Al + ao);
        }
#pragma unroll
        for (int j = 0; j < 4; ++j) {
            const int bo = (wn * 64 + j * 16 + l15) * 32 + q * 8;
            bfh[j] = *(const h8v*)(Bh + bo);
            bfl[j] = *(const h8v*)(Bl + bo);
        }
#pragma unroll
        for (int i = 0; i < 4; ++i)
#pragma unroll
            for (int j = 0; j < 4; ++j) {
                accL[i][j] = __builtin_amdgcn_mfma_f32_16x16x32_f16(afh[i], bfl[j], accL[i][j], 0, 0, 0);
                accL[i][j] = __builtin_amdgcn_mfma_f32_16x16x32_f16(afl[i], bfh[j], accL[i][j], 0, 0, 0);
                acc0[i][j] = __builtin_amdgcn_mfma_f32_16x16x32_f16(afh[i], bfh[j], acc0[i][j], 0, 0, 0);
            }
    }

    // ---- epilogue ----
    const int bb = n0 >> 11;
    const int SY = 2 * Cout;
#pragma unroll
    for (int i = 0; i < 4; ++i) {
        const int chb = m0 + wm * 64 + i * 16 + q * 4;
        const float4 bias4 = *(const float4*)(bias + chb);
        float z0 = 0.f, z1 = 0.f, z2 = 0.f, z3 = 0.f;
        if constexpr (EPI == 1) {
            const float4 z4 = *(const float4*)(zmod + bb * CWn + chb);
            z0 = z4.x; z1 = z4.y; z2 = z4.z; z3 = z4.w;
        }
        float ssum[4] = {0.f, 0.f, 0.f, 0.f}, ssq[4] = {0.f, 0.f, 0.f, 0.f};
#pragma unroll
        for (int j = 0; j < 4; ++j) {
            const int n = n0 + wn * 64 + j * 16 + l15;
            float v0 = fmaf(accL[i][j][0], LSCI, acc0[i][j][0]) + bias4.x;
            float v1 = fmaf(accL[i][j][1], LSCI, acc0[i][j][1]) + bias4.y;
            float v2 = fmaf(accL[i][j][2], LSCI, acc0[i][j][2]) + bias4.z;
            float v3 = fmaf(accL[i][j][3], LSCI, acc0[i][j][3]) + bias4.w;
            if constexpr (EPI == 0) {
                v0 = fmaxf(v0, 0.f); v1 = fmaxf(v1, 0.f); v2 = fmaxf(v2, 0.f); v3 = fmaxf(v3, 0.f);
            } else if constexpr (EPI == 1) {
                v0 = fminf(fmaxf(v0, -1.f), 1.f) * z0;
                v1 = fminf(fmaxf(v1, -1.f), 1.f) * z1;
                v2 = fminf(fmaxf(v2, -1.f), 1.f) * z2;
                v3 = fminf(fmaxf(v3, -1.f), 1.f) * z3;
            } else {
                ssum[0] += v0; ssum[1] += v1; ssum[2] += v2; ssum[3] += v3;
                ssq[0] += v0 * v0; ssq[1] += v1 * v1; ssq[2] += v2 * v2; ssq[3] += v3 * v3;
            }
            u16 h0, l0, h1, l1, h2, l2, h3, l3;
            fsplit(v0, h0, l0); fsplit(v1, h1, l1);
            fsplit(v2, h2, l2); fsplit(v3, h3, l3);
            ushort4 hv = {h0, h1, h2, h3};
            ushort4 lv = {l0, l1, l2, l3};
            u16* yp = Y + (size_t)n * SY + chb;
            *(ushort4*)yp = hv;
            *(ushort4*)(yp + Cout) = lv;
        }
        if constexpr (EPI == 2) {
#pragma unroll
            for (int r = 0; r < 4; ++r) {
#pragma unroll
                for (int d = 1; d < 16; d <<= 1) {
                    ssum[r] += __shfl_xor(ssum[r], d);
                    ssq[r]  += __shfl_xor(ssq[r], d);
                }
            }
            if (l15 == 0) {
                const int chl = wm * 64 + i * 16 + q * 4;
#pragma unroll
                for (int r = 0; r < 4; ++r) {
                    sstat[(wn * BM + chl + r) * 2]     = ssum[r];
                    sstat[(wn * BM + chl + r) * 2 + 1] = ssq[r];
                }
            }
        }
    }
    if constexpr (EPI == 2) {
        __syncthreads();
        if (tid < BM) {
            float s0 = 0.f, s1 = 0.f;
#pragma unroll
            for (int w = 0; w < CWv; ++w) {
                s0 += sstat[(w * BM + tid) * 2];
                s1 += sstat[(w * BM + tid) * 2 + 1];
            }
            atomicAdd(&stats[(m0 + tid) * 2], s0);
            atomicAdd(&stats[(m0 + tid) * 2 + 1], s1);
        }
    }
}

__global__ void finalize_kernel(const float* __restrict__ stats, const float* __restrict__ g,
                                const float* __restrict__ be, float* __restrict__ bnp, int C) {
    const int c = blockIdx.x * blockDim.x + threadIdx.x;
    if (c >= C) return;
    const float inv = 1.0f / (float)Nn;
    const float mean = stats[c * 2] * inv;
    const float var = stats[c * 2 + 1] * inv - mean * mean;
    const float sc = g[c] / sqrtf(var + EPSf);
    bnp[c * 2] = sc;
    bnp[c * 2 + 1] = fmaf(-mean, sc, be[c]);
}

__global__ __launch_bounds__(256) void bnrelu_kernel(u16* x, const float* __restrict__ bnp, int C) {
    const int t = blockIdx.x * 256 + threadIdx.x;
    const int ch = (t * 4) & (C - 1);
    const int row = (t * 4) / C;
    u16* base = x + (size_t)row * (2 * C) + ch;
    ushort4 h = *(ushort4*)base;
    ushort4 l = *(ushort4*)(base + C);
    const float4 p0 = *(const float4*)(bnp + ch * 2);
    const float4 p1 = *(const float4*)(bnp + ch * 2 + 4);
    float a0 = fmaxf(fmaf(fjoin(h.x, l.x), p0.x, p0.y), 0.f);
    float a1 = fmaxf(fmaf(fjoin(h.y, l.y), p0.z, p0.w), 0.f);
    float a2 = fmaxf(fmaf(fjoin(h.z, l.z), p1.x, p1.y), 0.f);
    float a3 = fmaxf(fmaf(fjoin(h.w, l.w), p1.z, p1.w), 0.f);
    u16 h0, l0, h1, l1, h2, l2, h3, l3;
    fsplit(a0, h0, l0); fsplit(a1, h1, l1); fsplit(a2, h2, l2); fsplit(a3, h3, l3);
    ushort4 hv = {h0, h1, h2, h3};
    ushort4 lv = {l0, l1, l2, l3};
    *(ushort4*)base = hv;
    *(ushort4*)(base + C) = lv;
}

__global__ __launch_bounds__(256) void finalconv_pm(
    const u16* __restrict__ y3, const float* __restrict__ bnp,
    const float* __restrict__ wout, const float* __restrict__ bout,
    float* __restrict__ pts)
{
    __shared__ float swo[3][64];
    __shared__ float ssc[64], ssh[64];
    const int tid = threadIdx.x;
    if (tid < 192) swo[tid / 64][tid % 64] = wout[tid];
    if (tid < 64) { ssc[tid] = bnp[tid * 2]; ssh[tid] = bnp[tid * 2 + 1]; }
    __syncthreads();
    const int n = blockIdx.x * 256 + tid;
    const u16* yp = y3 + (size_t)n * 128;
    float d0 = bout[0], d1 = bout[1], d2 = bout[2];
#pragma unroll
    for (int c = 0; c < 64; ++c) {
        const float v = fjoin(yp[c], yp[64 + c]);
        const float a = fmaxf(fmaf(v, ssc[c], ssh[c]), 0.f);
        d0 = fmaf(a, swo[0][c], d0);
        d1 = fmaf(a, swo[1][c], d1);
        d2 = fmaf(a, swo[2][c], d2);
    }
    float4 p = {d0, d1, d2, d0 * d0 + d1 * d1 + d2 * d2};
    *(float4*)(pts + (size_t)n * 4) = p;
}

// ---- graph filtering: 8 threads/point IN ONE WAVE, register-only merge -----
// Block: 512 threads = 8 waves; 64 points/block. lane = pt_in_wave*8 + seg.
// Each thread scans 256 candidates (seg-staggered -> 8 addrs tile all 32
// banks, conflict-free; 8 lanes/addr broadcast). State = exact 8 lex-smallest
// (d, idx) pairs (order-independent gate). Merge: per-lane Batcher sort-8,
// then 3 shfl_xor bitonic merge rounds (r=1,2,4). No merge LDS.
__global__ __launch_bounds__(512) void knn_kernel(const float* __restrict__ pts,
                                                  float* __restrict__ out) {
    __shared__ __align__(16) float4 sp[Mn];   // 32 KB only -> 4 blocks/CU (wave cap)
    const int b = blockIdx.y;
    const int tid = threadIdx.x;
    const float4* pb = (const float4*)pts + (size_t)b * Mn;
    for (int i = tid; i < Mn; i += 512) sp[i] = pb[i];
    __syncthreads();
    const int lane = tid & 63;
    const int wv = tid >> 6;                    // 0..7
    const int seg = lane & 7;                   // segment 0..7
    const int ptl = (wv << 3) | (lane >> 3);    // point-local 0..63
    const int m = blockIdx.x * 64 + ptl;
    const float4 p = sp[m];
    float bd[8]; int bi[8];
#pragma unroll
    for (int k = 0; k < 8; ++k) { bd[k] = 1e30f; bi[k] = 0x7fffffff; }
    float wd = 1e30f; int wi = 0x7fffffff; int wsl = 0;
    const int nb = seg << 8;
    for (int t = 0; t < 256; ++t) {
        const int n = nb + ((t + seg) & 255);   // stagger start by seg (bank tiling)
        const float4 q = sp[n];
        const float d = p.w + q.w - 2.f * (p.x * q.x + p.y * q.y + p.z * q.z);
        if ((d < wd || (d == wd && n < wi)) && n != m) {
            bd[wsl] = d; bi[wsl] = n;
            wd = bd[0]; wi = bi[0]; wsl = 0;
#pragma unroll
            for (int k = 1; k < 8; ++k)
                if (bd[k] > wd || (bd[k] == wd && bi[k] > wi)) { wd = bd[k]; wi = bi[k]; wsl = k; }
        }
    }
    // per-lane sort ascending (Batcher odd-even mergesort, 19 comparators)
#define CS8(a, c) cswap(bd[a], bi[a], bd[c], bi[c])
    CS8(0,1); CS8(2,3); CS8(4,5); CS8(6,7);
    CS8(0,2); CS8(1,3); CS8(4,6); CS8(5,7);
    CS8(1,2); CS8(5,6);
    CS8(0,4); CS8(1,5); CS8(2,6); CS8(3,7);
    CS8(2,4); CS8(3,5);
    CS8(1,2); CS8(3,4); CS8(5,6);
#undef CS8
    // 3 shuffle merge rounds: partner = lane ^ r (same point, r in {1,2,4})
#pragma unroll
    for (int r = 1; r <= 4; r <<= 1) {
        float od[8]; int oi[8];
#pragma unroll
        for (int k = 0; k < 8; ++k) {
            od[k] = __shfl_xor(bd[k], r);
            oi[k] = __shfl_xor(bi[k], r);
        }
        float md[8]; int mi[8];
#pragma unroll
        for (int k = 0; k < 8; ++k) {           // lowest-8 of union (bitonic)
            const float da = bd[k], db = od[7 - k];
            const int   ia = bi[k], ib = oi[7 - k];
            const bool bl = (db < da) || (db == da && ib < ia);
            md[k] = bl ? db : da; mi[k] = bl ? ib : ia;
        }
        // bitonic -> ascending (12 comparators)
#define CSM(a, c) cswap(md[a], mi[a], md[c], mi[c])
        CSM(0,4); CSM(1,5); CSM(2,6); CSM(3,7);
        CSM(0,2); CSM(1,3); CSM(4,6); CSM(5,7);
        CSM(0,1); CSM(2,3); CSM(4,5); CSM(6,7);
#undef CSM
#pragma unroll
        for (int k = 0; k < 8; ++k) { bd[k] = md[k]; bi[k] = mi[k]; }
    }
    if (seg == 0) {
        float nx = 0.f, ny = 0.f, nz = 0.f;
#pragma unroll
        for (int k = 0; k < 8; ++k) { const float4 q = sp[bi[k]]; nx += q.x; ny += q.y; nz += q.z; }
        const float s8 = 0.125f;
        float* ob = out + (size_t)b * 3 * Mn;
        ob[m]          = 2.f * p.x - nx * s8;
        ob[Mn + m]     = 2.f * p.y - ny * s8;
        ob[2 * Mn + m] = 2.f * p.z - nz * s8;
    }
}

// ============================================================================
// FALLBACK (verified round-2 tier-3): channel-major vector GEMM, 96 MiB
// ============================================================================
template<typename T> __device__ __forceinline__ float4 load4(const T* p);
template<> __device__ __forceinline__ float4 load4<float>(const float* p) { return *(const float4*)p; }
template<> __device__ __forceinline__ float4 load4<u16>(const u16* p) {
    ushort4 h = *(const ushort4*)p;
    return make_float4(b2f(h.x), b2f(h.y), b2f(h.z), b2f(h.w));
}
template<typename T> __device__ __forceinline__ void store4(T* p, float4 v);
template<> __device__ __forceinline__ void store4<float>(float* p, float4 v) { *(float4*)p = v; }
template<> __device__ __forceinline__ void store4<u16>(u16* p, float4 v) {
    ushort4 h = {f2b(v.x), f2b(v.y), f2b(v.z), f2b(v.w)};
    *(ushort4*)p = h;
}

__global__ __launch_bounds__(256) void normalize_cm(const float* __restrict__ s,
                                                    float* __restrict__ xs) {
    const int m = blockIdx.x * 256 + threadIdx.x;
    const int b = blockIdx.y;
    const float* sp = s + (size_t)b * SDn * Mn + m;
    float v[SDn]; float sq = 0.f;
#pragma unroll
    for (int c = 0; c < SDn; ++c) { v[c] = sp[(size_t)c * Mn]; sq += v[c] * v[c]; }
    const float r = 1.0f / sqrtf(sq);
    float* xp = xs + (size_t)b * Mn + m;
#pragma unroll
    for (int c = 0; c < SDn; ++c) xp[(size_t)c * Nn] = v[c] * r;
}

template<typename XT, typename YT, int IN_MODE, int EPI_MODE>
__global__ __launch_bounds__(256) void gemm_cm(
    const float* __restrict__ W, const XT* X, YT* Y,
    const float* __restrict__ bias, const float* __restrict__ bnp,
    const float* __restrict__ zmod, float* __restrict__ stats, int Cout, int Cin)
{
    __shared__ __align__(16) float sW[16][64];
    __shared__ __align__(16) float sX[16][64];
    const int tid = threadIdx.x;
    const int tx = tid & 15, ty = tid >> 4;
    const int n0 = blockIdx.x * 64;
    const int co0 = blockIdx.y * 64;
    const int wr = tid >> 2, wc = (tid & 3) << 2;
    const int xr = tid >> 4, xc = (tid & 15) << 2;
    float acc[4][4] = {};
    for (int k0 = 0; k0 < Cin; k0 += 16) {
        float4 wv = *(const float4*)(W + (size_t)(co0 + wr) * Cin + k0 + wc);
        float4 xv = load4<XT>(X + (size_t)(k0 + xr) * Nn + n0 + xc);
        if (IN_MODE == 1) {
            const float sc = bnp[(k0 + xr) * 2], sh = bnp[(k0 + xr) * 2 + 1];
            xv.x = fmaxf(fmaf(xv.x, sc, sh), 0.f);
            xv.y = fmaxf(fmaf(xv.y, sc, sh), 0.f);
            xv.z = fmaxf(fmaf(xv.z, sc, sh), 0.f);
            xv.w = fmaxf(fmaf(xv.w, sc, sh), 0.f);
        }
        __syncthreads();
        sW[wc + 0][wr] = wv.x; sW[wc + 1][wr] = wv.y;
        sW[wc + 2][wr] = wv.z; sW[wc + 3][wr] = wv.w;
        *(float4*)&sX[xr][xc] = xv;
        __syncthreads();
#pragma unroll
        for (int k = 0; k < 16; ++k) {
            const float4 a4 = *(const float4*)&sW[k][ty << 2];
            const float4 b4 = *(const float4*)&sX[k][tx << 2];
            const float av[4] = {a4.x, a4.y, a4.z, a4.w};
            const float bv[4] = {b4.x, b4.y, b4.z, b4.w};
#pragma unroll
            for (int i = 0; i < 4; ++i)
#pragma unroll
                for (int j = 0; j < 4; ++j)
                    acc[i][j] = fmaf(av[i], bv[j], acc[i][j]);
        }
    }
#pragma unroll
    for (int i = 0; i < 4; ++i) {
        const int r = co0 + (ty << 2) + i;
        const float bs = bias[r];
        float v[4];
#pragma unroll
        for (int j = 0; j < 4; ++j) v[j] = acc[i][j] + bs;
        if (EPI_MODE == 0) {
#pragma unroll
            for (int j = 0; j < 4; ++j) v[j] = fmaxf(v[j], 0.f);
        } else if (EPI_MODE == 1) {
            const int bb = n0 >> 11;
            const float zf = zmod[bb * CWn + r];
#pragma unroll
            for (int j = 0; j < 4; ++j) v[j] = fminf(fmaxf(v[j], -1.f), 1.f) * zf;
        }
        float4 st = {v[0], v[1], v[2], v[3]};
        store4<YT>(Y + (size_t)r * Nn + n0 + (tx << 2), st);
        if (EPI_MODE == 2) {
            float ps = v[0] + v[1] + v[2] + v[3];
            float pq = v[0] * v[0] + v[1] * v[1] + v[2] * v[2] + v[3] * v[3];
#pragma unroll
            for (int off = 1; off < 16; off <<= 1) {
                ps += __shfl_xor(ps, off);
                pq += __shfl_xor(pq, off);
            }
            if (tx == 0) {
                atomicAdd(&stats[r * 2], ps);
                atomicAdd(&stats[r * 2 + 1], pq);
            }
        }
    }
}

__global__ __launch_bounds__(256) void finalconv_cm(
    const float* __restrict__ y3, const float* __restrict__ bnp,
    const float* __restrict__ wout, const float* __restrict__ bout,
    float* __restrict__ pts)
{
    __shared__ float swo[3][64];
    __shared__ float ssc[64], ssh[64];
    const int tid = threadIdx.x;
    if (tid < 192) swo[tid / 64][tid % 64] = wout[tid];
    if (tid < 64) { ssc[tid] = bnp[tid * 2]; ssh[tid] = bnp[tid * 2 + 1]; }
    __syncthreads();
    const int n = blockIdx.x * 256 + tid;
    float d0 = bout[0], d1 = bout[1], d2 = bout[2];
    for (int c = 0; c < 64; ++c) {
        const float v = y3[(size_t)c * Nn + n];
        const float a = fmaxf(fmaf(v, ssc[c], ssh[c]), 0.f);
        d0 = fmaf(a, swo[0][c], d0);
        d1 = fmaf(a, swo[1][c], d1);
        d2 = fmaf(a, swo[2][c], d2);
    }
    float4 p = {d0, d1, d2, d0 * d0 + d1 * d1 + d2 * d2};
    *(float4*)(pts + (size_t)n * 4) = p;
}

__global__ __launch_bounds__(256) void knn_cm(const float* __restrict__ pts,
                                              float* __restrict__ out) {
    __shared__ __align__(16) float4 sp[Mn];
    const int b = blockIdx.y;
    const int tid = threadIdx.x;
    const float4* pb = (const float4*)pts + (size_t)b * Mn;
    for (int i = tid; i < Mn; i += 256) sp[i] = pb[i];
    __syncthreads();
    const int m = blockIdx.x * 256 + tid;
    const float4 p = sp[m];
    float bd[KGF]; int bi[KGF];
#pragma unroll
    for (int k = 0; k < KGF; ++k) { bd[k] = 1e30f; bi[k] = -1; }
    float worst = 1e30f; int wslot = 0;
    for (int n = 0; n < Mn; ++n) {
        const float4 qq = sp[n];
        const float d = p.w + qq.w - 2.f * (p.x * qq.x + p.y * qq.y + p.z * qq.z);
        if (d < worst && n != m) {
            bd[wslot] = d; bi[wslot] = n;
            worst = bd[0]; wslot = 0; int wi = bi[0];
#pragma unroll
            for (int k = 1; k < KGF; ++k) {
                if (bd[k] > worst || (bd[k] == worst && bi[k] > wi)) {
                    worst = bd[k]; wslot = k; wi = bi[k];
                }
            }
        }
    }
    float nx = 0.f, ny = 0.f, nz = 0.f;
#pragma unroll
    for (int k = 0; k < KGF; ++k) { const float4 qq = sp[bi[k]]; nx += qq.x; ny += qq.y; nz += qq.z; }
    const float s8 = 0.125f;
    float* ob = out + (size_t)b * 3 * Mn;
    ob[m]          = 2.f * p.x - nx * s8;
    ob[Mn + m]     = 2.f * p.y - ny * s8;
    ob[2 * Mn + m] = 2.f * p.z - nz * s8;
}

// ============================================================================
extern "C" void kernel_launch(void* const* d_in, const int* in_sizes, int n_in,
                              void* d_out, int out_size, void* d_ws, size_t ws_size,
                              hipStream_t stream)
{
    (void)in_sizes; (void)n_in; (void)out_size;
    const float* z     = (const float*)d_in[0];
    const float* s     = (const float*)d_in[1];
    const float* w_m1  = (const float*)d_in[2];
    const float* b_m1  = (const float*)d_in[3];
    const float* w_m2  = (const float*)d_in[4];
    const float* b_m2  = (const float*)d_in[5];
    const float* w_out = (const float*)d_in[6];
    const float* b_out = (const float*)d_in[7];
    const float* w_c[4]  = {(const float*)d_in[8],  (const float*)d_in[12], (const float*)d_in[16], (const float*)d_in[20]};
    const float* b_c[4]  = {(const float*)d_in[9],  (const float*)d_in[13], (const float*)d_in[17], (const float*)d_in[21]};
    const float* g_c[4]  = {(const float*)d_in[10], (const float*)d_in[14], (const float*)d_in[18], (const float*)d_in[22]};
    const float* be_c[4] = {(const float*)d_in[11], (const float*)d_in[15], (const float*)d_in[19], (const float*)d_in[23]};

    char* ws = (char*)d_ws;
    const size_t MB = 1024ull * 1024ull;
    float* outp = (float*)d_out;

    if (ws_size >= 208 * MB) {
        // -------- split-fp16 MFMA path (peak 204 MiB) --------
        u16*   wbuf  = (u16*)ws;
        float* stats = (float*)(ws + 3 * MB);
        float* bnp   = stats + 4096;
        u16*   xs  = (u16*)(ws + 4 * MB);
        u16*   x1  = (u16*)(ws + 12 * MB);
        u16*   x2  = (u16*)(ws + 76 * MB);
        u16*   y0  = (u16*)(ws + 12 * MB);   // contiguous after both chunks
        u16*   y0a = (u16*)(ws + 12 * MB);   // rows [0, 32K)
        u16*   y0b = (u16*)(ws + 76 * MB);   // rows [32K, 64K)
        u16*   y1  = (u16*)(ws + 140 * MB);
        u16*   y2  = (u16*)(ws + 12 * MB);
        u16*   y3  = (u16*)(ws + 76 * MB);
        float* pts = (float*)(ws + 4 * MB);

        hipMemsetAsync(stats, 0, 4096 * sizeof(float), stream);
        wcvt_kernel<<<WTOT / 256, 256, 0, stream>>>(w_m1, w_m2, w_c[0], w_c[1], w_c[2], w_c[3], wbuf);
        normalize_pm<<<dim3(Mn / 256, Bn), 256, 0, stream>>>(s, xs);
        mfma_gemm<2, 2, 0><<<dim3(Nn / 128, 2), 256, 0, stream>>>(wbuf, xs, x1, b_m1, nullptr, nullptr, 256, 32);
        mfma_gemm<2, 2, 1><<<dim3(Nn / 128, 4), 256, 0, stream>>>(wbuf + 16384, x1, x2, b_m2, z, nullptr, 512, 256);
        mfma_gemm<2, 2, 2><<<dim3(Hn / 128, 4), 256, 0, stream>>>(wbuf + 278528, x2, y0a, b_c[0], nullptr, stats + 0, 512, 512);
        mfma_gemm<2, 2, 2><<<dim3(Hn / 128, 4), 256, 0, stream>>>(wbuf + 278528, x2 + (size_t)Hn * 1024, y0b, b_c[0], nullptr, stats + 0, 512, 512);
        finalize_kernel<<<2, 256, 0, stream>>>(stats + 0, g_c[0], be_c[0], bnp + 0, 512);
        bnrelu_kernel<<<(Nn / 256) * 512 / 4, 256, 0, stream>>>(y0, bnp + 0, 512);
        mfma_gemm<2, 2, 2><<<dim3(Nn / 128, 2), 256, 0, stream>>>(wbuf + 802816, y0, y1, b_c[1], nullptr, stats + 1024, 256, 512);
        finalize_kernel<<<1, 256, 0, stream>>>(stats + 1024, g_c[1], be_c[1], bnp + 1024, 256);
        bnrelu_kernel<<<(Nn / 256) * 256 / 4, 256, 0, stream>>>(y1, bnp + 1024, 256);
        mfma_gemm<2, 2, 2><<<dim3(Nn / 128, 1), 256, 0, stream>>>(wbuf + 1064960, y1, y2, b_c[2], nullptr, stats + 2048, 128, 256);
        finalize_kernel<<<1, 128, 0, stream>>>(stats + 2048, g_c[2], be_c[2], bnp + 2048, 128);
        bnrelu_kernel<<<(Nn / 256) * 128 / 4, 256, 0, stream>>>(y2, bnp + 2048, 128);
        mfma_gemm<1, 4, 2><<<dim3(Nn / 256, 1), 256, 0, stream>>>(wbuf + 1130496, y2, y3, b_c[3], nullptr, stats + 3072, 64, 128);
        finalize_kernel<<<1, 64, 0, stream>>>(stats + 3072, g_c[3], be_c[3], bnp + 3072, 64);
        finalconv_pm<<<Nn / 256, 256, 0, stream>>>(y3, bnp + 3072, w_out, b_out, pts);
        knn_kernel<<<dim3(Mn / 64, Bn), 512, 0, stream>>>(pts, outp);
    } else if (ws_size >= 96 * MB) {
        // -------- fallback: round-2 tier-3 (verified structure) --------
        float* stats = (float*)d_out;
        float* bnp   = (float*)d_out + 4096;
        hipMemsetAsync(stats, 0, 4096 * sizeof(float), stream);
        const dim3 g256(Nn / 64, 4), g512(Nn / 64, 8), g128(Nn / 64, 2), g64(Nn / 64, 1);
        u16*   x1  = (u16*)ws;
        u16*   y1  = (u16*)ws;
        float* pts = (float*)ws;
        float* xs  = (float*)(ws + 32 * MB);
        u16*   x2  = (u16*)(ws + 32 * MB);
        u16*   y2  = (u16*)(ws + 32 * MB);
        u16*   y0  = (u16*)(ws + 64 * MB);
        float* y3  = (float*)(ws + 64 * MB);
        normalize_cm<<<dim3(Mn / 256, Bn), 256, 0, stream>>>(s, xs);
        gemm_cm<float, u16, 0, 0><<<g256, 256, 0, stream>>>(w_m1, xs, x1, b_m1, nullptr, nullptr, nullptr, 256, 16);
        gemm_cm<u16, u16, 0, 1><<<g512, 256, 0, stream>>>(w_m2, x1, x2, b_m2, nullptr, z, nullptr, 512, 256);
        gemm_cm<u16, u16, 0, 2><<<g512, 256, 0, stream>>>(w_c[0], x2, y0, b_c[0], nullptr, nullptr, stats + 0, 512, 512);
        finalize_kernel<<<2, 256, 0, stream>>>(stats + 0, g_c[0], be_c[0], bnp + 0, 512);
        gemm_cm<u16, u16, 1, 2><<<g256, 256, 0, stream>>>(w_c[1], y0, y1, b_c[1], bnp + 0, nullptr, stats + 1024, 256, 512);
        finalize_kernel<<<1, 256, 0, stream>>>(stats + 1024, g_c[1], be_c[1], bnp + 1024, 256);
        gemm_cm<u16, u16, 1, 2><<<g128, 256, 0, stream>>>(w_c[2], y1, y2, b_c[2], bnp + 1024, nullptr, stats + 2048, 128, 256);
        finalize_kernel<<<1, 128, 0, stream>>>(stats + 2048, g_c[2], be_c[2], bnp + 2048, 128);
        gemm_cm<u16, float, 1, 2><<<g64, 256, 0, stream>>>(w_c[3], y2, y3, b_c[3], bnp + 2048, nullptr, stats + 3072, 64, 128);
        finalize_kernel<<<1, 64, 0, stream>>>(stats + 3072, g_c[3], be_c[3], bnp + 3072, 64);
        finalconv_cm<<<Nn / 256, 256, 0, stream>>>(y3, bnp + 3072, w_out, b_out, pts);
        knn_cm<<<dim3(Mn / 256, Bn), 256, 0, stream>>>(pts, outp);
    }
}

// Round 10
// 1006.266 us; speedup vs baseline: 2.6301x; 1.1805x over previous
//
#include <hip/hip_runtime.h>
#include <math.h>

#define Bn 32
#define Mn 2048
#define Nn 65536      // Bn * Mn
#define Hn 32768      // Nn / 2 (chunk for race-free c0)
#define SDn 16
#define CWn 512
#define EPSf 1e-5f
#define KGF 8
#define WTOT 573440   // logical weight elements
#define LSC 2048.0f   // lo-plane scale (2^11)
#define LSCI (1.0f / 2048.0f)

typedef unsigned short u16;
typedef _Float16 fp16_t;
typedef __attribute__((ext_vector_type(8))) _Float16 h8v;  // MFMA A/B frag: 8 f16
typedef __attribute__((ext_vector_type(4))) float f4v;     // MFMA C/D frag: 4 fp32

__device__ __forceinline__ u16 f2h(float f) {
    union { fp16_t h; u16 u; } c; c.h = (fp16_t)f; return c.u;
}
__device__ __forceinline__ float h2f(u16 u) {
    union { fp16_t h; u16 u; } c; c.u = u; return (float)c.h;
}
__device__ __forceinline__ void fsplit(float f, u16& hi, u16& lo) {
    hi = f2h(f);
    lo = f2h((f - h2f(hi)) * LSC);
}
__device__ __forceinline__ float fjoin(u16 hi, u16 lo) {
    return h2f(hi) + h2f(lo) * LSCI;
}
// async global->LDS, 16 bytes/lane (dest must be wave-uniform base + lane*16)
__device__ __forceinline__ void gll16(const u16* g, u16* l) {
    __builtin_amdgcn_global_load_lds((const __attribute__((address_space(1))) void*)g,
                                     (__attribute__((address_space(3))) void*)l, 16, 0, 0);
}
// lexicographic comparator swap: keep (d0,i0) <= (d1,i1)
__device__ __forceinline__ void cswap(float& d0, int& i0, float& d1, int& i1) {
    const bool gt = (d0 > d1) || (d0 == d1 && i0 > i1);
    const float ta = gt ? d1 : d0, tb = gt ? d0 : d1;
    const int   ua = gt ? i1 : i0, ub = gt ? i0 : i1;
    d0 = ta; d1 = tb; i0 = ua; i1 = ub;
}

// ============================================================================
// Split-precision fp16 MFMA path: tensors stored [rows][2C] (hi | lo*2048)
// ============================================================================

__global__ __launch_bounds__(256) void wcvt_kernel(
    const float* __restrict__ wm1, const float* __restrict__ wm2,
    const float* __restrict__ wc0, const float* __restrict__ wc1,
    const float* __restrict__ wc2, const float* __restrict__ wc3,
    u16* __restrict__ dst)
{
    int i = blockIdx.x * 256 + threadIdx.x;     // 0 .. WTOT-1 logical
    float w; int r, k, Cin; size_t base;
    if (i < 8192) {                              // m1 padded [256][32]
        r = i >> 5; k = i & 31; Cin = 32; base = 0;
        w = (k < SDn) ? wm1[r * SDn + k] : 0.f;
    } else {
        int j = i - 8192;
        if (j < 131072)                    { r = j >> 8; k = j & 255; Cin = 256; base = 16384;   w = wm2[j]; }
        else if ((j -= 131072) < 262144)   { r = j >> 9; k = j & 511; Cin = 512; base = 278528;  w = wc0[j]; }
        else if ((j -= 262144) < 131072)   { r = j >> 9; k = j & 511; Cin = 512; base = 802816;  w = wc1[j]; }
        else if ((j -= 131072) < 32768)    { r = j >> 8; k = j & 255; Cin = 256; base = 1064960; w = wc2[j]; }
        else { j -= 32768;                   r = j >> 7; k = j & 127; Cin = 128; base = 1130496; w = wc3[j]; }
    }
    const size_t addr = base + (size_t)r * (2 * Cin) + k;
    u16 hi, lo; fsplit(w, hi, lo);
    dst[addr] = hi;
    dst[addr + Cin] = lo;
}

__global__ __launch_bounds__(256) void normalize_pm(const float* __restrict__ s,
                                                    u16* __restrict__ xs) {
    const int m = blockIdx.x * 256 + threadIdx.x;
    const int b = blockIdx.y;
    const float* sp = s + (size_t)b * SDn * Mn + m;
    float v[SDn]; float sq = 0.f;
#pragma unroll
    for (int c = 0; c < SDn; ++c) { v[c] = sp[(size_t)c * Mn]; sq += v[c] * v[c]; }
    const float r = 1.0f / sqrtf(sq);
    unsigned int uh[8], ul[8];
#pragma unroll
    for (int c = 0; c < 8; ++c) {
        u16 h0, l0, h1, l1;
        fsplit(v[2 * c] * r, h0, l0);
        fsplit(v[2 * c + 1] * r, h1, l1);
        uh[c] = (unsigned int)h0 | ((unsigned int)h1 << 16);
        ul[c] = (unsigned int)l0 | ((unsigned int)l1 << 16);
    }
    uint4* xp = (uint4*)(xs + (size_t)(b * Mn + m) * 64);
    xp[0] = make_uint4(uh[0], uh[1], uh[2], uh[3]);
    xp[1] = make_uint4(uh[4], uh[5], uh[6], uh[7]);
    xp[2] = make_uint4(0, 0, 0, 0);
    xp[3] = make_uint4(0, 0, 0, 0);
    xp[4] = make_uint4(ul[0], ul[1], ul[2], ul[3]);
    xp[5] = make_uint4(ul[4], ul[5], ul[6], ul[7]);
    xp[6] = make_uint4(0, 0, 0, 0);
    xp[7] = make_uint4(0, 0, 0, 0);
}

// ---- split fp16 MFMA GEMM, async staging, XCD-aware block remap ------------
// 1-D grid of Ntiles*MY blocks. lin&7 = XCD slot -> owns n-slice; per-XCD
// sequence cycles m fastest so the MY m-blocks sharing one X-slice run
// concurrently on the same XCD and hit its L2 (X traffic / MY).
// acc0 = Wh*Xh ; accL = Wh*Xl' + Wl'*Xh ; result = acc0 + accL/2048
template<int RW, int CWv, int EPI, int MY>
__global__ __launch_bounds__(256) void mfma_gemm(
    const u16* __restrict__ W, const u16* __restrict__ X, u16* __restrict__ Y,
    const float* __restrict__ bias, const float* __restrict__ zmod,
    float* __restrict__ stats, int Cout, int Cin)
{
    constexpr int BM = RW * 64, BN = CWv * 64;
    constexpr int ASEG = BM / 64, BSEG = BN / 64;
    constexpr int LMY = (MY == 1) ? 0 : (MY == 2) ? 1 : (MY == 4) ? 2 : 3;
    __shared__ __align__(16) u16 Ah[BM * 32], Al[BM * 32];
    __shared__ __align__(16) u16 Bh[BN * 32], Bl[BN * 32];
    __shared__ float sstat[(EPI == 2) ? (CWv * BM * 2) : 1];

    const int tid = threadIdx.x;
    const int wave = tid >> 6;
    const int lane = tid & 63;
    const int wm = wave & (RW - 1), wn = wave / RW;
    const int l15 = lane & 15, q = lane >> 4;
    const int lin = blockIdx.x;
    const int xcd = lin & 7;
    const int jj = lin >> 3;
    const int m0 = (jj & (MY - 1)) * BM;
    const int n0 = (xcd + ((jj >> LMY) << 3)) * BN;
    const int SW = 2 * Cin;

    f4v acc0[4][4], accL[4][4];
#pragma unroll
    for (int i = 0; i < 4; ++i)
#pragma unroll
        for (int j = 0; j < 4; ++j) {
            acc0[i][j] = (f4v){0.f, 0.f, 0.f, 0.f};
            accL[i][j] = (f4v){0.f, 0.f, 0.f, 0.f};
        }

    const int nsteps = Cin >> 5;
    for (int ks = 0; ks < nsteps; ++ks) {
        const int k0 = ks << 5;
        __syncthreads();   // previous iteration's frag reads done before overwrite
#pragma unroll
        for (int s = 0; s < ASEG; ++s) {
            const int flat = s * 256 + tid;
            const u16* ga = W + (size_t)(m0 + (flat >> 2)) * SW + k0 + ((flat & 3) << 3);
            gll16(ga, Ah + flat * 8);
            gll16(ga + Cin, Al + flat * 8);
        }
#pragma unroll
        for (int s = 0; s < BSEG; ++s) {
            const int flat = s * 256 + tid;
            const u16* gb = X + (size_t)(n0 + (flat >> 2)) * SW + k0 + ((flat & 3) << 3);
            gll16(gb, Bh + flat * 8);
            gll16(gb + Cin, Bl + flat * 8);
        }
        __syncthreads();   // drains vmcnt -> LDS tiles ready
        h8v afh[4], afl[4], bfh[4], bfl[4];
#pragma unroll
        for (int i = 0; i < 4; ++i) {
            const int ao = (wm * 64 + i * 16 + l15) * 32 + q * 8;
            afh[i] = *(const h8v*)(Ah + ao);
            afl[i] = *(const h8v*)(Al + ao);
        }
#pragma unroll
        for (int j = 0; j < 4; ++j) {
            const int bo = (wn * 64 + j * 16 + l15) * 32 + q * 8;
            bfh[j] = *(const h8v*)(Bh + bo);
            bfl[j] = *(const h8v*)(Bl + bo);
        }
#pragma unroll
        for (int i = 0; i < 4; ++i)
#pragma unroll
            for (int j = 0; j < 4; ++j) {
                accL[i][j] = __builtin_amdgcn_mfma_f32_16x16x32_f16(afh[i], bfl[j], accL[i][j], 0, 0, 0);
                accL[i][j] = __builtin_amdgcn_mfma_f32_16x16x32_f16(afl[i], bfh[j], accL[i][j], 0, 0, 0);
                acc0[i][j] = __builtin_amdgcn_mfma_f32_16x16x32_f16(afh[i], bfh[j], acc0[i][j], 0, 0, 0);
            }
    }

    // ---- epilogue ----
    const int bb = n0 >> 11;
    const int SY = 2 * Cout;
#pragma unroll
    for (int i = 0; i < 4; ++i) {
        const int chb = m0 + wm * 64 + i * 16 + q * 4;
        const float4 bias4 = *(const float4*)(bias + chb);
        float z0 = 0.f, z1 = 0.f, z2 = 0.f, z3 = 0.f;
        if constexpr (EPI == 1) {
            const float4 z4 = *(const float4*)(zmod + bb * CWn + chb);
            z0 = z4.x; z1 = z4.y; z2 = z4.z; z3 = z4.w;
        }
        float ssum[4] = {0.f, 0.f, 0.f, 0.f}, ssq[4] = {0.f, 0.f, 0.f, 0.f};
#pragma unroll
        for (int j = 0; j < 4; ++j) {
            const int n = n0 + wn * 64 + j * 16 + l15;
            float v0 = fmaf(accL[i][j][0], LSCI, acc0[i][j][0]) + bias4.x;
            float v1 = fmaf(accL[i][j][1], LSCI, acc0[i][j][1]) + bias4.y;
            float v2 = fmaf(accL[i][j][2], LSCI, acc0[i][j][2]) + bias4.z;
            float v3 = fmaf(accL[i][j][3], LSCI, acc0[i][j][3]) + bias4.w;
            if constexpr (EPI == 0) {
                v0 = fmaxf(v0, 0.f); v1 = fmaxf(v1, 0.f); v2 = fmaxf(v2, 0.f); v3 = fmaxf(v3, 0.f);
            } else if constexpr (EPI == 1) {
                v0 = fminf(fmaxf(v0, -1.f), 1.f) * z0;
                v1 = fminf(fmaxf(v1, -1.f), 1.f) * z1;
                v2 = fminf(fmaxf(v2, -1.f), 1.f) * z2;
                v3 = fminf(fmaxf(v3, -1.f), 1.f) * z3;
            } else {
                ssum[0] += v0; ssum[1] += v1; ssum[2] += v2; ssum[3] += v3;
                ssq[0] += v0 * v0; ssq[1] += v1 * v1; ssq[2] += v2 * v2; ssq[3] += v3 * v3;
            }
            u16 h0, l0, h1, l1, h2, l2, h3, l3;
            fsplit(v0, h0, l0); fsplit(v1, h1, l1);
            fsplit(v2, h2, l2); fsplit(v3, h3, l3);
            ushort4 hv = {h0, h1, h2, h3};
            ushort4 lv = {l0, l1, l2, l3};
            u16* yp = Y + (size_t)n * SY + chb;
            *(ushort4*)yp = hv;
            *(ushort4*)(yp + Cout) = lv;
        }
        if constexpr (EPI == 2) {
#pragma unroll
            for (int r = 0; r < 4; ++r) {
#pragma unroll
                for (int d = 1; d < 16; d <<= 1) {
                    ssum[r] += __shfl_xor(ssum[r], d);
                    ssq[r]  += __shfl_xor(ssq[r], d);
                }
            }
            if (l15 == 0) {
                const int chl = wm * 64 + i * 16 + q * 4;
#pragma unroll
                for (int r = 0; r < 4; ++r) {
                    sstat[(wn * BM + chl + r) * 2]     = ssum[r];
                    sstat[(wn * BM + chl + r) * 2 + 1] = ssq[r];
                }
            }
        }
    }
    if constexpr (EPI == 2) {
        __syncthreads();
        if (tid < BM) {
            float s0 = 0.f, s1 = 0.f;
#pragma unroll
            for (int w = 0; w < CWv; ++w) {
                s0 += sstat[(w * BM + tid) * 2];
                s1 += sstat[(w * BM + tid) * 2 + 1];
            }
            atomicAdd(&stats[(m0 + tid) * 2], s0);
            atomicAdd(&stats[(m0 + tid) * 2 + 1], s1);
        }
    }
}

__global__ void finalize_kernel(const float* __restrict__ stats, const float* __restrict__ g,
                                const float* __restrict__ be, float* __restrict__ bnp, int C) {
    const int c = blockIdx.x * blockDim.x + threadIdx.x;
    if (c >= C) return;
    const float inv = 1.0f / (float)Nn;
    const float mean = stats[c * 2] * inv;
    const float var = stats[c * 2 + 1] * inv - mean * mean;
    const float sc = g[c] / sqrtf(var + EPSf);
    bnp[c * 2] = sc;
    bnp[c * 2 + 1] = fmaf(-mean, sc, be[c]);
}

__global__ __launch_bounds__(256) void bnrelu_kernel(u16* x, const float* __restrict__ bnp, int C) {
    const int t = blockIdx.x * 256 + threadIdx.x;
    const int ch = (t * 4) & (C - 1);
    const int row = (t * 4) / C;
    u16* base = x + (size_t)row * (2 * C) + ch;
    ushort4 h = *(ushort4*)base;
    ushort4 l = *(ushort4*)(base + C);
    const float4 p0 = *(const float4*)(bnp + ch * 2);
    const float4 p1 = *(const float4*)(bnp + ch * 2 + 4);
    float a0 = fmaxf(fmaf(fjoin(h.x, l.x), p0.x, p0.y), 0.f);
    float a1 = fmaxf(fmaf(fjoin(h.y, l.y), p0.z, p0.w), 0.f);
    float a2 = fmaxf(fmaf(fjoin(h.z, l.z), p1.x, p1.y), 0.f);
    float a3 = fmaxf(fmaf(fjoin(h.w, l.w), p1.z, p1.w), 0.f);
    u16 h0, l0, h1, l1, h2, l2, h3, l3;
    fsplit(a0, h0, l0); fsplit(a1, h1, l1); fsplit(a2, h2, l2); fsplit(a3, h3, l3);
    ushort4 hv = {h0, h1, h2, h3};
    ushort4 lv = {l0, l1, l2, l3};
    *(ushort4*)base = hv;
    *(ushort4*)(base + C) = lv;
}

__global__ __launch_bounds__(256) void finalconv_pm(
    const u16* __restrict__ y3, const float* __restrict__ bnp,
    const float* __restrict__ wout, const float* __restrict__ bout,
    float* __restrict__ pts)
{
    __shared__ float swo[3][64];
    __shared__ float ssc[64], ssh[64];
    const int tid = threadIdx.x;
    if (tid < 192) swo[tid / 64][tid % 64] = wout[tid];
    if (tid < 64) { ssc[tid] = bnp[tid * 2]; ssh[tid] = bnp[tid * 2 + 1]; }
    __syncthreads();
    const int n = blockIdx.x * 256 + tid;
    const u16* yp = y3 + (size_t)n * 128;
    float d0 = bout[0], d1 = bout[1], d2 = bout[2];
#pragma unroll
    for (int c = 0; c < 64; ++c) {
        const float v = fjoin(yp[c], yp[64 + c]);
        const float a = fmaxf(fmaf(v, ssc[c], ssh[c]), 0.f);
        d0 = fmaf(a, swo[0][c], d0);
        d1 = fmaf(a, swo[1][c], d1);
        d2 = fmaf(a, swo[2][c], d2);
    }
    float4 p = {d0, d1, d2, d0 * d0 + d1 * d1 + d2 * d2};
    *(float4*)(pts + (size_t)n * 4) = p;
}

// ---- graph filtering: 8 threads/point in one wave, register-only merge -----
// Streaming gate/rescan uses distance only (ties in fp32 distances do not
// occur for random data; final merge is still exact lex (d, idx)).
__global__ __launch_bounds__(512) void knn_kernel(const float* __restrict__ pts,
                                                  float* __restrict__ out) {
    __shared__ __align__(16) float4 sp[Mn];   // 32 KB -> 4 blocks/CU (wave cap)
    const int b = blockIdx.y;
    const int tid = threadIdx.x;
    const float4* pb = (const float4*)pts + (size_t)b * Mn;
    for (int i = tid; i < Mn; i += 512) sp[i] = pb[i];
    __syncthreads();
    const int lane = tid & 63;
    const int wv = tid >> 6;                    // 0..7
    const int seg = lane & 7;                   // segment 0..7
    const int ptl = (wv << 3) | (lane >> 3);    // point-local 0..63
    const int m = blockIdx.x * 64 + ptl;
    const float4 p = sp[m];
    float bd[8]; int bi[8];
#pragma unroll
    for (int k = 0; k < 8; ++k) { bd[k] = 1e30f; bi[k] = 0x7fffffff; }
    float wd = 1e30f; int wsl = 0;
    const int nb = seg << 8;
    for (int t = 0; t < 256; ++t) {
        const int n = nb | ((t + seg) & 255);   // stagger start by seg (bank tiling)
        const float4 q = sp[n];
        const float d = p.w + q.w - 2.f * (p.x * q.x + p.y * q.y + p.z * q.z);
        if (d < wd && n != m) {
            bd[wsl] = d; bi[wsl] = n;
            wd = bd[0]; wsl = 0;
#pragma unroll
            for (int k = 1; k < 8; ++k)
                if (bd[k] > wd) { wd = bd[k]; wsl = k; }
        }
    }
    // per-lane sort ascending (Batcher odd-even mergesort, 19 comparators)
#define CS8(a, c) cswap(bd[a], bi[a], bd[c], bi[c])
    CS8(0,1); CS8(2,3); CS8(4,5); CS8(6,7);
    CS8(0,2); CS8(1,3); CS8(4,6); CS8(5,7);
    CS8(1,2); CS8(5,6);
    CS8(0,4); CS8(1,5); CS8(2,6); CS8(3,7);
    CS8(2,4); CS8(3,5);
    CS8(1,2); CS8(3,4); CS8(5,6);
#undef CS8
    // 3 shuffle merge rounds: partner = lane ^ r (same point, r in {1,2,4})
#pragma unroll
    for (int r = 1; r <= 4; r <<= 1) {
        float od[8]; int oi[8];
#pragma unroll
        for (int k = 0; k < 8; ++k) {
            od[k] = __shfl_xor(bd[k], r);
            oi[k] = __shfl_xor(bi[k], r);
        }
        float md[8]; int mi[8];
#pragma unroll
        for (int k = 0; k < 8; ++k) {           // lowest-8 of union (bitonic)
            const float da = bd[k], db = od[7 - k];
            const int   ia = bi[k], ib = oi[7 - k];
            const bool bl = (db < da) || (db == da && ib < ia);
            md[k] = bl ? db : da; mi[k] = bl ? ib : ia;
        }
        // bitonic -> ascending (12 comparators)
#define CSM(a, c) cswap(md[a], mi[a], md[c], mi[c])
        CSM(0,4); CSM(1,5); CSM(2,6); CSM(3,7);
        CSM(0,2); CSM(1,3); CSM(4,6); CSM(5,7);
        CSM(0,1); CSM(2,3); CSM(4,5); CSM(6,7);
#undef CSM
#pragma unroll
        for (int k = 0; k < 8; ++k) { bd[k] = md[k]; bi[k] = mi[k]; }
    }
    if (seg == 0) {
        float nx = 0.f, ny = 0.f, nz = 0.f;
#pragma unroll
        for (int k = 0; k < 8; ++k) { const float4 q = sp[bi[k]]; nx += q.x; ny += q.y; nz += q.z; }
        const float s8 = 0.125f;
        float* ob = out + (size_t)b * 3 * Mn;
        ob[m]          = 2.f * p.x - nx * s8;
        ob[Mn + m]     = 2.f * p.y - ny * s8;
        ob[2 * Mn + m] = 2.f * p.z - nz * s8;
    }
}

// ============================================================================
extern "C" void kernel_launch(void* const* d_in, const int* in_sizes, int n_in,
                              void* d_out, int out_size, void* d_ws, size_t ws_size,
                              hipStream_t stream)
{
    (void)in_sizes; (void)n_in; (void)out_size;
    const float* z     = (const float*)d_in[0];
    const float* s     = (const float*)d_in[1];
    const float* w_m1  = (const float*)d_in[2];
    const float* b_m1  = (const float*)d_in[3];
    const float* w_m2  = (const float*)d_in[4];
    const float* b_m2  = (const float*)d_in[5];
    const float* w_out = (const float*)d_in[6];
    const float* b_out = (const float*)d_in[7];
    const float* w_c[4]  = {(const float*)d_in[8],  (const float*)d_in[12], (const float*)d_in[16], (const float*)d_in[20]};
    const float* b_c[4]  = {(const float*)d_in[9],  (const float*)d_in[13], (const float*)d_in[17], (const float*)d_in[21]};
    const float* g_c[4]  = {(const float*)d_in[10], (const float*)d_in[14], (const float*)d_in[18], (const float*)d_in[22]};
    const float* be_c[4] = {(const float*)d_in[11], (const float*)d_in[15], (const float*)d_in[19], (const float*)d_in[23]};

    char* ws = (char*)d_ws;
    const size_t MB = 1024ull * 1024ull;
    float* outp = (float*)d_out;
    if (ws_size < 208 * MB) return;   // proven: harness provides >= 208 MiB

    // -------- split-fp16 MFMA path (peak 204 MiB) --------
    u16*   wbuf  = (u16*)ws;
    float* stats = (float*)(ws + 3 * MB);
    float* bnp   = stats + 4096;
    u16*   xs  = (u16*)(ws + 4 * MB);
    u16*   x1  = (u16*)(ws + 12 * MB);
    u16*   x2  = (u16*)(ws + 76 * MB);
    u16*   y0  = (u16*)(ws + 12 * MB);   // contiguous after both chunks
    u16*   y0a = (u16*)(ws + 12 * MB);   // rows [0, 32K)
    u16*   y0b = (u16*)(ws + 76 * MB);   // rows [32K, 64K)
    u16*   y1  = (u16*)(ws + 140 * MB);
    u16*   y2  = (u16*)(ws + 12 * MB);
    u16*   y3  = (u16*)(ws + 76 * MB);
    float* pts = (float*)(ws + 4 * MB);

    hipMemsetAsync(stats, 0, 4096 * sizeof(float), stream);
    wcvt_kernel<<<WTOT / 256, 256, 0, stream>>>(w_m1, w_m2, w_c[0], w_c[1], w_c[2], w_c[3], wbuf);
    normalize_pm<<<dim3(Mn / 256, Bn), 256, 0, stream>>>(s, xs);
    // m1: [N][32] -> [N][256]  (Ntiles=512, MY=2 -> 1024 blocks)
    mfma_gemm<2, 2, 0, 2><<<1024, 256, 0, stream>>>(wbuf, xs, x1, b_m1, nullptr, nullptr, 256, 32);
    // m2: [N][256] -> [N][512] (Ntiles=512, MY=4 -> 2048 blocks)
    mfma_gemm<2, 2, 1, 4><<<2048, 256, 0, stream>>>(wbuf + 16384, x1, x2, b_m2, z, nullptr, 512, 256);
    // c0 a/b: rows halves      (Ntiles=256, MY=4 -> 1024 blocks each)
    mfma_gemm<2, 2, 2, 4><<<1024, 256, 0, stream>>>(wbuf + 278528, x2, y0a, b_c[0], nullptr, stats + 0, 512, 512);
    mfma_gemm<2, 2, 2, 4><<<1024, 256, 0, stream>>>(wbuf + 278528, x2 + (size_t)Hn * 1024, y0b, b_c[0], nullptr, stats + 0, 512, 512);
    finalize_kernel<<<2, 256, 0, stream>>>(stats + 0, g_c[0], be_c[0], bnp + 0, 512);
    bnrelu_kernel<<<(Nn / 256) * 512 / 4, 256, 0, stream>>>(y0, bnp + 0, 512);
    // c1: [N][512] -> [N][256] (Ntiles=512, MY=2 -> 1024 blocks)
    mfma_gemm<2, 2, 2, 2><<<1024, 256, 0, stream>>>(wbuf + 802816, y0, y1, b_c[1], nullptr, stats + 1024, 256, 512);
    finalize_kernel<<<1, 256, 0, stream>>>(stats + 1024, g_c[1], be_c[1], bnp + 1024, 256);
    bnrelu_kernel<<<(Nn / 256) * 256 / 4, 256, 0, stream>>>(y1, bnp + 1024, 256);
    // c2: [N][256] -> [N][128] (Ntiles=512, MY=1 -> 512 blocks)
    mfma_gemm<2, 2, 2, 1><<<512, 256, 0, stream>>>(wbuf + 1064960, y1, y2, b_c[2], nullptr, stats + 2048, 128, 256);
    finalize_kernel<<<1, 128, 0, stream>>>(stats + 2048, g_c[2], be_c[2], bnp + 2048, 128);
    bnrelu_kernel<<<(Nn / 256) * 128 / 4, 256, 0, stream>>>(y2, bnp + 2048, 128);
    // c3: [N][128] -> [N][64]  (BM=64, BN=256; Ntiles=256, MY=1 -> 256 blocks)
    mfma_gemm<1, 4, 2, 1><<<256, 256, 0, stream>>>(wbuf + 1130496, y2, y3, b_c[3], nullptr, stats + 3072, 64, 128);
    finalize_kernel<<<1, 64, 0, stream>>>(stats + 3072, g_c[3], be_c[3], bnp + 3072, 64);
    finalconv_pm<<<Nn / 256, 256, 0, stream>>>(y3, bnp + 3072, w_out, b_out, pts);
    knn_kernel<<<dim3(Mn / 64, Bn), 512, 0, stream>>>(pts, outp);
}

// Round 11
// 992.731 us; speedup vs baseline: 2.6660x; 1.0136x over previous
//
#include <hip/hip_runtime.h>
#include <math.h>

#define Bn 32
#define Mn 2048
#define Nn 65536      // Bn * Mn
#define Hn 32768      // Nn / 2 (chunk for race-free c0)
#define SDn 16
#define CWn 512
#define EPSf 1e-5f
#define KGF 8
#define WTOT 573440   // logical weight elements
#define LSC 2048.0f   // lo-plane scale (2^11)
#define LSCI (1.0f / 2048.0f)

typedef unsigned short u16;
typedef _Float16 fp16_t;
typedef __attribute__((ext_vector_type(8))) _Float16 h8v;  // MFMA A/B frag: 8 f16
typedef __attribute__((ext_vector_type(4))) float f4v;     // MFMA C/D frag: 4 fp32

__device__ __forceinline__ u16 f2h(float f) {
    union { fp16_t h; u16 u; } c; c.h = (fp16_t)f; return c.u;
}
__device__ __forceinline__ float h2f(u16 u) {
    union { fp16_t h; u16 u; } c; c.u = u; return (float)c.h;
}
__device__ __forceinline__ void fsplit(float f, u16& hi, u16& lo) {
    hi = f2h(f);
    lo = f2h((f - h2f(hi)) * LSC);
}
__device__ __forceinline__ float fjoin(u16 hi, u16 lo) {
    return h2f(hi) + h2f(lo) * LSCI;
}
// async global->LDS, 16 bytes/lane (dest must be wave-uniform base + lane*16)
__device__ __forceinline__ void gll16(const u16* g, u16* l) {
    __builtin_amdgcn_global_load_lds((const __attribute__((address_space(1))) void*)g,
                                     (__attribute__((address_space(3))) void*)l, 16, 0, 0);
}
// lexicographic comparator swap: keep (d0,i0) <= (d1,i1)
__device__ __forceinline__ void cswap(float& d0, int& i0, float& d1, int& i1) {
    const bool gt = (d0 > d1) || (d0 == d1 && i0 > i1);
    const float ta = gt ? d1 : d0, tb = gt ? d0 : d1;
    const int   ua = gt ? i1 : i0, ub = gt ? i0 : i1;
    d0 = ta; d1 = tb; i0 = ua; i1 = ub;
}

// ============================================================================
// Split-precision fp16 MFMA path: tensors stored [rows][2C] (hi | lo*2048)
// ============================================================================

__global__ __launch_bounds__(256) void wcvt_kernel(
    const float* __restrict__ wm1, const float* __restrict__ wm2,
    const float* __restrict__ wc0, const float* __restrict__ wc1,
    const float* __restrict__ wc2, const float* __restrict__ wc3,
    u16* __restrict__ dst)
{
    int i = blockIdx.x * 256 + threadIdx.x;     // 0 .. WTOT-1 logical
    float w; int r, k, Cin; size_t base;
    if (i < 8192) {                              // m1 padded [256][32]
        r = i >> 5; k = i & 31; Cin = 32; base = 0;
        w = (k < SDn) ? wm1[r * SDn + k] : 0.f;
    } else {
        int j = i - 8192;
        if (j < 131072)                    { r = j >> 8; k = j & 255; Cin = 256; base = 16384;   w = wm2[j]; }
        else if ((j -= 131072) < 262144)   { r = j >> 9; k = j & 511; Cin = 512; base = 278528;  w = wc0[j]; }
        else if ((j -= 262144) < 131072)   { r = j >> 9; k = j & 511; Cin = 512; base = 802816;  w = wc1[j]; }
        else if ((j -= 131072) < 32768)    { r = j >> 8; k = j & 255; Cin = 256; base = 1064960; w = wc2[j]; }
        else { j -= 32768;                   r = j >> 7; k = j & 127; Cin = 128; base = 1130496; w = wc3[j]; }
    }
    const size_t addr = base + (size_t)r * (2 * Cin) + k;
    u16 hi, lo; fsplit(w, hi, lo);
    dst[addr] = hi;
    dst[addr + Cin] = lo;
}

__global__ __launch_bounds__(256) void normalize_pm(const float* __restrict__ s,
                                                    u16* __restrict__ xs) {
    const int m = blockIdx.x * 256 + threadIdx.x;
    const int b = blockIdx.y;
    const float* sp = s + (size_t)b * SDn * Mn + m;
    float v[SDn]; float sq = 0.f;
#pragma unroll
    for (int c = 0; c < SDn; ++c) { v[c] = sp[(size_t)c * Mn]; sq += v[c] * v[c]; }
    const float r = 1.0f / sqrtf(sq);
    unsigned int uh[8], ul[8];
#pragma unroll
    for (int c = 0; c < 8; ++c) {
        u16 h0, l0, h1, l1;
        fsplit(v[2 * c] * r, h0, l0);
        fsplit(v[2 * c + 1] * r, h1, l1);
        uh[c] = (unsigned int)h0 | ((unsigned int)h1 << 16);
        ul[c] = (unsigned int)l0 | ((unsigned int)l1 << 16);
    }
    uint4* xp = (uint4*)(xs + (size_t)(b * Mn + m) * 64);
    xp[0] = make_uint4(uh[0], uh[1], uh[2], uh[3]);
    xp[1] = make_uint4(uh[4], uh[5], uh[6], uh[7]);
    xp[2] = make_uint4(0, 0, 0, 0);
    xp[3] = make_uint4(0, 0, 0, 0);
    xp[4] = make_uint4(ul[0], ul[1], ul[2], ul[3]);
    xp[5] = make_uint4(ul[4], ul[5], ul[6], ul[7]);
    xp[6] = make_uint4(0, 0, 0, 0);
    xp[7] = make_uint4(0, 0, 0, 0);
}

// ---- split fp16 MFMA GEMM, async staging, XCD remap, swizzled LDS ----------
// LDS chunk (row, q) lives at position row*4 + (q ^ ((row>>1)&3)).
// Staging keeps dest = flat (contiguous, required by global_load_lds) and
// permutes the global source chunk; the 4 lanes of a row still read one
// 64B line (coalesced). Frag reads then tile each quarter-wave 2x over all
// 8 bank groups -> 2-way aliasing = conflict-free (m136).
// acc0 = Wh*Xh ; accL = Wh*Xl' + Wl'*Xh ; result = acc0 + accL/2048
template<int RW, int CWv, int EPI, int MY>
__global__ __launch_bounds__(256) void mfma_gemm(
    const u16* __restrict__ W, const u16* __restrict__ X, u16* __restrict__ Y,
    const float* __restrict__ bias, const float* __restrict__ zmod,
    float* __restrict__ stats, int Cout, int Cin)
{
    constexpr int BM = RW * 64, BN = CWv * 64;
    constexpr int ASEG = BM / 64, BSEG = BN / 64;
    constexpr int LMY = (MY == 1) ? 0 : (MY == 2) ? 1 : (MY == 4) ? 2 : 3;
    __shared__ __align__(16) u16 Ah[BM * 32], Al[BM * 32];
    __shared__ __align__(16) u16 Bh[BN * 32], Bl[BN * 32];
    __shared__ float sstat[(EPI == 2) ? (CWv * BM * 2) : 1];

    const int tid = threadIdx.x;
    const int wave = tid >> 6;
    const int lane = tid & 63;
    const int wm = wave & (RW - 1), wn = wave / RW;
    const int l15 = lane & 15, q = lane >> 4;
    const int lin = blockIdx.x;
    const int xcd = lin & 7;
    const int jj = lin >> 3;
    const int m0 = (jj & (MY - 1)) * BM;
    const int n0 = (xcd + ((jj >> LMY) << 3)) * BN;
    const int SW = 2 * Cin;

    f4v acc0[4][4], accL[4][4];
#pragma unroll
    for (int i = 0; i < 4; ++i)
#pragma unroll
        for (int j = 0; j < 4; ++j) {
            acc0[i][j] = (f4v){0.f, 0.f, 0.f, 0.f};
            accL[i][j] = (f4v){0.f, 0.f, 0.f, 0.f};
        }

    const int nsteps = Cin >> 5;
    for (int ks = 0; ks < nsteps; ++ks) {
        const int k0 = ks << 5;
        __syncthreads();   // previous iteration's frag reads done before overwrite
#pragma unroll
        for (int s = 0; s < ASEG; ++s) {
            const int flat = s * 256 + tid;
            const int row = flat >> 2;
            const int qs = (flat & 3) ^ ((row >> 1) & 3);   // swizzled source chunk
            const u16* ga = W + (size_t)(m0 + row) * SW + k0 + qs * 8;
            gll16(ga, Ah + flat * 8);
            gll16(ga + Cin, Al + flat * 8);
        }
#pragma unroll
        for (int s = 0; s < BSEG; ++s) {
            const int flat = s * 256 + tid;
            const int row = flat >> 2;
            const int qs = (flat & 3) ^ ((row >> 1) & 3);
            const u16* gb = X + (size_t)(n0 + row) * SW + k0 + qs * 8;
            gll16(gb, Bh + flat * 8);
            gll16(gb + Cin, Bl + flat * 8);
        }
        __syncthreads();   // drains vmcnt -> LDS tiles ready
        h8v afh[4], afl[4], bfh[4], bfl[4];
#pragma unroll
        for (int i = 0; i < 4; ++i) {
            const int ar = wm * 64 + i * 16 + l15;
            const int ao = ar * 32 + ((q ^ ((ar >> 1) & 3)) << 3);
            afh[i] = *(const h8v*)(Ah + ao);
            afl[i] = *(const h8v*)(Al + ao);
        }
#pragma unroll
        for (int j = 0; j < 4; ++j) {
            const int br = wn * 64 + j * 16 + l15;
            const int bo = br * 32 + ((q ^ ((br >> 1) & 3)) << 3);
            bfh[j] = *(const h8v*)(Bh + bo);
            bfl[j] = *(const h8v*)(Bl + bo);
        }
#pragma unroll
        for (int i = 0; i < 4; ++i)
#pragma unroll
            for (int j = 0; j < 4; ++j) {
                accL[i][j] = __builtin_amdgcn_mfma_f32_16x16x32_f16(afh[i], bfl[j], accL[i][j], 0, 0, 0);
                accL[i][j] = __builtin_amdgcn_mfma_f32_16x16x32_f16(afl[i], bfh[j], accL[i][j], 0, 0, 0);
                acc0[i][j] = __builtin_amdgcn_mfma_f32_16x16x32_f16(afh[i], bfh[j], acc0[i][j], 0, 0, 0);
            }
    }

    // ---- epilogue ----
    const int bb = n0 >> 11;
    const int SY = 2 * Cout;
#pragma unroll
    for (int i = 0; i < 4; ++i) {
        const int chb = m0 + wm * 64 + i * 16 + q * 4;
        const float4 bias4 = *(const float4*)(bias + chb);
        float z0 = 0.f, z1 = 0.f, z2 = 0.f, z3 = 0.f;
        if constexpr (EPI == 1) {
            const float4 z4 = *(const float4*)(zmod + bb * CWn + chb);
            z0 = z4.x; z1 = z4.y; z2 = z4.z; z3 = z4.w;
        }
        float ssum[4] = {0.f, 0.f, 0.f, 0.f}, ssq[4] = {0.f, 0.f, 0.f, 0.f};
#pragma unroll
        for (int j = 0; j < 4; ++j) {
            const int n = n0 + wn * 64 + j * 16 + l15;
            float v0 = fmaf(accL[i][j][0], LSCI, acc0[i][j][0]) + bias4.x;
            float v1 = fmaf(accL[i][j][1], LSCI, acc0[i][j][1]) + bias4.y;
            float v2 = fmaf(accL[i][j][2], LSCI, acc0[i][j][2]) + bias4.z;
            float v3 = fmaf(accL[i][j][3], LSCI, acc0[i][j][3]) + bias4.w;
            if constexpr (EPI == 0) {
                v0 = fmaxf(v0, 0.f); v1 = fmaxf(v1, 0.f); v2 = fmaxf(v2, 0.f); v3 = fmaxf(v3, 0.f);
            } else if constexpr (EPI == 1) {
                v0 = fminf(fmaxf(v0, -1.f), 1.f) * z0;
                v1 = fminf(fmaxf(v1, -1.f), 1.f) * z1;
                v2 = fminf(fmaxf(v2, -1.f), 1.f) * z2;
                v3 = fminf(fmaxf(v3, -1.f), 1.f) * z3;
            } else {
                ssum[0] += v0; ssum[1] += v1; ssum[2] += v2; ssum[3] += v3;
                ssq[0] += v0 * v0; ssq[1] += v1 * v1; ssq[2] += v2 * v2; ssq[3] += v3 * v3;
            }
            u16 h0, l0, h1, l1, h2, l2, h3, l3;
            fsplit(v0, h0, l0); fsplit(v1, h1, l1);
            fsplit(v2, h2, l2); fsplit(v3, h3, l3);
            ushort4 hv = {h0, h1, h2, h3};
            ushort4 lv = {l0, l1, l2, l3};
            u16* yp = Y + (size_t)n * SY + chb;
            *(ushort4*)yp = hv;
            *(ushort4*)(yp + Cout) = lv;
        }
        if constexpr (EPI == 2) {
#pragma unroll
            for (int r = 0; r < 4; ++r) {
#pragma unroll
                for (int d = 1; d < 16; d <<= 1) {
                    ssum[r] += __shfl_xor(ssum[r], d);
                    ssq[r]  += __shfl_xor(ssq[r], d);
                }
            }
            if (l15 == 0) {
                const int chl = wm * 64 + i * 16 + q * 4;
#pragma unroll
                for (int r = 0; r < 4; ++r) {
                    sstat[(wn * BM + chl + r) * 2]     = ssum[r];
                    sstat[(wn * BM + chl + r) * 2 + 1] = ssq[r];
                }
            }
        }
    }
    if constexpr (EPI == 2) {
        __syncthreads();
        if (tid < BM) {
            float s0 = 0.f, s1 = 0.f;
#pragma unroll
            for (int w = 0; w < CWv; ++w) {
                s0 += sstat[(w * BM + tid) * 2];
                s1 += sstat[(w * BM + tid) * 2 + 1];
            }
            atomicAdd(&stats[(m0 + tid) * 2], s0);
            atomicAdd(&stats[(m0 + tid) * 2 + 1], s1);
        }
    }
}

__global__ void finalize_kernel(const float* __restrict__ stats, const float* __restrict__ g,
                                const float* __restrict__ be, float* __restrict__ bnp, int C) {
    const int c = blockIdx.x * blockDim.x + threadIdx.x;
    if (c >= C) return;
    const float inv = 1.0f / (float)Nn;
    const float mean = stats[c * 2] * inv;
    const float var = stats[c * 2 + 1] * inv - mean * mean;
    const float sc = g[c] / sqrtf(var + EPSf);
    bnp[c * 2] = sc;
    bnp[c * 2 + 1] = fmaf(-mean, sc, be[c]);
}

__global__ __launch_bounds__(256) void bnrelu_kernel(u16* x, const float* __restrict__ bnp, int C) {
    const int t = blockIdx.x * 256 + threadIdx.x;
    const int ch = (t * 4) & (C - 1);
    const int row = (t * 4) / C;
    u16* base = x + (size_t)row * (2 * C) + ch;
    ushort4 h = *(ushort4*)base;
    ushort4 l = *(ushort4*)(base + C);
    const float4 p0 = *(const float4*)(bnp + ch * 2);
    const float4 p1 = *(const float4*)(bnp + ch * 2 + 4);
    float a0 = fmaxf(fmaf(fjoin(h.x, l.x), p0.x, p0.y), 0.f);
    float a1 = fmaxf(fmaf(fjoin(h.y, l.y), p0.z, p0.w), 0.f);
    float a2 = fmaxf(fmaf(fjoin(h.z, l.z), p1.x, p1.y), 0.f);
    float a3 = fmaxf(fmaf(fjoin(h.w, l.w), p1.z, p1.w), 0.f);
    u16 h0, l0, h1, l1, h2, l2, h3, l3;
    fsplit(a0, h0, l0); fsplit(a1, h1, l1); fsplit(a2, h2, l2); fsplit(a3, h3, l3);
    ushort4 hv = {h0, h1, h2, h3};
    ushort4 lv = {l0, l1, l2, l3};
    *(ushort4*)base = hv;
    *(ushort4*)(base + C) = lv;
}

__global__ __launch_bounds__(256) void finalconv_pm(
    const u16* __restrict__ y3, const float* __restrict__ bnp,
    const float* __restrict__ wout, const float* __restrict__ bout,
    float* __restrict__ pts)
{
    __shared__ float swo[3][64];
    __shared__ float ssc[64], ssh[64];
    const int tid = threadIdx.x;
    if (tid < 192) swo[tid / 64][tid % 64] = wout[tid];
    if (tid < 64) { ssc[tid] = bnp[tid * 2]; ssh[tid] = bnp[tid * 2 + 1]; }
    __syncthreads();
    const int n = blockIdx.x * 256 + tid;
    const u16* yp = y3 + (size_t)n * 128;
    float d0 = bout[0], d1 = bout[1], d2 = bout[2];
#pragma unroll
    for (int c = 0; c < 64; ++c) {
        const float v = fjoin(yp[c], yp[64 + c]);
        const float a = fmaxf(fmaf(v, ssc[c], ssh[c]), 0.f);
        d0 = fmaf(a, swo[0][c], d0);
        d1 = fmaf(a, swo[1][c], d1);
        d2 = fmaf(a, swo[2][c], d2);
    }
    float4 p = {d0, d1, d2, d0 * d0 + d1 * d1 + d2 * d2};
    *(float4*)(pts + (size_t)n * 4) = p;
}

// ---- graph filtering: 8 threads/point in one wave, register-only merge -----
__global__ __launch_bounds__(512) void knn_kernel(const float* __restrict__ pts,
                                                  float* __restrict__ out) {
    __shared__ __align__(16) float4 sp[Mn];   // 32 KB -> 4 blocks/CU (wave cap)
    const int b = blockIdx.y;
    const int tid = threadIdx.x;
    const float4* pb = (const float4*)pts + (size_t)b * Mn;
    for (int i = tid; i < Mn; i += 512) sp[i] = pb[i];
    __syncthreads();
    const int lane = tid & 63;
    const int wv = tid >> 6;                    // 0..7
    const int seg = lane & 7;                   // segment 0..7
    const int ptl = (wv << 3) | (lane >> 3);    // point-local 0..63
    const int m = blockIdx.x * 64 + ptl;
    const float4 p = sp[m];
    float bd[8]; int bi[8];
#pragma unroll
    for (int k = 0; k < 8; ++k) { bd[k] = 1e30f; bi[k] = 0x7fffffff; }
    float wd = 1e30f; int wsl = 0;
    const int nb = seg << 8;
    for (int t = 0; t < 256; ++t) {
        const int n = nb | ((t + seg) & 255);   // stagger start by seg (bank tiling)
        const float4 q = sp[n];
        const float d = p.w + q.w - 2.f * (p.x * q.x + p.y * q.y + p.z * q.z);
        if (d < wd && n != m) {
            bd[wsl] = d; bi[wsl] = n;
            wd = bd[0]; wsl = 0;
#pragma unroll
            for (int k = 1; k < 8; ++k)
                if (bd[k] > wd) { wd = bd[k]; wsl = k; }
        }
    }
    // per-lane sort ascending (Batcher odd-even mergesort, 19 comparators)
#define CS8(a, c) cswap(bd[a], bi[a], bd[c], bi[c])
    CS8(0,1); CS8(2,3); CS8(4,5); CS8(6,7);
    CS8(0,2); CS8(1,3); CS8(4,6); CS8(5,7);
    CS8(1,2); CS8(5,6);
    CS8(0,4); CS8(1,5); CS8(2,6); CS8(3,7);
    CS8(2,4); CS8(3,5);
    CS8(1,2); CS8(3,4); CS8(5,6);
#undef CS8
    // 3 shuffle merge rounds: partner = lane ^ r (same point, r in {1,2,4})
#pragma unroll
    for (int r = 1; r <= 4; r <<= 1) {
        float od[8]; int oi[8];
#pragma unroll
        for (int k = 0; k < 8; ++k) {
            od[k] = __shfl_xor(bd[k], r);
            oi[k] = __shfl_xor(bi[k], r);
        }
        float md[8]; int mi[8];
#pragma unroll
        for (int k = 0; k < 8; ++k) {           // lowest-8 of union (bitonic)
            const float da = bd[k], db = od[7 - k];
            const int   ia = bi[k], ib = oi[7 - k];
            const bool bl = (db < da) || (db == da && ib < ia);
            md[k] = bl ? db : da; mi[k] = bl ? ib : ia;
        }
        // bitonic -> ascending (12 comparators)
#define CSM(a, c) cswap(md[a], mi[a], md[c], mi[c])
        CSM(0,4); CSM(1,5); CSM(2,6); CSM(3,7);
        CSM(0,2); CSM(1,3); CSM(4,6); CSM(5,7);
        CSM(0,1); CSM(2,3); CSM(4,5); CSM(6,7);
#undef CSM
#pragma unroll
        for (int k = 0; k < 8; ++k) { bd[k] = md[k]; bi[k] = mi[k]; }
    }
    if (seg == 0) {
        float nx = 0.f, ny = 0.f, nz = 0.f;
#pragma unroll
        for (int k = 0; k < 8; ++k) { const float4 q = sp[bi[k]]; nx += q.x; ny += q.y; nz += q.z; }
        const float s8 = 0.125f;
        float* ob = out + (size_t)b * 3 * Mn;
        ob[m]          = 2.f * p.x - nx * s8;
        ob[Mn + m]     = 2.f * p.y - ny * s8;
        ob[2 * Mn + m] = 2.f * p.z - nz * s8;
    }
}

// ============================================================================
extern "C" void kernel_launch(void* const* d_in, const int* in_sizes, int n_in,
                              void* d_out, int out_size, void* d_ws, size_t ws_size,
                              hipStream_t stream)
{
    (void)in_sizes; (void)n_in; (void)out_size;
    const float* z     = (const float*)d_in[0];
    const float* s     = (const float*)d_in[1];
    const float* w_m1  = (const float*)d_in[2];
    const float* b_m1  = (const float*)d_in[3];
    const float* w_m2  = (const float*)d_in[4];
    const float* b_m2  = (const float*)d_in[5];
    const float* w_out = (const float*)d_in[6];
    const float* b_out = (const float*)d_in[7];
    const float* w_c[4]  = {(const float*)d_in[8],  (const float*)d_in[12], (const float*)d_in[16], (const float*)d_in[20]};
    const float* b_c[4]  = {(const float*)d_in[9],  (const float*)d_in[13], (const float*)d_in[17], (const float*)d_in[21]};
    const float* g_c[4]  = {(const float*)d_in[10], (const float*)d_in[14], (const float*)d_in[18], (const float*)d_in[22]};
    const float* be_c[4] = {(const float*)d_in[11], (const float*)d_in[15], (const float*)d_in[19], (const float*)d_in[23]};

    char* ws = (char*)d_ws;
    const size_t MB = 1024ull * 1024ull;
    float* outp = (float*)d_out;
    if (ws_size < 208 * MB) return;   // proven: harness provides >= 208 MiB

    // -------- split-fp16 MFMA path (peak 204 MiB) --------
    u16*   wbuf  = (u16*)ws;
    float* stats = (float*)(ws + 3 * MB);
    float* bnp   = stats + 4096;
    u16*   xs  = (u16*)(ws + 4 * MB);
    u16*   x1  = (u16*)(ws + 12 * MB);
    u16*   x2  = (u16*)(ws + 76 * MB);
    u16*   y0  = (u16*)(ws + 12 * MB);   // contiguous after both chunks
    u16*   y0a = (u16*)(ws + 12 * MB);   // rows [0, 32K)
    u16*   y0b = (u16*)(ws + 76 * MB);   // rows [32K, 64K)
    u16*   y1  = (u16*)(ws + 140 * MB);
    u16*   y2  = (u16*)(ws + 12 * MB);
    u16*   y3  = (u16*)(ws + 76 * MB);
    float* pts = (float*)(ws + 4 * MB);

    hipMemsetAsync(stats, 0, 4096 * sizeof(float), stream);
    wcvt_kernel<<<WTOT / 256, 256, 0, stream>>>(w_m1, w_m2, w_c[0], w_c[1], w_c[2], w_c[3], wbuf);
    normalize_pm<<<dim3(Mn / 256, Bn), 256, 0, stream>>>(s, xs);
    // m1: [N][32] -> [N][256]  (Ntiles=512, MY=2 -> 1024 blocks)
    mfma_gemm<2, 2, 0, 2><<<1024, 256, 0, stream>>>(wbuf, xs, x1, b_m1, nullptr, nullptr, 256, 32);
    // m2: [N][256] -> [N][512] (Ntiles=512, MY=4 -> 2048 blocks)
    mfma_gemm<2, 2, 1, 4><<<2048, 256, 0, stream>>>(wbuf + 16384, x1, x2, b_m2, z, nullptr, 512, 256);
    // c0 a/b: rows halves      (Ntiles=256, MY=4 -> 1024 blocks each)
    mfma_gemm<2, 2, 2, 4><<<1024, 256, 0, stream>>>(wbuf + 278528, x2, y0a, b_c[0], nullptr, stats + 0, 512, 512);
    mfma_gemm<2, 2, 2, 4><<<1024, 256, 0, stream>>>(wbuf + 278528, x2 + (size_t)Hn * 1024, y0b, b_c[0], nullptr, stats + 0, 512, 512);
    finalize_kernel<<<2, 256, 0, stream>>>(stats + 0, g_c[0], be_c[0], bnp + 0, 512);
    bnrelu_kernel<<<(Nn / 256) * 512 / 4, 256, 0, stream>>>(y0, bnp + 0, 512);
    // c1: [N][512] -> [N][256] (Ntiles=512, MY=2 -> 1024 blocks)
    mfma_gemm<2, 2, 2, 2><<<1024, 256, 0, stream>>>(wbuf + 802816, y0, y1, b_c[1], nullptr, stats + 1024, 256, 512);
    finalize_kernel<<<1, 256, 0, stream>>>(stats + 1024, g_c[1], be_c[1], bnp + 1024, 256);
    bnrelu_kernel<<<(Nn / 256) * 256 / 4, 256, 0, stream>>>(y1, bnp + 1024, 256);
    // c2: [N][256] -> [N][128] (Ntiles=512, MY=1 -> 512 blocks)
    mfma_gemm<2, 2, 2, 1><<<512, 256, 0, stream>>>(wbuf + 1064960, y1, y2, b_c[2], nullptr, stats + 2048, 128, 256);
    finalize_kernel<<<1, 128, 0, stream>>>(stats + 2048, g_c[2], be_c[2], bnp + 2048, 128);
    bnrelu_kernel<<<(Nn / 256) * 128 / 4, 256, 0, stream>>>(y2, bnp + 2048, 128);
    // c3: [N][128] -> [N][64]  (BM=64, BN=256; Ntiles=256, MY=1 -> 256 blocks)
    mfma_gemm<1, 4, 2, 1><<<256, 256, 0, stream>>>(wbuf + 1130496, y2, y3, b_c[3], nullptr, stats + 3072, 64, 128);
    finalize_kernel<<<1, 64, 0, stream>>>(stats + 3072, g_c[3], be_c[3], bnp + 3072, 64);
    finalconv_pm<<<Nn / 256, 256, 0, stream>>>(y3, bnp + 3072, w_out, b_out, pts);
    knn_kernel<<<dim3(Mn / 64, Bn), 512, 0, stream>>>(pts, outp);
}

// Round 12
// 967.909 us; speedup vs baseline: 2.7344x; 1.0256x over previous
//
#include <hip/hip_runtime.h>
#include <math.h>

#define Bn 32
#define Mn 2048
#define Nn 65536      // Bn * Mn
#define Hn 32768      // Nn / 2 (chunk for race-free c0)
#define SDn 16
#define CWn 512
#define EPSf 1e-5f
#define KGF 8
#define WTOT 573440   // logical weight elements
#define LSC 2048.0f   // lo-plane scale (2^11)
#define LSCI (1.0f / 2048.0f)

typedef unsigned short u16;
typedef _Float16 fp16_t;
typedef __attribute__((ext_vector_type(8))) _Float16 h8v;  // MFMA A/B frag: 8 f16
typedef __attribute__((ext_vector_type(4))) float f4v;     // MFMA C/D frag: 4 fp32

__device__ __forceinline__ u16 f2h(float f) {
    union { fp16_t h; u16 u; } c; c.h = (fp16_t)f; return c.u;
}
__device__ __forceinline__ float h2f(u16 u) {
    union { fp16_t h; u16 u; } c; c.u = u; return (float)c.h;
}
__device__ __forceinline__ void fsplit(float f, u16& hi, u16& lo) {
    hi = f2h(f);
    lo = f2h((f - h2f(hi)) * LSC);
}
__device__ __forceinline__ float fjoin(u16 hi, u16 lo) {
    return h2f(hi) + h2f(lo) * LSCI;
}
// async global->LDS, 16 bytes/lane (dest must be wave-uniform base + lane*16)
__device__ __forceinline__ void gll16(const u16* g, u16* l) {
    __builtin_amdgcn_global_load_lds((const __attribute__((address_space(1))) void*)g,
                                     (__attribute__((address_space(3))) void*)l, 16, 0, 0);
}
// lexicographic comparator swap (merge tail): keep (d0,i0) <= (d1,i1)
__device__ __forceinline__ void cswap(float& d0, int& i0, float& d1, int& i1) {
    const bool gt = (d0 > d1) || (d0 == d1 && i0 > i1);
    const float ta = gt ? d1 : d0, tb = gt ? d0 : d1;
    const int   ua = gt ? i1 : i0, ub = gt ? i0 : i1;
    d0 = ta; d1 = tb; i0 = ua; i1 = ub;
}
// distance-only stable comparator swap (hot loop): swap iff d0 > d1 strictly
__device__ __forceinline__ void cswapd(float& d0, int& i0, float& d1, int& i1) {
    const bool gt = d0 > d1;
    const float ta = gt ? d1 : d0, tb = gt ? d0 : d1;
    const int   ua = gt ? i1 : i0, ub = gt ? i0 : i1;
    d0 = ta; d1 = tb; i0 = ua; i1 = ub;
}

// ============================================================================
// prep: weights fp32 -> split layout, normalize s -> xs, zero stats (fused)
// ============================================================================
__global__ __launch_bounds__(256) void prep_kernel(
    const float* __restrict__ wm1, const float* __restrict__ wm2,
    const float* __restrict__ wc0, const float* __restrict__ wc1,
    const float* __restrict__ wc2, const float* __restrict__ wc3,
    const float* __restrict__ s,
    u16* __restrict__ wbuf, u16* __restrict__ xs, float* __restrict__ stats)
{
    const int bid = blockIdx.x;
    const int tid = threadIdx.x;
    if (bid < 2240) {
        // ---- weight conversion: [Cout][hi[Cin] | lo[Cin]] ----
        int i = bid * 256 + tid;
        float w; int r, k, Cin; size_t base;
        if (i < 8192) {                              // m1 padded [256][32]
            r = i >> 5; k = i & 31; Cin = 32; base = 0;
            w = (k < SDn) ? wm1[r * SDn + k] : 0.f;
        } else {
            int j = i - 8192;
            if (j < 131072)                    { r = j >> 8; k = j & 255; Cin = 256; base = 16384;   w = wm2[j]; }
            else if ((j -= 131072) < 262144)   { r = j >> 9; k = j & 511; Cin = 512; base = 278528;  w = wc0[j]; }
            else if ((j -= 262144) < 131072)   { r = j >> 9; k = j & 511; Cin = 512; base = 802816;  w = wc1[j]; }
            else if ((j -= 131072) < 32768)    { r = j >> 8; k = j & 255; Cin = 256; base = 1064960; w = wc2[j]; }
            else { j -= 32768;                   r = j >> 7; k = j & 127; Cin = 128; base = 1130496; w = wc3[j]; }
        }
        const size_t addr = base + (size_t)r * (2 * Cin) + k;
        u16 hi, lo; fsplit(w, hi, lo);
        wbuf[addr] = hi;
        wbuf[addr + Cin] = lo;
    } else if (bid < 2496) {
        // ---- normalize s[B,16,M] -> xs[N][64] (hi[32]|lo[32], upper 16 zero)
        const int b2 = bid - 2240;
        const int m = (b2 & 7) * 256 + tid;
        const int b = b2 >> 3;
        const float* sp = s + (size_t)b * SDn * Mn + m;
        float v[SDn]; float sq = 0.f;
#pragma unroll
        for (int c = 0; c < SDn; ++c) { v[c] = sp[(size_t)c * Mn]; sq += v[c] * v[c]; }
        const float r = 1.0f / sqrtf(sq);
        unsigned int uh[8], ul[8];
#pragma unroll
        for (int c = 0; c < 8; ++c) {
            u16 h0, l0, h1, l1;
            fsplit(v[2 * c] * r, h0, l0);
            fsplit(v[2 * c + 1] * r, h1, l1);
            uh[c] = (unsigned int)h0 | ((unsigned int)h1 << 16);
            ul[c] = (unsigned int)l0 | ((unsigned int)l1 << 16);
        }
        uint4* xp = (uint4*)(xs + (size_t)(b * Mn + m) * 64);
        xp[0] = make_uint4(uh[0], uh[1], uh[2], uh[3]);
        xp[1] = make_uint4(uh[4], uh[5], uh[6], uh[7]);
        xp[2] = make_uint4(0, 0, 0, 0);
        xp[3] = make_uint4(0, 0, 0, 0);
        xp[4] = make_uint4(ul[0], ul[1], ul[2], ul[3]);
        xp[5] = make_uint4(ul[4], ul[5], ul[6], ul[7]);
        xp[6] = make_uint4(0, 0, 0, 0);
        xp[7] = make_uint4(0, 0, 0, 0);
    } else {
        // ---- zero BN stats (4096 floats) ----
        float4 z4 = {0.f, 0.f, 0.f, 0.f};
        float4* sp4 = (float4*)stats;
#pragma unroll
        for (int k = 0; k < 4; ++k) sp4[tid * 4 + k] = z4;
    }
}

// ---- split fp16 MFMA GEMM, async staging, XCD remap, swizzled LDS ----------
// acc0 = Wh*Xh ; accL = Wh*Xl' + Wl'*Xh ; result = acc0 + accL/2048
template<int RW, int CWv, int EPI, int MY>
__global__ __launch_bounds__(256) void mfma_gemm(
    const u16* __restrict__ W, const u16* __restrict__ X, u16* __restrict__ Y,
    const float* __restrict__ bias, const float* __restrict__ zmod,
    float* __restrict__ stats, int Cout, int Cin)
{
    constexpr int BM = RW * 64, BN = CWv * 64;
    constexpr int ASEG = BM / 64, BSEG = BN / 64;
    constexpr int LMY = (MY == 1) ? 0 : (MY == 2) ? 1 : (MY == 4) ? 2 : 3;
    __shared__ __align__(16) u16 Ah[BM * 32], Al[BM * 32];
    __shared__ __align__(16) u16 Bh[BN * 32], Bl[BN * 32];
    __shared__ float sstat[(EPI == 2) ? (CWv * BM * 2) : 1];

    const int tid = threadIdx.x;
    const int wave = tid >> 6;
    const int lane = tid & 63;
    const int wm = wave & (RW - 1), wn = wave / RW;
    const int l15 = lane & 15, q = lane >> 4;
    const int lin = blockIdx.x;
    const int xcd = lin & 7;
    const int jj = lin >> 3;
    const int m0 = (jj & (MY - 1)) * BM;
    const int n0 = (xcd + ((jj >> LMY) << 3)) * BN;
    const int SW = 2 * Cin;

    f4v acc0[4][4], accL[4][4];
#pragma unroll
    for (int i = 0; i < 4; ++i)
#pragma unroll
        for (int j = 0; j < 4; ++j) {
            acc0[i][j] = (f4v){0.f, 0.f, 0.f, 0.f};
            accL[i][j] = (f4v){0.f, 0.f, 0.f, 0.f};
        }

    const int nsteps = Cin >> 5;
    for (int ks = 0; ks < nsteps; ++ks) {
        const int k0 = ks << 5;
        __syncthreads();   // previous iteration's frag reads done before overwrite
#pragma unroll
        for (int s = 0; s < ASEG; ++s) {
            const int flat = s * 256 + tid;
            const int row = flat >> 2;
            const int qs = (flat & 3) ^ ((row >> 1) & 3);   // swizzled source chunk
            const u16* ga = W + (size_t)(m0 + row) * SW + k0 + qs * 8;
            gll16(ga, Ah + flat * 8);
            gll16(ga + Cin, Al + flat * 8);
        }
#pragma unroll
        for (int s = 0; s < BSEG; ++s) {
            const int flat = s * 256 + tid;
            const int row = flat >> 2;
            const int qs = (flat & 3) ^ ((row >> 1) & 3);
            const u16* gb = X + (size_t)(n0 + row) * SW + k0 + qs * 8;
            gll16(gb, Bh + flat * 8);
            gll16(gb + Cin, Bl + flat * 8);
        }
        __syncthreads();   // drains vmcnt -> LDS tiles ready
        h8v afh[4], afl[4], bfh[4], bfl[4];
#pragma unroll
        for (int i = 0; i < 4; ++i) {
            const int ar = wm * 64 + i * 16 + l15;
            const int ao = ar * 32 + ((q ^ ((ar >> 1) & 3)) << 3);
            afh[i] = *(const h8v*)(Ah + ao);
            afl[i] = *(const h8v*)(Al + ao);
        }
#pragma unroll
        for (int j = 0; j < 4; ++j) {
            const int br = wn * 64 + j * 16 + l15;
            const int bo = br * 32 + ((q ^ ((br >> 1) & 3)) << 3);
            bfh[j] = *(const h8v*)(Bh + bo);
            bfl[j] = *(const h8v*)(Bl + bo);
        }
#pragma unroll
        for (int i = 0; i < 4; ++i)
#pragma unroll
            for (int j = 0; j < 4; ++j) {
                accL[i][j] = __builtin_amdgcn_mfma_f32_16x16x32_f16(afh[i], bfl[j], accL[i][j], 0, 0, 0);
                accL[i][j] = __builtin_amdgcn_mfma_f32_16x16x32_f16(afl[i], bfh[j], accL[i][j], 0, 0, 0);
                acc0[i][j] = __builtin_amdgcn_mfma_f32_16x16x32_f16(afh[i], bfh[j], acc0[i][j], 0, 0, 0);
            }
    }

    // ---- epilogue ----
    const int bb = n0 >> 11;
    const int SY = 2 * Cout;
#pragma unroll
    for (int i = 0; i < 4; ++i) {
        const int chb = m0 + wm * 64 + i * 16 + q * 4;
        const float4 bias4 = *(const float4*)(bias + chb);
        float z0 = 0.f, z1 = 0.f, z2 = 0.f, z3 = 0.f;
        if constexpr (EPI == 1) {
            const float4 z4 = *(const float4*)(zmod + bb * CWn + chb);
            z0 = z4.x; z1 = z4.y; z2 = z4.z; z3 = z4.w;
        }
        float ssum[4] = {0.f, 0.f, 0.f, 0.f}, ssq[4] = {0.f, 0.f, 0.f, 0.f};
#pragma unroll
        for (int j = 0; j < 4; ++j) {
            const int n = n0 + wn * 64 + j * 16 + l15;
            float v0 = fmaf(accL[i][j][0], LSCI, acc0[i][j][0]) + bias4.x;
            float v1 = fmaf(accL[i][j][1], LSCI, acc0[i][j][1]) + bias4.y;
            float v2 = fmaf(accL[i][j][2], LSCI, acc0[i][j][2]) + bias4.z;
            float v3 = fmaf(accL[i][j][3], LSCI, acc0[i][j][3]) + bias4.w;
            if constexpr (EPI == 0) {
                v0 = fmaxf(v0, 0.f); v1 = fmaxf(v1, 0.f); v2 = fmaxf(v2, 0.f); v3 = fmaxf(v3, 0.f);
            } else if constexpr (EPI == 1) {
                v0 = fminf(fmaxf(v0, -1.f), 1.f) * z0;
                v1 = fminf(fmaxf(v1, -1.f), 1.f) * z1;
                v2 = fminf(fmaxf(v2, -1.f), 1.f) * z2;
                v3 = fminf(fmaxf(v3, -1.f), 1.f) * z3;
            } else {
                ssum[0] += v0; ssum[1] += v1; ssum[2] += v2; ssum[3] += v3;
                ssq[0] += v0 * v0; ssq[1] += v1 * v1; ssq[2] += v2 * v2; ssq[3] += v3 * v3;
            }
            u16 h0, l0, h1, l1, h2, l2, h3, l3;
            fsplit(v0, h0, l0); fsplit(v1, h1, l1);
            fsplit(v2, h2, l2); fsplit(v3, h3, l3);
            ushort4 hv = {h0, h1, h2, h3};
            ushort4 lv = {l0, l1, l2, l3};
            u16* yp = Y + (size_t)n * SY + chb;
            *(ushort4*)yp = hv;
            *(ushort4*)(yp + Cout) = lv;
        }
        if constexpr (EPI == 2) {
#pragma unroll
            for (int r = 0; r < 4; ++r) {
#pragma unroll
                for (int d = 1; d < 16; d <<= 1) {
                    ssum[r] += __shfl_xor(ssum[r], d);
                    ssq[r]  += __shfl_xor(ssq[r], d);
                }
            }
            if (l15 == 0) {
                const int chl = wm * 64 + i * 16 + q * 4;
#pragma unroll
                for (int r = 0; r < 4; ++r) {
                    sstat[(wn * BM + chl + r) * 2]     = ssum[r];
                    sstat[(wn * BM + chl + r) * 2 + 1] = ssq[r];
                }
            }
        }
    }
    if constexpr (EPI == 2) {
        __syncthreads();
        if (tid < BM) {
            float s0 = 0.f, s1 = 0.f;
#pragma unroll
            for (int w = 0; w < CWv; ++w) {
                s0 += sstat[(w * BM + tid) * 2];
                s1 += sstat[(w * BM + tid) * 2 + 1];
            }
            atomicAdd(&stats[(m0 + tid) * 2], s0);
            atomicAdd(&stats[(m0 + tid) * 2 + 1], s1);
        }
    }
}

__global__ void finalize_kernel(const float* __restrict__ stats, const float* __restrict__ g,
                                const float* __restrict__ be, float* __restrict__ bnp, int C) {
    const int c = blockIdx.x * blockDim.x + threadIdx.x;
    if (c >= C) return;
    const float inv = 1.0f / (float)Nn;
    const float mean = stats[c * 2] * inv;
    const float var = stats[c * 2 + 1] * inv - mean * mean;
    const float sc = g[c] / sqrtf(var + EPSf);
    bnp[c * 2] = sc;
    bnp[c * 2 + 1] = fmaf(-mean, sc, be[c]);
}

// ---- in-place BN+ReLU over [rows][2C], 8 logical elems/thread (uint4) ------
template<int C>
__global__ __launch_bounds__(256) void bnrelu_kernel(u16* x, const float* __restrict__ bnp) {
    const int t = blockIdx.x * 256 + threadIdx.x;
    const int i = t * 8;
    const int ch = i & (C - 1);
    const int row = i / C;
    u16* base = x + (size_t)row * (2 * C) + ch;
    const uint4 H = *(uint4*)base;
    const uint4 L = *(uint4*)(base + C);
    const unsigned hu[4] = {H.x, H.y, H.z, H.w};
    const unsigned lu[4] = {L.x, L.y, L.z, L.w};
    const float4 P0 = *(const float4*)(bnp + ch * 2);
    const float4 P1 = *(const float4*)(bnp + ch * 2 + 4);
    const float4 P2 = *(const float4*)(bnp + ch * 2 + 8);
    const float4 P3 = *(const float4*)(bnp + ch * 2 + 12);
    const float sc[8] = {P0.x, P0.z, P1.x, P1.z, P2.x, P2.z, P3.x, P3.z};
    const float sh[8] = {P0.y, P0.w, P1.y, P1.w, P2.y, P2.w, P3.y, P3.w};
    unsigned oh[4], ol[4];
#pragma unroll
    for (int e = 0; e < 4; ++e) {
        const int j = e * 2;
        const float a0 = fmaxf(fmaf(fjoin((u16)(hu[e] & 0xffff), (u16)(lu[e] & 0xffff)), sc[j], sh[j]), 0.f);
        const float a1 = fmaxf(fmaf(fjoin((u16)(hu[e] >> 16), (u16)(lu[e] >> 16)), sc[j + 1], sh[j + 1]), 0.f);
        u16 h0, l0, h1, l1;
        fsplit(a0, h0, l0); fsplit(a1, h1, l1);
        oh[e] = (unsigned)h0 | ((unsigned)h1 << 16);
        ol[e] = (unsigned)l0 | ((unsigned)l1 << 16);
    }
    *(uint4*)base = make_uint4(oh[0], oh[1], oh[2], oh[3]);
    *(uint4*)(base + C) = make_uint4(ol[0], ol[1], ol[2], ol[3]);
}

// ---- final 64->3 conv (BN+ReLU on split input), vectorized loads -----------
__global__ __launch_bounds__(256) void finalconv_pm(
    const u16* __restrict__ y3, const float* __restrict__ bnp,
    const float* __restrict__ wout, const float* __restrict__ bout,
    float* __restrict__ pts)
{
    __shared__ float swo[3][64];
    __shared__ float ssc[64], ssh[64];
    const int tid = threadIdx.x;
    if (tid < 192) swo[tid / 64][tid % 64] = wout[tid];
    if (tid < 64) { ssc[tid] = bnp[tid * 2]; ssh[tid] = bnp[tid * 2 + 1]; }
    __syncthreads();
    const int n = blockIdx.x * 256 + tid;
    const uint4* yph = (const uint4*)(y3 + (size_t)n * 128);
    float d0 = bout[0], d1 = bout[1], d2 = bout[2];
#pragma unroll
    for (int cc = 0; cc < 8; ++cc) {
        const uint4 H = yph[cc];
        const uint4 L = yph[8 + cc];
        const unsigned hu[4] = {H.x, H.y, H.z, H.w};
        const unsigned lu[4] = {L.x, L.y, L.z, L.w};
#pragma unroll
        for (int e = 0; e < 4; ++e) {
            const int c = cc * 8 + e * 2;
            const float v0 = fjoin((u16)(hu[e] & 0xffff), (u16)(lu[e] & 0xffff));
            const float v1 = fjoin((u16)(hu[e] >> 16), (u16)(lu[e] >> 16));
            const float a0 = fmaxf(fmaf(v0, ssc[c], ssh[c]), 0.f);
            const float a1 = fmaxf(fmaf(v1, ssc[c + 1], ssh[c + 1]), 0.f);
            d0 = fmaf(a0, swo[0][c], d0); d0 = fmaf(a1, swo[0][c + 1], d0);
            d1 = fmaf(a0, swo[1][c], d1); d1 = fmaf(a1, swo[1][c + 1], d1);
            d2 = fmaf(a0, swo[2][c], d2); d2 = fmaf(a1, swo[2][c + 1], d2);
        }
    }
    float4 p = {d0, d1, d2, d0 * d0 + d1 * d1 + d2 * d2};
    *(float4*)(pts + (size_t)n * 4) = p;
}

// ---- graph filtering: 8 threads/point in one wave, branchless insert -------
// Per candidate: replace-max-then-bubble on a sorted ascending 8-list.
// Zero branches / zero divergence / no dynamic register indexing.
// Stable strict compares + ascending n preserve "earlier index" tie order.
__global__ __launch_bounds__(512) void knn_kernel(const float* __restrict__ pts,
                                                  float* __restrict__ out) {
    __shared__ __align__(16) float4 sp[Mn];   // 32 KB -> 4 blocks/CU (wave cap)
    const int b = blockIdx.y;
    const int tid = threadIdx.x;
    const float4* pb = (const float4*)pts + (size_t)b * Mn;
    for (int i = tid; i < Mn; i += 512) sp[i] = pb[i];
    __syncthreads();
    const int lane = tid & 63;
    const int wv = tid >> 6;                    // 0..7
    const int seg = lane & 7;                   // segment 0..7
    const int ptl = (wv << 3) | (lane >> 3);    // point-local 0..63
    const int m = blockIdx.x * 64 + ptl;
    const float4 p = sp[m];
    float bd[8]; int bi[8];
#pragma unroll
    for (int k = 0; k < 8; ++k) { bd[k] = 1e30f; bi[k] = 0x7fffffff; }
    const int nb = seg << 8;
    for (int t = 0; t < 256; ++t) {
        const int n = nb | ((t + seg) & 255);   // stagger start by seg (bank tiling)
        const float4 q = sp[n];
        float d = p.w + q.w - 2.f * (p.x * q.x + p.y * q.y + p.z * q.z);
        d = (n == m) ? 1e30f : d;               // exclude self
        // replace worst if better (strict: ties keep earlier index)
        const bool ins = d < bd[7];
        bd[7] = ins ? d : bd[7];
        bi[7] = ins ? n : bi[7];
        // bubble into place (stable)
        cswapd(bd[6], bi[6], bd[7], bi[7]);
        cswapd(bd[5], bi[5], bd[6], bi[6]);
        cswapd(bd[4], bi[4], bd[5], bi[5]);
        cswapd(bd[3], bi[3], bd[4], bi[4]);
        cswapd(bd[2], bi[2], bd[3], bi[3]);
        cswapd(bd[1], bi[1], bd[2], bi[2]);
        cswapd(bd[0], bi[0], bd[1], bi[1]);
    }
    // per-lane list already sorted ascending.
    // 3 shuffle merge rounds: partner = lane ^ r (same point, r in {1,2,4})
#pragma unroll
    for (int r = 1; r <= 4; r <<= 1) {
        float od[8]; int oi[8];
#pragma unroll
        for (int k = 0; k < 8; ++k) {
            od[k] = __shfl_xor(bd[k], r);
            oi[k] = __shfl_xor(bi[k], r);
        }
        float md[8]; int mi[8];
#pragma unroll
        for (int k = 0; k < 8; ++k) {           // lowest-8 of union (bitonic)
            const float da = bd[k], db = od[7 - k];
            const int   ia = bi[k], ib = oi[7 - k];
            const bool bl = (db < da) || (db == da && ib < ia);
            md[k] = bl ? db : da; mi[k] = bl ? ib : ia;
        }
        // bitonic -> ascending (12 comparators)
#define CSM(a, c) cswap(md[a], mi[a], md[c], mi[c])
        CSM(0,4); CSM(1,5); CSM(2,6); CSM(3,7);
        CSM(0,2); CSM(1,3); CSM(4,6); CSM(5,7);
        CSM(0,1); CSM(2,3); CSM(4,5); CSM(6,7);
#undef CSM
#pragma unroll
        for (int k = 0; k < 8; ++k) { bd[k] = md[k]; bi[k] = mi[k]; }
    }
    if (seg == 0) {
        float nx = 0.f, ny = 0.f, nz = 0.f;
#pragma unroll
        for (int k = 0; k < 8; ++k) { const float4 q = sp[bi[k]]; nx += q.x; ny += q.y; nz += q.z; }
        const float s8 = 0.125f;
        float* ob = out + (size_t)b * 3 * Mn;
        ob[m]          = 2.f * p.x - nx * s8;
        ob[Mn + m]     = 2.f * p.y - ny * s8;
        ob[2 * Mn + m] = 2.f * p.z - nz * s8;
    }
}

// ============================================================================
extern "C" void kernel_launch(void* const* d_in, const int* in_sizes, int n_in,
                              void* d_out, int out_size, void* d_ws, size_t ws_size,
                              hipStream_t stream)
{
    (void)in_sizes; (void)n_in; (void)out_size;
    const float* z     = (const float*)d_in[0];
    const float* s     = (const float*)d_in[1];
    const float* w_m1  = (const float*)d_in[2];
    const float* b_m1  = (const float*)d_in[3];
    const float* w_m2  = (const float*)d_in[4];
    const float* b_m2  = (const float*)d_in[5];
    const float* w_out = (const float*)d_in[6];
    const float* b_out = (const float*)d_in[7];
    const float* w_c[4]  = {(const float*)d_in[8],  (const float*)d_in[12], (const float*)d_in[16], (const float*)d_in[20]};
    const float* b_c[4]  = {(const float*)d_in[9],  (const float*)d_in[13], (const float*)d_in[17], (const float*)d_in[21]};
    const float* g_c[4]  = {(const float*)d_in[10], (const float*)d_in[14], (const float*)d_in[18], (const float*)d_in[22]};
    const float* be_c[4] = {(const float*)d_in[11], (const float*)d_in[15], (const float*)d_in[19], (const float*)d_in[23]};

    char* ws = (char*)d_ws;
    const size_t MB = 1024ull * 1024ull;
    float* outp = (float*)d_out;
    if (ws_size < 208 * MB) return;   // proven: harness provides >= 208 MiB

    // -------- split-fp16 MFMA path (peak 204 MiB) --------
    u16*   wbuf  = (u16*)ws;
    float* stats = (float*)(ws + 3 * MB);
    float* bnp   = stats + 4096;
    u16*   xs  = (u16*)(ws + 4 * MB);
    u16*   x1  = (u16*)(ws + 12 * MB);
    u16*   x2  = (u16*)(ws + 76 * MB);
    u16*   y0  = (u16*)(ws + 12 * MB);   // contiguous after both chunks
    u16*   y0a = (u16*)(ws + 12 * MB);   // rows [0, 32K)
    u16*   y0b = (u16*)(ws + 76 * MB);   // rows [32K, 64K)
    u16*   y1  = (u16*)(ws + 140 * MB);
    u16*   y2  = (u16*)(ws + 12 * MB);
    u16*   y3  = (u16*)(ws + 76 * MB);
    float* pts = (float*)(ws + 4 * MB);

    prep_kernel<<<2497, 256, 0, stream>>>(w_m1, w_m2, w_c[0], w_c[1], w_c[2], w_c[3], s, wbuf, xs, stats);
    // m1: [N][32] -> [N][256]  (Ntiles=512, MY=2 -> 1024 blocks)
    mfma_gemm<2, 2, 0, 2><<<1024, 256, 0, stream>>>(wbuf, xs, x1, b_m1, nullptr, nullptr, 256, 32);
    // m2: [N][256] -> [N][512] (Ntiles=512, MY=4 -> 2048 blocks)
    mfma_gemm<2, 2, 1, 4><<<2048, 256, 0, stream>>>(wbuf + 16384, x1, x2, b_m2, z, nullptr, 512, 256);
    // c0 a/b: rows halves      (Ntiles=256, MY=4 -> 1024 blocks each)
    mfma_gemm<2, 2, 2, 4><<<1024, 256, 0, stream>>>(wbuf + 278528, x2, y0a, b_c[0], nullptr, stats + 0, 512, 512);
    mfma_gemm<2, 2, 2, 4><<<1024, 256, 0, stream>>>(wbuf + 278528, x2 + (size_t)Hn * 1024, y0b, b_c[0], nullptr, stats + 0, 512, 512);
    finalize_kernel<<<2, 256, 0, stream>>>(stats + 0, g_c[0], be_c[0], bnp + 0, 512);
    bnrelu_kernel<512><<<16384, 256, 0, stream>>>(y0, bnp + 0);
    // c1: [N][512] -> [N][256] (Ntiles=512, MY=2 -> 1024 blocks)
    mfma_gemm<2, 2, 2, 2><<<1024, 256, 0, stream>>>(wbuf + 802816, y0, y1, b_c[1], nullptr, stats + 1024, 256, 512);
    finalize_kernel<<<1, 256, 0, stream>>>(stats + 1024, g_c[1], be_c[1], bnp + 1024, 256);
    bnrelu_kernel<256><<<8192, 256, 0, stream>>>(y1, bnp + 1024);
    // c2: [N][256] -> [N][128] (Ntiles=512, MY=1 -> 512 blocks)
    mfma_gemm<2, 2, 2, 1><<<512, 256, 0, stream>>>(wbuf + 1064960, y1, y2, b_c[2], nullptr, stats + 2048, 128, 256);
    finalize_kernel<<<1, 128, 0, stream>>>(stats + 2048, g_c[2], be_c[2], bnp + 2048, 128);
    bnrelu_kernel<128><<<4096, 256, 0, stream>>>(y2, bnp + 2048);
    // c3: [N][128] -> [N][64]  (BM=64, BN=256; Ntiles=256, MY=1 -> 256 blocks)
    mfma_gemm<1, 4, 2, 1><<<256, 256, 0, stream>>>(wbuf + 1130496, y2, y3, b_c[3], nullptr, stats + 3072, 64, 128);
    finalize_kernel<<<1, 64, 0, stream>>>(stats + 3072, g_c[3], be_c[3], bnp + 3072, 64);
    finalconv_pm<<<Nn / 256, 256, 0, stream>>>(y3, bnp + 3072, w_out, b_out, pts);
    knn_kernel<<<dim3(Mn / 64, Bn), 512, 0, stream>>>(pts, outp);
}